// Round 3
// baseline (612.143 us; speedup 1.0000x reference)
//
#include <hip/hip_runtime.h>
#include <hip/hip_fp16.h>
#include <math.h>

// GAT layer: N=100000, E=1600000, F=64, H=4 (Dh=16).
//
// Restructure: e_h = k[s]*q[t] = h[s] . qq[t,h,:], where
//   qq[t,h,f] = sum_d q[t,h,d] * Wk[f, h*16+d]   (Wk folded into q side).
// Pipeline: fused {qq GEMM (fp16 out, pre-scaled by log2e) | in-degree hist}
// -> scan -> scatter-lite (srcs[p]=src only, 4B payload) ->
// fused score+aggregate (per record: gather h[src] row once, per-lane
// product vs per-node qq regs, DPP 64-lane add-reduce x4 heads (VALU pipe,
// no LDS), exp2, SGPR-uniform weights, PV accumulate) -> in-place out GEMM.
//
// This removes: k16/q16 arrays, the k/q random gathers (191 MB fetch in the
// old scatter), the 16-20B scattered record write (150 MB), and the record
// stream read in aggregate. The only remaining gathers are the h[src] rows
// aggregate always needed.

#define FDIM 64
#define NHEADS 4

// ---- K1: multi-role kernel: [0,KQB) qq-GEMM | rest hist ----
__global__ __launch_bounds__(256) void fused_pre_kernel(
    const float* __restrict__ h, const float* __restrict__ Wk,
    const float* __restrict__ Wq, __half* __restrict__ qq16,
    const int* __restrict__ dst, int* __restrict__ counts,
    int N, int E, int KQB)
{
    __shared__ float sWk[FDIM * FDIM];   // Wk * log2(e)  (only feeds qq)
    __shared__ float sWq[FDIM * FDIM];
    int bid = blockIdx.x;
    if (bid < KQB) {
        for (int i = threadIdx.x; i < FDIM * FDIM; i += 256) {
            sWk[i] = Wk[i] * 1.4426950408889634f;
            sWq[i] = Wq[i];
        }
        __syncthreads();
        int cg = threadIdx.x & 3;      // head
        int rg = threadIdx.x >> 2;
        long base = (long)bid * 128 + rg * 2;
        const float4* sWk4 = (const float4*)sWk;
        const float4* sWq4 = (const float4*)sWq;
        const float4* h4 = (const float4*)h;

        // ---- stage 1: q[r, cg*16 + d] for d=0..15, f32 ----
        float accq[2][16];
#pragma unroll
        for (int i = 0; i < 2; ++i)
#pragma unroll
            for (int c = 0; c < 16; ++c) accq[i][c] = 0.f;

        for (int fs = 0; fs < FDIM; fs += 4) {
            float4 hv[2];
#pragma unroll
            for (int i = 0; i < 2; ++i) {
                long r = base + i; if (r >= N) r = N - 1;
                hv[i] = h4[r * 16 + (fs >> 2)];
            }
#pragma unroll
            for (int fi = 0; fi < 4; ++fi) {
                int f = fs + fi;
                float4 wq0 = sWq4[f * 16 + cg * 4 + 0];
                float4 wq1 = sWq4[f * 16 + cg * 4 + 1];
                float4 wq2 = sWq4[f * 16 + cg * 4 + 2];
                float4 wq3 = sWq4[f * 16 + cg * 4 + 3];
#pragma unroll
                for (int i = 0; i < 2; ++i) {
                    float hvf = (&hv[i].x)[fi];
                    accq[i][0]  = fmaf(hvf, wq0.x, accq[i][0]);
                    accq[i][1]  = fmaf(hvf, wq0.y, accq[i][1]);
                    accq[i][2]  = fmaf(hvf, wq0.z, accq[i][2]);
                    accq[i][3]  = fmaf(hvf, wq0.w, accq[i][3]);
                    accq[i][4]  = fmaf(hvf, wq1.x, accq[i][4]);
                    accq[i][5]  = fmaf(hvf, wq1.y, accq[i][5]);
                    accq[i][6]  = fmaf(hvf, wq1.z, accq[i][6]);
                    accq[i][7]  = fmaf(hvf, wq1.w, accq[i][7]);
                    accq[i][8]  = fmaf(hvf, wq2.x, accq[i][8]);
                    accq[i][9]  = fmaf(hvf, wq2.y, accq[i][9]);
                    accq[i][10] = fmaf(hvf, wq2.z, accq[i][10]);
                    accq[i][11] = fmaf(hvf, wq2.w, accq[i][11]);
                    accq[i][12] = fmaf(hvf, wq3.x, accq[i][12]);
                    accq[i][13] = fmaf(hvf, wq3.y, accq[i][13]);
                    accq[i][14] = fmaf(hvf, wq3.z, accq[i][14]);
                    accq[i][15] = fmaf(hvf, wq3.w, accq[i][15]);
                }
            }
        }

        // ---- stage 2: qq[r, cg, f] = sum_d accq[d] * sWk[f][cg*16+d] ----
        for (int fc = 0; fc < 4; ++fc) {
            float o[2][16];
#pragma unroll
            for (int ff = 0; ff < 16; ++ff) {
                int f = fc * 16 + ff;
                float4 w0 = sWk4[f * 16 + cg * 4 + 0];
                float4 w1 = sWk4[f * 16 + cg * 4 + 1];
                float4 w2 = sWk4[f * 16 + cg * 4 + 2];
                float4 w3 = sWk4[f * 16 + cg * 4 + 3];
#pragma unroll
                for (int i = 0; i < 2; ++i) {
                    float s = 0.f;
                    s = fmaf(accq[i][0],  w0.x, s);
                    s = fmaf(accq[i][1],  w0.y, s);
                    s = fmaf(accq[i][2],  w0.z, s);
                    s = fmaf(accq[i][3],  w0.w, s);
                    s = fmaf(accq[i][4],  w1.x, s);
                    s = fmaf(accq[i][5],  w1.y, s);
                    s = fmaf(accq[i][6],  w1.z, s);
                    s = fmaf(accq[i][7],  w1.w, s);
                    s = fmaf(accq[i][8],  w2.x, s);
                    s = fmaf(accq[i][9],  w2.y, s);
                    s = fmaf(accq[i][10], w2.z, s);
                    s = fmaf(accq[i][11], w2.w, s);
                    s = fmaf(accq[i][12], w3.x, s);
                    s = fmaf(accq[i][13], w3.y, s);
                    s = fmaf(accq[i][14], w3.z, s);
                    s = fmaf(accq[i][15], w3.w, s);
                    o[i][ff] = s;
                }
            }
#pragma unroll
            for (int i = 0; i < 2; ++i) {
                long r = base + i;
                if (r >= N) continue;
                __half2 hp[8];
#pragma unroll
                for (int c = 0; c < 8; ++c)
                    hp[c] = __floats2half2_rn(o[i][2 * c], o[i][2 * c + 1]);
                float4* outp = (float4*)(qq16 + (size_t)r * 256 + cg * 64 + fc * 16);
                outp[0] = ((float4*)hp)[0];
                outp[1] = ((float4*)hp)[1];
            }
        }
    } else {
        // --- hist role: in-degree histogram ---
        int e = (bid - KQB) * 256 + threadIdx.x;
        if (e < E) atomicAdd(&counts[dst[e]], 1);
    }
}

// K2a: per-1024-chunk exclusive scan of counts -> rowptr, block totals -> bsum.
__global__ __launch_bounds__(256) void scan1_kernel(
    const int* __restrict__ counts, int* __restrict__ rowptr,
    int* __restrict__ bsum, int N)
{
    __shared__ int sd[256];
    int base = blockIdx.x * 1024;
    int t = threadIdx.x;
    int c[4];
    int s = 0;
#pragma unroll
    for (int i = 0; i < 4; ++i) {
        int idx = base + t * 4 + i;
        c[i] = (idx < N) ? counts[idx] : 0;
        s += c[i];
    }
    sd[t] = s;
    __syncthreads();
    for (int off = 1; off < 256; off <<= 1) {
        int v = (t >= off) ? sd[t - off] : 0;
        __syncthreads();
        sd[t] += v;
        __syncthreads();
    }
    int ex = sd[t] - s;
#pragma unroll
    for (int i = 0; i < 4; ++i) {
        int idx = base + t * 4 + i;
        if (idx < N) rowptr[idx] = ex;
        ex += c[i];
    }
    if (t == 255) bsum[blockIdx.x] = sd[255];
}

// K2b: single-block exclusive scan of bsum (NBLK <= 256).
__global__ __launch_bounds__(256) void scan2_kernel(int* __restrict__ bsum, int NBLK)
{
    __shared__ int sd[256];
    int t = threadIdx.x;
    int v = (t < NBLK) ? bsum[t] : 0;
    sd[t] = v;
    __syncthreads();
    for (int off = 1; off < 256; off <<= 1) {
        int u = (t >= off) ? sd[t - off] : 0;
        __syncthreads();
        sd[t] += u;
        __syncthreads();
    }
    if (t < NBLK) bsum[t] = sd[t] - v;
}

// K2c: add chunk offsets.
__global__ __launch_bounds__(256) void scan3_kernel(
    int* __restrict__ rowptr, const int* __restrict__ bsum, int N)
{
    int i = blockIdx.x * 256 + threadIdx.x;
    if (i < N) rowptr[i] += bsum[i >> 10];
}

// K3: scatter-lite: CSR slot via atomic, 4B payload (src id only).
__global__ __launch_bounds__(256) void scatter_kernel(
    const int* __restrict__ src, const int* __restrict__ dst,
    int* __restrict__ rowptr, int* __restrict__ srcs, int E)
{
    int e = blockIdx.x * 256 + threadIdx.x;
    if (e < E) {
        int s = src[e];
        int p = atomicAdd(&rowptr[dst[e]], 1);
        srcs[p] = s;
    }
}

// ---- DPP 64-lane add reduce (VALU pipe, no LDS). Lane 63 holds the sum. ----
__device__ __forceinline__ float dpp_reduce_add64(float x) {
    float s = x, t;
    t = __int_as_float(__builtin_amdgcn_update_dpp(0, __float_as_int(s), 0x111, 0xf, 0xf, true)); s += t; // row_shr:1
    t = __int_as_float(__builtin_amdgcn_update_dpp(0, __float_as_int(s), 0x112, 0xf, 0xf, true)); s += t; // row_shr:2
    t = __int_as_float(__builtin_amdgcn_update_dpp(0, __float_as_int(s), 0x114, 0xf, 0xf, true)); s += t; // row_shr:4
    t = __int_as_float(__builtin_amdgcn_update_dpp(0, __float_as_int(s), 0x118, 0xf, 0xf, true)); s += t; // row_shr:8
    t = __int_as_float(__builtin_amdgcn_update_dpp(0, __float_as_int(s), 0x142, 0xf, 0xf, true)); s += t; // row_bcast:15
    t = __int_as_float(__builtin_amdgcn_update_dpp(0, __float_as_int(s), 0x143, 0xf, 0xf, true)); s += t; // row_bcast:31
    return s;
}

__device__ __forceinline__ float uniform_lane63(float x) {
    return __int_as_float(__builtin_amdgcn_readlane(__float_as_int(x), 63));
}

// K4: fused score + aggregate over CSR rows. One wave per node; lane = feature.
// Per record: hv = h[src][lane] (one gather, reused for dot AND accumulate);
// e_h = sum_lanes hv * qv_h (DPP reduce); w_h = exp2(e_h) (log2e folded into
// qq); weights are wave-uniform (SGPR) -> scalar-fma accumulate.
__device__ __forceinline__ void agg_one(
    float hv, float qv0, float qv1, float qv2, float qv3,
    float& a0, float& a1, float& a2, float& a3,
    float& z0, float& z1, float& z2, float& z3)
{
    float e0 = dpp_reduce_add64(hv * qv0);
    float e1 = dpp_reduce_add64(hv * qv1);
    float e2 = dpp_reduce_add64(hv * qv2);
    float e3 = dpp_reduce_add64(hv * qv3);
    float w0 = uniform_lane63(__builtin_amdgcn_exp2f(e0));
    float w1 = uniform_lane63(__builtin_amdgcn_exp2f(e1));
    float w2 = uniform_lane63(__builtin_amdgcn_exp2f(e2));
    float w3 = uniform_lane63(__builtin_amdgcn_exp2f(e3));
    a0 = fmaf(w0, hv, a0); z0 += w0;
    a1 = fmaf(w1, hv, a1); z1 += w1;
    a2 = fmaf(w2, hv, a2); z2 += w2;
    a3 = fmaf(w3, hv, a3); z3 += w3;
}

__global__ __launch_bounds__(256) void aggregate_kernel(
    const int* __restrict__ rowend, const int* __restrict__ srcs,
    const __half* __restrict__ qq16, const float* __restrict__ h,
    float* __restrict__ hn, int N)
{
    int lane = threadIdx.x & 63;
    int n = blockIdx.x * 4 + (threadIdx.x >> 6);
    if (n >= N) return;
    int end   = rowend[n];
    int start = (n == 0) ? 0 : rowend[n - 1];

    const __half* qqr = qq16 + (size_t)n * 256 + lane;
    float qv0 = __half2float(qqr[0]);
    float qv1 = __half2float(qqr[64]);
    float qv2 = __half2float(qqr[128]);
    float qv3 = __half2float(qqr[192]);

    float a0 = 0.f, a1 = 0.f, a2 = 0.f, a3 = 0.f;
    float z0 = 0.f, z1 = 0.f, z2 = 0.f, z3 = 0.f;
    const float* hl = h + lane;

    int i = start;
    for (; i + 3 < end; i += 4) {
        int s0 = srcs[i], s1 = srcs[i + 1], s2 = srcs[i + 2], s3 = srcs[i + 3];
        float hv0 = hl[(size_t)s0 * FDIM];
        float hv1 = hl[(size_t)s1 * FDIM];
        float hv2 = hl[(size_t)s2 * FDIM];
        float hv3 = hl[(size_t)s3 * FDIM];
        agg_one(hv0, qv0, qv1, qv2, qv3, a0, a1, a2, a3, z0, z1, z2, z3);
        agg_one(hv1, qv0, qv1, qv2, qv3, a0, a1, a2, a3, z0, z1, z2, z3);
        agg_one(hv2, qv0, qv1, qv2, qv3, a0, a1, a2, a3, z0, z1, z2, z3);
        agg_one(hv3, qv0, qv1, qv2, qv3, a0, a1, a2, a3, z0, z1, z2, z3);
    }
    for (; i < end; ++i) {
        int s0 = srcs[i];
        float hv0 = hl[(size_t)s0 * FDIM];
        agg_one(hv0, qv0, qv1, qv2, qv3, a0, a1, a2, a3, z0, z1, z2, z3);
    }

    float* outr = hn + (size_t)n * (NHEADS * FDIM);
    if (end > start) {
        outr[lane]             = a0 / z0;
        outr[FDIM + lane]      = a1 / z1;
        outr[2 * FDIM + lane]  = a2 / z2;
        outr[3 * FDIM + lane]  = a3 / z3;
    } else {
        outr[lane] = 0.f;
        outr[FDIM + lane] = 0.f;
        outr[2 * FDIM + lane] = 0.f;
        outr[3 * FDIM + lane] = 0.f;
    }
}

// K5: out = hn @ W + b, IN PLACE (hn == out == d_out). Thread = 4 rows x 16 cols.
// In-place safe: the 4 threads sharing a row-group are consecutive lanes of one
// wave, so all row reads complete before any store (lockstep).
__global__ __launch_bounds__(256) void out_kernel(
    const float* hn, const float* __restrict__ W,
    const float* __restrict__ b, float* out, int R)
{
    __shared__ float sW[FDIM * FDIM];
    __shared__ float sb[FDIM];
    for (int i = threadIdx.x; i < FDIM * FDIM; i += 256) sW[i] = W[i];
    if (threadIdx.x < FDIM) sb[threadIdx.x] = b[threadIdx.x];
    __syncthreads();
    int cg = threadIdx.x & 3;
    int rg = threadIdx.x >> 2;
    long base = (long)blockIdx.x * 256 + rg * 4;
    const float4* sW4 = (const float4*)sW;
    const float4* hn4 = (const float4*)hn;
    float acc[4][16];
#pragma unroll
    for (int i = 0; i < 4; ++i)
#pragma unroll
        for (int c = 0; c < 16; ++c) acc[i][c] = sb[cg * 16 + c];

    for (int fs = 0; fs < FDIM; fs += 4) {
        float4 hv[4];
#pragma unroll
        for (int i = 0; i < 4; ++i) {
            long r = base + i; if (r >= R) r = R - 1;
            hv[i] = hn4[r * 16 + (fs >> 2)];
        }
#pragma unroll
        for (int fi = 0; fi < 4; ++fi) {
            int f = fs + fi;
            float4 w0 = sW4[f * 16 + cg * 4 + 0];
            float4 w1 = sW4[f * 16 + cg * 4 + 1];
            float4 w2 = sW4[f * 16 + cg * 4 + 2];
            float4 w3 = sW4[f * 16 + cg * 4 + 3];
#pragma unroll
            for (int i = 0; i < 4; ++i) {
                float hvf = (&hv[i].x)[fi];
                acc[i][0]  = fmaf(hvf, w0.x, acc[i][0]);
                acc[i][1]  = fmaf(hvf, w0.y, acc[i][1]);
                acc[i][2]  = fmaf(hvf, w0.z, acc[i][2]);
                acc[i][3]  = fmaf(hvf, w0.w, acc[i][3]);
                acc[i][4]  = fmaf(hvf, w1.x, acc[i][4]);
                acc[i][5]  = fmaf(hvf, w1.y, acc[i][5]);
                acc[i][6]  = fmaf(hvf, w1.z, acc[i][6]);
                acc[i][7]  = fmaf(hvf, w1.w, acc[i][7]);
                acc[i][8]  = fmaf(hvf, w2.x, acc[i][8]);
                acc[i][9]  = fmaf(hvf, w2.y, acc[i][9]);
                acc[i][10] = fmaf(hvf, w2.z, acc[i][10]);
                acc[i][11] = fmaf(hvf, w2.w, acc[i][11]);
                acc[i][12] = fmaf(hvf, w3.x, acc[i][12]);
                acc[i][13] = fmaf(hvf, w3.y, acc[i][13]);
                acc[i][14] = fmaf(hvf, w3.z, acc[i][14]);
                acc[i][15] = fmaf(hvf, w3.w, acc[i][15]);
            }
        }
    }
#pragma unroll
    for (int i = 0; i < 4; ++i) {
        long r = base + i;
        if (r >= R) continue;
        float4* o = (float4*)(out + (size_t)r * FDIM + cg * 16);
#pragma unroll
        for (int c4 = 0; c4 < 4; ++c4)
            o[c4] = make_float4(acc[i][c4*4], acc[i][c4*4+1], acc[i][c4*4+2], acc[i][c4*4+3]);
    }
}

extern "C" void kernel_launch(void* const* d_in, const int* in_sizes, int n_in,
                              void* d_out, int out_size, void* d_ws, size_t ws_size,
                              hipStream_t stream) {
    const float* h   = (const float*)d_in[0];
    const int*   src = (const int*)d_in[1];
    const int*   dst = (const int*)d_in[2];
    const float* Wk  = (const float*)d_in[3];
    const float* Wq  = (const float*)d_in[4];
    const float* W   = (const float*)d_in[5];
    const float* b   = (const float*)d_in[6];
    float* out = (float*)d_out;

    const int N = in_sizes[0] / FDIM;   // 100000
    const int E = in_sizes[1];          // 1600000

    // Workspace: qq16[N*256 h] (51.2MB), srcs[E int] (6.4MB),
    //            counts[N], rowptr[N], bsum[256].  (~58.4 MB)
    __half* qq16 = (__half*)d_ws;
    int* srcs   = (int*)(qq16 + (size_t)N * 256);
    int* counts = srcs + E;
    int* rowptr = counts + N;
    int* bsum   = rowptr + N;

    const int NBLK = (N + 1023) / 1024;            // 98
    const int KQB  = (N + 127) / 128;              // 782
    const int HIB  = (E + 255) / 256;              // 6250

    hipMemsetAsync(counts, 0, (size_t)N * sizeof(int), stream);

    fused_pre_kernel<<<KQB + HIB, 256, 0, stream>>>(
        h, Wk, Wq, qq16, dst, counts, N, E, KQB);
    scan1_kernel<<<NBLK, 256, 0, stream>>>(counts, rowptr, bsum, N);
    scan2_kernel<<<1, 256, 0, stream>>>(bsum, NBLK);
    scan3_kernel<<<(N + 255) / 256, 256, 0, stream>>>(rowptr, bsum, N);
    scatter_kernel<<<HIB, 256, 0, stream>>>(src, dst, rowptr, srcs, E);
    aggregate_kernel<<<(N + 3) / 4, 256, 0, stream>>>(
        rowptr, srcs, qq16, h, out, N);
    out_kernel<<<(N * NHEADS + 255) / 256, 256, 0, stream>>>(out, W, b, out, N * NHEADS);
}

// Round 4
// 560.452 us; speedup vs baseline: 1.0922x; 1.0922x over previous
//
#include <hip/hip_runtime.h>
#include <hip/hip_fp16.h>
#include <math.h>

// GAT layer: N=100000, E=1600000, F=64, H=4 (Dh=16).
//
// Pipeline: fused {kq GEMM (fp16 out, log2e folded into Wk) | h->fp16 |
// in-degree hist} -> scan -> scatter-lite (srcs[p]=src, 4B payload) ->
// score (CSR row-walk: q-row loaded once per node, k[src] gathered, fp16 dot,
// w=exp2(e'), bf16 weights written STREAMING in CSR order) ->
// gather-aggregate (bf16 weight decode = shl/mask, fp16 h gather) ->
// in-place out GEMM.
//
// Why this split (R0-R3 lessons):
//  - per-edge dot must be edge/head-parallel (R3's in-aggregate DPP reduce was
//    VALU-bound at 93%: ~70 inst/record).
//  - scoring after CSR build makes warr writes sequential (R2's scattered
//    record write was 150 MB for 32 MB payload) and q-gathers per-node.
//  - aggregate gathers fp16 h16 (f32 h doubled FETCH: 209 vs 97 MB).
//  - bf16 weights: 8-bit exponent covers exp range (e*log2e up to +-36);
//    decode is 1 shl + 1 mask per pair, no trans ops.

#define FDIM 64
#define NHEADS 4

// ---- K1: multi-role kernel: [0,KQB) kq | [KQB,KQB+H2B) h2half | rest hist ----
__global__ __launch_bounds__(256) void fused_pre_kernel(
    const float* __restrict__ h, const float* __restrict__ Wk,
    const float* __restrict__ Wq, __half* __restrict__ k16,
    __half* __restrict__ q16, __half* __restrict__ h16,
    const int* __restrict__ dst, int* __restrict__ counts,
    int N, int E, int KQB, int H2B)
{
    __shared__ float sWk[FDIM * FDIM];   // Wk * log2(e): dot yields e*log2e
    __shared__ float sWq[FDIM * FDIM];
    int bid = blockIdx.x;
    if (bid < KQB) {
        for (int i = threadIdx.x; i < FDIM * FDIM; i += 256) {
            sWk[i] = Wk[i] * 1.4426950408889634f;
            sWq[i] = Wq[i];
        }
        __syncthreads();
        int cg = threadIdx.x & 3;
        int rg = threadIdx.x >> 2;
        long base = (long)bid * 128 + rg * 2;
        const float4* sWk4 = (const float4*)sWk;
        const float4* sWq4 = (const float4*)sWq;
        const float4* h4 = (const float4*)h;
        float acck[2][16], accq[2][16];
#pragma unroll
        for (int i = 0; i < 2; ++i)
#pragma unroll
            for (int c = 0; c < 16; ++c) { acck[i][c] = 0.f; accq[i][c] = 0.f; }

        for (int fs = 0; fs < FDIM; fs += 4) {
            float4 hv[2];
#pragma unroll
            for (int i = 0; i < 2; ++i) {
                long r = base + i; if (r >= N) r = N - 1;
                hv[i] = h4[r * 16 + (fs >> 2)];
            }
#pragma unroll
            for (int fi = 0; fi < 4; ++fi) {
                int f = fs + fi;
                float4 wk0 = sWk4[f * 16 + cg * 4 + 0];
                float4 wk1 = sWk4[f * 16 + cg * 4 + 1];
                float4 wk2 = sWk4[f * 16 + cg * 4 + 2];
                float4 wk3 = sWk4[f * 16 + cg * 4 + 3];
                float4 wq0 = sWq4[f * 16 + cg * 4 + 0];
                float4 wq1 = sWq4[f * 16 + cg * 4 + 1];
                float4 wq2 = sWq4[f * 16 + cg * 4 + 2];
                float4 wq3 = sWq4[f * 16 + cg * 4 + 3];
#pragma unroll
                for (int i = 0; i < 2; ++i) {
                    float hvf = (&hv[i].x)[fi];
                    acck[i][0]  = fmaf(hvf, wk0.x, acck[i][0]);
                    acck[i][1]  = fmaf(hvf, wk0.y, acck[i][1]);
                    acck[i][2]  = fmaf(hvf, wk0.z, acck[i][2]);
                    acck[i][3]  = fmaf(hvf, wk0.w, acck[i][3]);
                    acck[i][4]  = fmaf(hvf, wk1.x, acck[i][4]);
                    acck[i][5]  = fmaf(hvf, wk1.y, acck[i][5]);
                    acck[i][6]  = fmaf(hvf, wk1.z, acck[i][6]);
                    acck[i][7]  = fmaf(hvf, wk1.w, acck[i][7]);
                    acck[i][8]  = fmaf(hvf, wk2.x, acck[i][8]);
                    acck[i][9]  = fmaf(hvf, wk2.y, acck[i][9]);
                    acck[i][10] = fmaf(hvf, wk2.z, acck[i][10]);
                    acck[i][11] = fmaf(hvf, wk2.w, acck[i][11]);
                    acck[i][12] = fmaf(hvf, wk3.x, acck[i][12]);
                    acck[i][13] = fmaf(hvf, wk3.y, acck[i][13]);
                    acck[i][14] = fmaf(hvf, wk3.z, acck[i][14]);
                    acck[i][15] = fmaf(hvf, wk3.w, acck[i][15]);
                    accq[i][0]  = fmaf(hvf, wq0.x, accq[i][0]);
                    accq[i][1]  = fmaf(hvf, wq0.y, accq[i][1]);
                    accq[i][2]  = fmaf(hvf, wq0.z, accq[i][2]);
                    accq[i][3]  = fmaf(hvf, wq0.w, accq[i][3]);
                    accq[i][4]  = fmaf(hvf, wq1.x, accq[i][4]);
                    accq[i][5]  = fmaf(hvf, wq1.y, accq[i][5]);
                    accq[i][6]  = fmaf(hvf, wq1.z, accq[i][6]);
                    accq[i][7]  = fmaf(hvf, wq1.w, accq[i][7]);
                    accq[i][8]  = fmaf(hvf, wq2.x, accq[i][8]);
                    accq[i][9]  = fmaf(hvf, wq2.y, accq[i][9]);
                    accq[i][10] = fmaf(hvf, wq2.z, accq[i][10]);
                    accq[i][11] = fmaf(hvf, wq2.w, accq[i][11]);
                    accq[i][12] = fmaf(hvf, wq3.x, accq[i][12]);
                    accq[i][13] = fmaf(hvf, wq3.y, accq[i][13]);
                    accq[i][14] = fmaf(hvf, wq3.z, accq[i][14]);
                    accq[i][15] = fmaf(hvf, wq3.w, accq[i][15]);
                }
            }
        }
#pragma unroll
        for (int i = 0; i < 2; ++i) {
            long r = base + i;
            if (r >= N) continue;
            __half2 hk[8], hq[8];
#pragma unroll
            for (int c = 0; c < 8; ++c) {
                hk[c] = __floats2half2_rn(acck[i][2 * c], acck[i][2 * c + 1]);
                hq[c] = __floats2half2_rn(accq[i][2 * c], accq[i][2 * c + 1]);
            }
            float4* kout = (float4*)(k16 + (size_t)r * FDIM + cg * 16);
            float4* qout = (float4*)(q16 + (size_t)r * FDIM + cg * 16);
            kout[0] = ((float4*)hk)[0]; kout[1] = ((float4*)hk)[1];
            qout[0] = ((float4*)hq)[0]; qout[1] = ((float4*)hq)[1];
        }
    } else if (bid < KQB + H2B) {
        // --- h2half role: h -> fp16, 8 elems/thread ---
        int i = (bid - KQB) * 256 + threadIdx.x;
        size_t base = (size_t)i * 8;
        size_t total = (size_t)N * FDIM;
        if (base >= total) return;
        const float4* h4 = (const float4*)(h + base);
        float4 a = h4[0], b2 = h4[1];
        __half2 o[4] = { __floats2half2_rn(a.x, a.y), __floats2half2_rn(a.z, a.w),
                         __floats2half2_rn(b2.x, b2.y), __floats2half2_rn(b2.z, b2.w) };
        *(float4*)(h16 + base) = *(float4*)o;
    } else {
        // --- hist role: in-degree histogram ---
        int e = (bid - KQB - H2B) * 256 + threadIdx.x;
        if (e < E) atomicAdd(&counts[dst[e]], 1);
    }
}

// K2a: per-1024-chunk exclusive scan of counts -> rowptr, block totals -> bsum.
__global__ __launch_bounds__(256) void scan1_kernel(
    const int* __restrict__ counts, int* __restrict__ rowptr,
    int* __restrict__ bsum, int N)
{
    __shared__ int sd[256];
    int base = blockIdx.x * 1024;
    int t = threadIdx.x;
    int c[4];
    int s = 0;
#pragma unroll
    for (int i = 0; i < 4; ++i) {
        int idx = base + t * 4 + i;
        c[i] = (idx < N) ? counts[idx] : 0;
        s += c[i];
    }
    sd[t] = s;
    __syncthreads();
    for (int off = 1; off < 256; off <<= 1) {
        int v = (t >= off) ? sd[t - off] : 0;
        __syncthreads();
        sd[t] += v;
        __syncthreads();
    }
    int ex = sd[t] - s;
#pragma unroll
    for (int i = 0; i < 4; ++i) {
        int idx = base + t * 4 + i;
        if (idx < N) rowptr[idx] = ex;
        ex += c[i];
    }
    if (t == 255) bsum[blockIdx.x] = sd[255];
}

// K2b: single-block exclusive scan of bsum (NBLK <= 256).
__global__ __launch_bounds__(256) void scan2_kernel(int* __restrict__ bsum, int NBLK)
{
    __shared__ int sd[256];
    int t = threadIdx.x;
    int v = (t < NBLK) ? bsum[t] : 0;
    sd[t] = v;
    __syncthreads();
    for (int off = 1; off < 256; off <<= 1) {
        int u = (t >= off) ? sd[t - off] : 0;
        __syncthreads();
        sd[t] += u;
        __syncthreads();
    }
    if (t < NBLK) bsum[t] = sd[t] - v;
}

// K2c: add chunk offsets.
__global__ __launch_bounds__(256) void scan3_kernel(
    int* __restrict__ rowptr, const int* __restrict__ bsum, int N)
{
    int i = blockIdx.x * 256 + threadIdx.x;
    if (i < N) rowptr[i] += bsum[i >> 10];
}

// K3: scatter-lite: CSR slot via atomic, 4B payload (src id only).
// After this kernel, rowptr[n] == row end (rowend semantics).
__global__ __launch_bounds__(256) void scatter_kernel(
    const int* __restrict__ src, const int* __restrict__ dst,
    int* __restrict__ rowptr, int* __restrict__ srcs, int E)
{
    int e = blockIdx.x * 256 + threadIdx.x;
    if (e < E) {
        int s = src[e];
        int p = atomicAdd(&rowptr[dst[e]], 1);
        srcs[p] = s;
    }
}

__device__ __forceinline__ float dot16(const float4* kk, const float* qf) {
    const __half2* kh = (const __half2*)kk;
    float acc = 0.f;
#pragma unroll
    for (int j = 0; j < 8; ++j) {
        float2 kf = __half22float2(kh[j]);
        acc = fmaf(kf.x, qf[2 * j], acc);
        acc = fmaf(kf.y, qf[2 * j + 1], acc);
    }
    return acc;
}

__device__ __forceinline__ unsigned short bf16_rne(float x) {
    unsigned int u = __float_as_uint(x);
    return (unsigned short)((u + 0x7fffu + ((u >> 16) & 1u)) >> 16);
}

// K4: score, CSR row-walk. 4-lane group = node (lane hh = head). q-row loaded
// once per node; per record gather k16[src] (32B/lane), fp16 dot, w=exp2(e'),
// bf16 weight stored STREAMING at warr16[4i+hh] (CSR order, no write amp,
// no atomics). 2-deep unroll overlaps the two k gathers.
__global__ __launch_bounds__(256) void score_kernel(
    const int* __restrict__ rowend, const int* __restrict__ srcs,
    const __half* __restrict__ k16, const __half* __restrict__ q16,
    unsigned short* __restrict__ warr16, int N)
{
    int hh = threadIdx.x & 3;
    int n = blockIdx.x * 64 + (threadIdx.x >> 2);
    if (n >= N) return;
    int end   = rowend[n];
    int start = (n == 0) ? 0 : rowend[n - 1];

    const float4* qp = (const float4*)(q16 + (size_t)n * FDIM + hh * 16);
    float4 qv[2] = { qp[0], qp[1] };
    const __half2* qh = (const __half2*)qv;
    float qf[16];
#pragma unroll
    for (int j = 0; j < 8; ++j) {
        float2 f = __half22float2(qh[j]);
        qf[2 * j] = f.x;
        qf[2 * j + 1] = f.y;
    }

    int i = start;
    for (; i + 1 < end; i += 2) {
        int s0 = srcs[i], s1 = srcs[i + 1];
        const float4* kp0 = (const float4*)(k16 + (size_t)s0 * FDIM + hh * 16);
        const float4* kp1 = (const float4*)(k16 + (size_t)s1 * FDIM + hh * 16);
        float4 ka[2] = { kp0[0], kp0[1] };
        float4 kb[2] = { kp1[0], kp1[1] };
        float w0 = __builtin_amdgcn_exp2f(dot16(ka, qf));
        float w1 = __builtin_amdgcn_exp2f(dot16(kb, qf));
        warr16[(size_t)i * 4 + hh] = bf16_rne(w0);
        warr16[(size_t)(i + 1) * 4 + hh] = bf16_rne(w1);
    }
    if (i < end) {
        int s0 = srcs[i];
        const float4* kp0 = (const float4*)(k16 + (size_t)s0 * FDIM + hh * 16);
        float4 ka[2] = { kp0[0], kp0[1] };
        float w0 = __builtin_amdgcn_exp2f(dot16(ka, qf));
        warr16[(size_t)i * 4 + hh] = bf16_rne(w0);
    }
}

// K5: gather aggregation over CSR rows. One wave per node; lane = feature.
// bf16 weight decode = shl/mask (no trans, no mul); fp16 h gather; 4-deep
// unroll to pipeline the srcs->gather chain. Writes hn (= d_out).
__global__ __launch_bounds__(256) void aggregate_kernel(
    const int* __restrict__ rowend, const uint2* __restrict__ wp,
    const int* __restrict__ srcs, const __half* __restrict__ h16,
    float* __restrict__ hn, int N)
{
    int lane = threadIdx.x & 63;
    int n = blockIdx.x * 4 + (threadIdx.x >> 6);
    if (n >= N) return;
    int end   = rowend[n];
    int start = (n == 0) ? 0 : rowend[n - 1];
    float a0 = 0.f, a1 = 0.f, a2 = 0.f, a3 = 0.f;
    float z0 = 0.f, z1 = 0.f, z2 = 0.f, z3 = 0.f;

#define AGG_REC(WW, HV)                                                  \
    {   float w0_ = __uint_as_float((WW).x << 16);                       \
        float w1_ = __uint_as_float((WW).x & 0xffff0000u);               \
        float w2_ = __uint_as_float((WW).y << 16);                       \
        float w3_ = __uint_as_float((WW).y & 0xffff0000u);               \
        a0 = fmaf(w0_, (HV), a0); z0 += w0_;                             \
        a1 = fmaf(w1_, (HV), a1); z1 += w1_;                             \
        a2 = fmaf(w2_, (HV), a2); z2 += w2_;                             \
        a3 = fmaf(w3_, (HV), a3); z3 += w3_; }

    int i = start;
    for (; i + 3 < end; i += 4) {
        uint2 ww0 = wp[i], ww1 = wp[i + 1], ww2 = wp[i + 2], ww3 = wp[i + 3];
        int s0 = srcs[i], s1 = srcs[i + 1], s2 = srcs[i + 2], s3 = srcs[i + 3];
        float hv0 = __half2float(h16[(size_t)s0 * FDIM + lane]);
        float hv1 = __half2float(h16[(size_t)s1 * FDIM + lane]);
        float hv2 = __half2float(h16[(size_t)s2 * FDIM + lane]);
        float hv3 = __half2float(h16[(size_t)s3 * FDIM + lane]);
        AGG_REC(ww0, hv0);
        AGG_REC(ww1, hv1);
        AGG_REC(ww2, hv2);
        AGG_REC(ww3, hv3);
    }
    for (; i < end; ++i) {
        uint2 ww0 = wp[i];
        int s0 = srcs[i];
        float hv0 = __half2float(h16[(size_t)s0 * FDIM + lane]);
        AGG_REC(ww0, hv0);
    }
#undef AGG_REC

    float* outr = hn + (size_t)n * (NHEADS * FDIM);
    if (end > start) {
        outr[lane]             = a0 / z0;
        outr[FDIM + lane]      = a1 / z1;
        outr[2 * FDIM + lane]  = a2 / z2;
        outr[3 * FDIM + lane]  = a3 / z3;
    } else {
        outr[lane] = 0.f;
        outr[FDIM + lane] = 0.f;
        outr[2 * FDIM + lane] = 0.f;
        outr[3 * FDIM + lane] = 0.f;
    }
}

// K6: out = hn @ W + b, IN PLACE (hn == out == d_out). Thread = 4 rows x 16 cols.
// In-place safe: the 4 threads sharing a row-group are consecutive lanes of one
// wave, so all row reads complete before any store (lockstep).
__global__ __launch_bounds__(256) void out_kernel(
    const float* hn, const float* __restrict__ W,
    const float* __restrict__ b, float* out, int R)
{
    __shared__ float sW[FDIM * FDIM];
    __shared__ float sb[FDIM];
    for (int i = threadIdx.x; i < FDIM * FDIM; i += 256) sW[i] = W[i];
    if (threadIdx.x < FDIM) sb[threadIdx.x] = b[threadIdx.x];
    __syncthreads();
    int cg = threadIdx.x & 3;
    int rg = threadIdx.x >> 2;
    long base = (long)blockIdx.x * 256 + rg * 4;
    const float4* sW4 = (const float4*)sW;
    const float4* hn4 = (const float4*)hn;
    float acc[4][16];
#pragma unroll
    for (int i = 0; i < 4; ++i)
#pragma unroll
        for (int c = 0; c < 16; ++c) acc[i][c] = sb[cg * 16 + c];

    for (int fs = 0; fs < FDIM; fs += 4) {
        float4 hv[4];
#pragma unroll
        for (int i = 0; i < 4; ++i) {
            long r = base + i; if (r >= R) r = R - 1;
            hv[i] = hn4[r * 16 + (fs >> 2)];
        }
#pragma unroll
        for (int fi = 0; fi < 4; ++fi) {
            int f = fs + fi;
            float4 w0 = sW4[f * 16 + cg * 4 + 0];
            float4 w1 = sW4[f * 16 + cg * 4 + 1];
            float4 w2 = sW4[f * 16 + cg * 4 + 2];
            float4 w3 = sW4[f * 16 + cg * 4 + 3];
#pragma unroll
            for (int i = 0; i < 4; ++i) {
                float hvf = (&hv[i].x)[fi];
                acc[i][0]  = fmaf(hvf, w0.x, acc[i][0]);
                acc[i][1]  = fmaf(hvf, w0.y, acc[i][1]);
                acc[i][2]  = fmaf(hvf, w0.z, acc[i][2]);
                acc[i][3]  = fmaf(hvf, w0.w, acc[i][3]);
                acc[i][4]  = fmaf(hvf, w1.x, acc[i][4]);
                acc[i][5]  = fmaf(hvf, w1.y, acc[i][5]);
                acc[i][6]  = fmaf(hvf, w1.z, acc[i][6]);
                acc[i][7]  = fmaf(hvf, w1.w, acc[i][7]);
                acc[i][8]  = fmaf(hvf, w2.x, acc[i][8]);
                acc[i][9]  = fmaf(hvf, w2.y, acc[i][9]);
                acc[i][10] = fmaf(hvf, w2.z, acc[i][10]);
                acc[i][11] = fmaf(hvf, w2.w, acc[i][11]);
                acc[i][12] = fmaf(hvf, w3.x, acc[i][12]);
                acc[i][13] = fmaf(hvf, w3.y, acc[i][13]);
                acc[i][14] = fmaf(hvf, w3.z, acc[i][14]);
                acc[i][15] = fmaf(hvf, w3.w, acc[i][15]);
            }
        }
    }
#pragma unroll
    for (int i = 0; i < 4; ++i) {
        long r = base + i;
        if (r >= R) continue;
        float4* o = (float4*)(out + (size_t)r * FDIM + cg * 16);
#pragma unroll
        for (int c4 = 0; c4 < 4; ++c4)
            o[c4] = make_float4(acc[i][c4*4], acc[i][c4*4+1], acc[i][c4*4+2], acc[i][c4*4+3]);
    }
}

extern "C" void kernel_launch(void* const* d_in, const int* in_sizes, int n_in,
                              void* d_out, int out_size, void* d_ws, size_t ws_size,
                              hipStream_t stream) {
    const float* h   = (const float*)d_in[0];
    const int*   src = (const int*)d_in[1];
    const int*   dst = (const int*)d_in[2];
    const float* Wk  = (const float*)d_in[3];
    const float* Wq  = (const float*)d_in[4];
    const float* W   = (const float*)d_in[5];
    const float* b   = (const float*)d_in[6];
    float* out = (float*)d_out;

    const int N = in_sizes[0] / FDIM;   // 100000
    const int E = in_sizes[1];          // 1600000

    // Workspace: k16[N*64 h] 12.8MB, q16 12.8MB, h16 12.8MB,
    //            warr16[E*4 ushort] 12.8MB, srcs[E int] 6.4MB,
    //            counts[N], rowptr[N], bsum[256].  (~58.4 MB)
    __half* k16 = (__half*)d_ws;
    __half* q16 = k16 + (size_t)N * FDIM;
    __half* h16 = q16 + (size_t)N * FDIM;
    unsigned short* warr16 = (unsigned short*)(h16 + (size_t)N * FDIM);
    int* srcs   = (int*)(warr16 + (size_t)E * 4);
    int* counts = srcs + E;
    int* rowptr = counts + N;
    int* bsum   = rowptr + N;

    const int NBLK = (N + 1023) / 1024;            // 98
    const int KQB  = (N + 127) / 128;              // 782
    const int H2B  = ((N * FDIM / 8) + 255) / 256; // 3125
    const int HIB  = (E + 255) / 256;              // 6250

    hipMemsetAsync(counts, 0, (size_t)N * sizeof(int), stream);

    fused_pre_kernel<<<KQB + H2B + HIB, 256, 0, stream>>>(
        h, Wk, Wq, k16, q16, h16, dst, counts, N, E, KQB, H2B);
    scan1_kernel<<<NBLK, 256, 0, stream>>>(counts, rowptr, bsum, N);
    scan2_kernel<<<1, 256, 0, stream>>>(bsum, NBLK);
    scan3_kernel<<<(N + 255) / 256, 256, 0, stream>>>(rowptr, bsum, N);
    scatter_kernel<<<HIB, 256, 0, stream>>>(src, dst, rowptr, srcs, E);
    score_kernel<<<(N + 63) / 64, 256, 0, stream>>>(
        rowptr, srcs, k16, q16, warr16, N);
    aggregate_kernel<<<(N + 3) / 4, 256, 0, stream>>>(
        rowptr, (const uint2*)warr16, srcs, h16, out, N);
    out_kernel<<<(N * NHEADS + 255) / 256, 256, 0, stream>>>(out, W, b, out, N * NHEADS);
}

// Round 6
// 493.644 us; speedup vs baseline: 1.2400x; 1.1353x over previous
//
#include <hip/hip_runtime.h>
#include <hip/hip_fp16.h>
#include <math.h>

// GAT layer: N=100000, E=1600000, F=64, H=4 (Dh=16).
//
// Pipeline: fused {kq GEMM (fp16, log2e in Wk) | h->fp16 | in-degree hist}
// -> scan (rowptr = exclusive starts, immutable) ->
// binA: bucket edges by dst>>8 into ebuf (LDS tile sort, coalesced appends) ->
// binB: per-bucket LDS counting sort -> srcs written STREAMING in CSR order ->
// score (CSR row-walk, fp16 dot, w=exp2, bf16 warr16 streaming) ->
// gather-aggregate (bf16 decode = shl/mask, fp16 h gather) -> in-place out GEMM.
//
// R0-R4 law: any per-edge random-slot global store costs 100-150us (64B line
// dirtied per 4B payload, bounced across XCD L2s; R4 scatter: 105MB WRITE for
// 6.4MB payload). So all scattering now happens in LDS; global writes are
// coalesced streams. BCAP overflow (32-sigma for random dst) is CLAMPED:
// graceful degradation instead of OOB.

#define FDIM 64
#define NHEADS 4
#define TILE 8192
#define BCAP 6144

// ---- K1: multi-role kernel: [0,KQB) kq | [KQB,KQB+H2B) h2half | rest hist ----
__global__ __launch_bounds__(256) void fused_pre_kernel(
    const float* __restrict__ h, const float* __restrict__ Wk,
    const float* __restrict__ Wq, __half* __restrict__ k16,
    __half* __restrict__ q16, __half* __restrict__ h16,
    const int* __restrict__ dst, int* __restrict__ counts,
    int N, int E, int KQB, int H2B)
{
    __shared__ float sWk[FDIM * FDIM];   // Wk * log2(e): dot yields e*log2e
    __shared__ float sWq[FDIM * FDIM];
    int bid = blockIdx.x;
    if (bid < KQB) {
        for (int i = threadIdx.x; i < FDIM * FDIM; i += 256) {
            sWk[i] = Wk[i] * 1.4426950408889634f;
            sWq[i] = Wq[i];
        }
        __syncthreads();
        int cg = threadIdx.x & 3;
        int rg = threadIdx.x >> 2;
        long base = (long)bid * 128 + rg * 2;
        const float4* sWk4 = (const float4*)sWk;
        const float4* sWq4 = (const float4*)sWq;
        const float4* h4 = (const float4*)h;
        float acck[2][16], accq[2][16];
#pragma unroll
        for (int i = 0; i < 2; ++i)
#pragma unroll
            for (int c = 0; c < 16; ++c) { acck[i][c] = 0.f; accq[i][c] = 0.f; }

        for (int fs = 0; fs < FDIM; fs += 4) {
            float4 hv[2];
#pragma unroll
            for (int i = 0; i < 2; ++i) {
                long r = base + i; if (r >= N) r = N - 1;
                hv[i] = h4[r * 16 + (fs >> 2)];
            }
#pragma unroll
            for (int fi = 0; fi < 4; ++fi) {
                int f = fs + fi;
                float4 wk0 = sWk4[f * 16 + cg * 4 + 0];
                float4 wk1 = sWk4[f * 16 + cg * 4 + 1];
                float4 wk2 = sWk4[f * 16 + cg * 4 + 2];
                float4 wk3 = sWk4[f * 16 + cg * 4 + 3];
                float4 wq0 = sWq4[f * 16 + cg * 4 + 0];
                float4 wq1 = sWq4[f * 16 + cg * 4 + 1];
                float4 wq2 = sWq4[f * 16 + cg * 4 + 2];
                float4 wq3 = sWq4[f * 16 + cg * 4 + 3];
#pragma unroll
                for (int i = 0; i < 2; ++i) {
                    float hvf = (&hv[i].x)[fi];
                    acck[i][0]  = fmaf(hvf, wk0.x, acck[i][0]);
                    acck[i][1]  = fmaf(hvf, wk0.y, acck[i][1]);
                    acck[i][2]  = fmaf(hvf, wk0.z, acck[i][2]);
                    acck[i][3]  = fmaf(hvf, wk0.w, acck[i][3]);
                    acck[i][4]  = fmaf(hvf, wk1.x, acck[i][4]);
                    acck[i][5]  = fmaf(hvf, wk1.y, acck[i][5]);
                    acck[i][6]  = fmaf(hvf, wk1.z, acck[i][6]);
                    acck[i][7]  = fmaf(hvf, wk1.w, acck[i][7]);
                    acck[i][8]  = fmaf(hvf, wk2.x, acck[i][8]);
                    acck[i][9]  = fmaf(hvf, wk2.y, acck[i][9]);
                    acck[i][10] = fmaf(hvf, wk2.z, acck[i][10]);
                    acck[i][11] = fmaf(hvf, wk2.w, acck[i][11]);
                    acck[i][12] = fmaf(hvf, wk3.x, acck[i][12]);
                    acck[i][13] = fmaf(hvf, wk3.y, acck[i][13]);
                    acck[i][14] = fmaf(hvf, wk3.z, acck[i][14]);
                    acck[i][15] = fmaf(hvf, wk3.w, acck[i][15]);
                    accq[i][0]  = fmaf(hvf, wq0.x, accq[i][0]);
                    accq[i][1]  = fmaf(hvf, wq0.y, accq[i][1]);
                    accq[i][2]  = fmaf(hvf, wq0.z, accq[i][2]);
                    accq[i][3]  = fmaf(hvf, wq0.w, accq[i][3]);
                    accq[i][4]  = fmaf(hvf, wq1.x, accq[i][4]);
                    accq[i][5]  = fmaf(hvf, wq1.y, accq[i][5]);
                    accq[i][6]  = fmaf(hvf, wq1.z, accq[i][6]);
                    accq[i][7]  = fmaf(hvf, wq1.w, accq[i][7]);
                    accq[i][8]  = fmaf(hvf, wq2.x, accq[i][8]);
                    accq[i][9]  = fmaf(hvf, wq2.y, accq[i][9]);
                    accq[i][10] = fmaf(hvf, wq2.z, accq[i][10]);
                    accq[i][11] = fmaf(hvf, wq2.w, accq[i][11]);
                    accq[i][12] = fmaf(hvf, wq3.x, accq[i][12]);
                    accq[i][13] = fmaf(hvf, wq3.y, accq[i][13]);
                    accq[i][14] = fmaf(hvf, wq3.z, accq[i][14]);
                    accq[i][15] = fmaf(hvf, wq3.w, accq[i][15]);
                }
            }
        }
#pragma unroll
        for (int i = 0; i < 2; ++i) {
            long r = base + i;
            if (r >= N) continue;
            __half2 hk[8], hq[8];
#pragma unroll
            for (int c = 0; c < 8; ++c) {
                hk[c] = __floats2half2_rn(acck[i][2 * c], acck[i][2 * c + 1]);
                hq[c] = __floats2half2_rn(accq[i][2 * c], accq[i][2 * c + 1]);
            }
            float4* kout = (float4*)(k16 + (size_t)r * FDIM + cg * 16);
            float4* qout = (float4*)(q16 + (size_t)r * FDIM + cg * 16);
            kout[0] = ((float4*)hk)[0]; kout[1] = ((float4*)hk)[1];
            qout[0] = ((float4*)hq)[0]; qout[1] = ((float4*)hq)[1];
        }
    } else if (bid < KQB + H2B) {
        // --- h2half role: h -> fp16, 8 elems/thread ---
        int i = (bid - KQB) * 256 + threadIdx.x;
        size_t base = (size_t)i * 8;
        size_t total = (size_t)N * FDIM;
        if (base >= total) return;
        const float4* h4 = (const float4*)(h + base);
        float4 a = h4[0], b2 = h4[1];
        __half2 o[4] = { __floats2half2_rn(a.x, a.y), __floats2half2_rn(a.z, a.w),
                         __floats2half2_rn(b2.x, b2.y), __floats2half2_rn(b2.z, b2.w) };
        *(float4*)(h16 + base) = *(float4*)o;
    } else {
        // --- hist role: in-degree histogram ---
        int e = (bid - KQB - H2B) * 256 + threadIdx.x;
        if (e < E) atomicAdd(&counts[dst[e]], 1);
    }
}

// K2a: per-1024-chunk exclusive scan of counts -> rowptr, block totals -> bsum.
__global__ __launch_bounds__(256) void scan1_kernel(
    const int* __restrict__ counts, int* __restrict__ rowptr,
    int* __restrict__ bsum, int N)
{
    __shared__ int sd[256];
    int base = blockIdx.x * 1024;
    int t = threadIdx.x;
    int c[4];
    int s = 0;
#pragma unroll
    for (int i = 0; i < 4; ++i) {
        int idx = base + t * 4 + i;
        c[i] = (idx < N) ? counts[idx] : 0;
        s += c[i];
    }
    sd[t] = s;
    __syncthreads();
    for (int off = 1; off < 256; off <<= 1) {
        int v = (t >= off) ? sd[t - off] : 0;
        __syncthreads();
        sd[t] += v;
        __syncthreads();
    }
    int ex = sd[t] - s;
#pragma unroll
    for (int i = 0; i < 4; ++i) {
        int idx = base + t * 4 + i;
        if (idx < N) rowptr[idx] = ex;
        ex += c[i];
    }
    if (t == 255) bsum[blockIdx.x] = sd[255];
}

// K2b: single-block exclusive scan of bsum (NBLK <= 256).
__global__ __launch_bounds__(256) void scan2_kernel(int* __restrict__ bsum, int NBLK)
{
    __shared__ int sd[256];
    int t = threadIdx.x;
    int v = (t < NBLK) ? bsum[t] : 0;
    sd[t] = v;
    __syncthreads();
    for (int off = 1; off < 256; off <<= 1) {
        int u = (t >= off) ? sd[t - off] : 0;
        __syncthreads();
        sd[t] += u;
        __syncthreads();
    }
    if (t < NBLK) bsum[t] = sd[t] - v;
}

// K2c: add chunk offsets.
__global__ __launch_bounds__(256) void scan3_kernel(
    int* __restrict__ rowptr, const int* __restrict__ bsum, int N)
{
    int i = blockIdx.x * 256 + threadIdx.x;
    if (i < N) rowptr[i] += bsum[i >> 10];
}

// K3a: bucket-binning pass. Tile of 8192 edges -> LDS counting sort by
// bucket (dst>>8, 391 buckets) -> per-bucket coalesced append to ebuf
// (contiguous ~21-edge runs; one global atomic per bucket per tile).
// Packed entry: src<<8 | (dst&255). Appends clamped to BCAP.
__global__ __launch_bounds__(256) void binA_kernel(
    const int* __restrict__ src, const int* __restrict__ dst,
    int* __restrict__ gcnt, unsigned int* __restrict__ ebuf,
    int E, int nbuck)
{
    __shared__ unsigned int bh[512];      // hist -> cursor
    __shared__ unsigned int bstart[512];  // stable exclusive offsets
    __shared__ unsigned int bbase[512];   // global base per bucket
    __shared__ unsigned int sd[256];
    __shared__ unsigned int ebuf_l[TILE];
    int t = threadIdx.x;
    long e0 = (long)blockIdx.x * TILE;
    int cnt_tile = (int)(((long)E - e0 < (long)TILE) ? ((long)E - e0) : (long)TILE);

    bh[t] = 0; bh[t + 256] = 0;
    __syncthreads();
    // phase 1: histogram (dst only)
    for (int j = t; j < cnt_tile; j += 256)
        atomicAdd(&bh[dst[e0 + j] >> 8], 1u);
    __syncthreads();
    // phase 2: exclusive scan of 512 entries (2/thread) + global reservation
    unsigned int c0 = bh[2 * t], c1 = bh[2 * t + 1];
    unsigned int s = c0 + c1;
    sd[t] = s;
    __syncthreads();
    for (int off = 1; off < 256; off <<= 1) {
        unsigned int v = (t >= off) ? sd[t - off] : 0;
        __syncthreads();
        sd[t] += v;
        __syncthreads();
    }
    unsigned int ex = sd[t] - s;
    bh[2 * t] = ex;          bstart[2 * t] = ex;
    bh[2 * t + 1] = ex + c0; bstart[2 * t + 1] = ex + c0;
    if (c0 > 0) bbase[2 * t] = (unsigned int)atomicAdd(&gcnt[2 * t], (int)c0);
    if (c1 > 0) bbase[2 * t + 1] = (unsigned int)atomicAdd(&gcnt[2 * t + 1], (int)c1);
    __syncthreads();
    // phase 3: scatter into LDS (re-read src/dst; streaming, cheap)
    for (int j = t; j < cnt_tile; j += 256) {
        int d = dst[e0 + j];
        int sv = src[e0 + j];
        unsigned int pos = atomicAdd(&bh[d >> 8], 1u);
        ebuf_l[pos] = ((unsigned int)sv << 8) | (unsigned int)(d & 255);
    }
    __syncthreads();
    // phase 4: flush per bucket; wave-parallel, lanes cover a bucket's run.
    // Clamp to BCAP (unreachable for random dst; prevents OOB if skewed).
    int wave = t >> 6, lane = t & 63;
    for (int b = wave; b < nbuck; b += 4) {
        unsigned int st = bstart[b];
        unsigned int en = bh[b];
        if (st == en) continue;
        unsigned int gb = bbase[b];
        if (gb >= (unsigned int)BCAP) continue;
        unsigned int room = (unsigned int)BCAP - gb;
        if (en - st > room) en = st + room;
        unsigned int* dstp = ebuf + (size_t)b * BCAP + gb;
        for (unsigned int j = st + lane; j < en; j += 64)
            dstp[j - st] = ebuf_l[j];
    }
}

// K3b: per-bucket LDS counting sort -> srcs streamed out coalesced in CSR
// order. Bucket = 256 consecutive nodes; global base = rowptr[n0].
__global__ __launch_bounds__(256) void binB_kernel(
    const int* __restrict__ gcnt, const unsigned int* __restrict__ ebuf,
    const int* __restrict__ rowptr, int* __restrict__ srcs, int N)
{
    __shared__ unsigned int lh[256];
    __shared__ unsigned int sd[256];
    __shared__ unsigned int srcs_l[BCAP];
    int t = threadIdx.x;
    int b = blockIdx.x;
    int cnt = gcnt[b];
    if (cnt > BCAP) cnt = BCAP;   // matches binA clamp
    int n0 = b << 8;
    int gbase = rowptr[n0];
    const unsigned int* eb = ebuf + (size_t)b * BCAP;

    lh[t] = 0;
    __syncthreads();
    for (int j = t; j < cnt; j += 256)
        atomicAdd(&lh[eb[j] & 255u], 1u);
    __syncthreads();
    unsigned int c = lh[t];
    sd[t] = c;
    __syncthreads();
    for (int off = 1; off < 256; off <<= 1) {
        unsigned int v = (t >= off) ? sd[t - off] : 0;
        __syncthreads();
        sd[t] += v;
        __syncthreads();
    }
    lh[t] = sd[t] - c;   // exclusive local row offsets -> cursors
    __syncthreads();
    for (int j = t; j < cnt; j += 256) {
        unsigned int p = eb[j];
        unsigned int pos = atomicAdd(&lh[p & 255u], 1u);
        srcs_l[pos] = p >> 8;
    }
    __syncthreads();
    for (int j = t; j < cnt; j += 256)
        srcs[gbase + j] = (int)srcs_l[j];
}

__device__ __forceinline__ float dot16(const float4* kk, const float* qf) {
    const __half2* kh = (const __half2*)kk;
    float acc = 0.f;
#pragma unroll
    for (int j = 0; j < 8; ++j) {
        float2 kf = __half22float2(kh[j]);
        acc = fmaf(kf.x, qf[2 * j], acc);
        acc = fmaf(kf.y, qf[2 * j + 1], acc);
    }
    return acc;
}

__device__ __forceinline__ unsigned short bf16_rne(float x) {
    unsigned int u = __float_as_uint(x);
    return (unsigned short)((u + 0x7fffu + ((u >> 16) & 1u)) >> 16);
}

// K4: score, CSR row-walk. 4-lane group = node (lane hh = head). q-row loaded
// once per node; per record gather k16[src], fp16 dot, w=exp2(e'),
// bf16 weight stored STREAMING at warr16[4i+hh].
__global__ __launch_bounds__(256) void score_kernel(
    const int* __restrict__ rowptr, const int* __restrict__ srcs,
    const __half* __restrict__ k16, const __half* __restrict__ q16,
    unsigned short* __restrict__ warr16, int N, int E)
{
    int hh = threadIdx.x & 3;
    int n = blockIdx.x * 64 + (threadIdx.x >> 2);
    if (n >= N) return;
    int start = rowptr[n];
    int end   = (n == N - 1) ? E : rowptr[n + 1];

    const float4* qp = (const float4*)(q16 + (size_t)n * FDIM + hh * 16);
    float4 qv[2] = { qp[0], qp[1] };
    const __half2* qh = (const __half2*)qv;
    float qf[16];
#pragma unroll
    for (int j = 0; j < 8; ++j) {
        float2 f = __half22float2(qh[j]);
        qf[2 * j] = f.x;
        qf[2 * j + 1] = f.y;
    }

    int i = start;
    for (; i + 1 < end; i += 2) {
        int s0 = srcs[i], s1 = srcs[i + 1];
        const float4* kp0 = (const float4*)(k16 + (size_t)s0 * FDIM + hh * 16);
        const float4* kp1 = (const float4*)(k16 + (size_t)s1 * FDIM + hh * 16);
        float4 ka[2] = { kp0[0], kp0[1] };
        float4 kb[2] = { kp1[0], kp1[1] };
        float w0 = __builtin_amdgcn_exp2f(dot16(ka, qf));
        float w1 = __builtin_amdgcn_exp2f(dot16(kb, qf));
        warr16[(size_t)i * 4 + hh] = bf16_rne(w0);
        warr16[(size_t)(i + 1) * 4 + hh] = bf16_rne(w1);
    }
    if (i < end) {
        int s0 = srcs[i];
        const float4* kp0 = (const float4*)(k16 + (size_t)s0 * FDIM + hh * 16);
        float4 ka[2] = { kp0[0], kp0[1] };
        float w0 = __builtin_amdgcn_exp2f(dot16(ka, qf));
        warr16[(size_t)i * 4 + hh] = bf16_rne(w0);
    }
}

// K5: gather aggregation over CSR rows. One wave per node; lane = feature.
// bf16 weight decode = shl/mask; fp16 h gather; 4-deep unroll.
__global__ __launch_bounds__(256) void aggregate_kernel(
    const int* __restrict__ rowptr, const uint2* __restrict__ wp,
    const int* __restrict__ srcs, const __half* __restrict__ h16,
    float* __restrict__ hn, int N, int E)
{
    int lane = threadIdx.x & 63;
    int n = blockIdx.x * 4 + (threadIdx.x >> 6);
    if (n >= N) return;
    int start = rowptr[n];
    int end   = (n == N - 1) ? E : rowptr[n + 1];
    float a0 = 0.f, a1 = 0.f, a2 = 0.f, a3 = 0.f;
    float z0 = 0.f, z1 = 0.f, z2 = 0.f, z3 = 0.f;

#define AGG_REC(WW, HV)                                                  \
    {   float w0_ = __uint_as_float((WW).x << 16);                       \
        float w1_ = __uint_as_float((WW).x & 0xffff0000u);               \
        float w2_ = __uint_as_float((WW).y << 16);                       \
        float w3_ = __uint_as_float((WW).y & 0xffff0000u);               \
        a0 = fmaf(w0_, (HV), a0); z0 += w0_;                             \
        a1 = fmaf(w1_, (HV), a1); z1 += w1_;                             \
        a2 = fmaf(w2_, (HV), a2); z2 += w2_;                             \
        a3 = fmaf(w3_, (HV), a3); z3 += w3_; }

    int i = start;
    for (; i + 3 < end; i += 4) {
        uint2 ww0 = wp[i], ww1 = wp[i + 1], ww2 = wp[i + 2], ww3 = wp[i + 3];
        int s0 = srcs[i], s1 = srcs[i + 1], s2 = srcs[i + 2], s3 = srcs[i + 3];
        float hv0 = __half2float(h16[(size_t)s0 * FDIM + lane]);
        float hv1 = __half2float(h16[(size_t)s1 * FDIM + lane]);
        float hv2 = __half2float(h16[(size_t)s2 * FDIM + lane]);
        float hv3 = __half2float(h16[(size_t)s3 * FDIM + lane]);
        AGG_REC(ww0, hv0);
        AGG_REC(ww1, hv1);
        AGG_REC(ww2, hv2);
        AGG_REC(ww3, hv3);
    }
    for (; i < end; ++i) {
        uint2 ww0 = wp[i];
        int s0 = srcs[i];
        float hv0 = __half2float(h16[(size_t)s0 * FDIM + lane]);
        AGG_REC(ww0, hv0);
    }
#undef AGG_REC

    float* outr = hn + (size_t)n * (NHEADS * FDIM);
    if (end > start) {
        outr[lane]             = a0 / z0;
        outr[FDIM + lane]      = a1 / z1;
        outr[2 * FDIM + lane]  = a2 / z2;
        outr[3 * FDIM + lane]  = a3 / z3;
    } else {
        outr[lane] = 0.f;
        outr[FDIM + lane] = 0.f;
        outr[2 * FDIM + lane] = 0.f;
        outr[3 * FDIM + lane] = 0.f;
    }
}

// K6: out = hn @ W + b, IN PLACE (hn == out == d_out). Thread = 4 rows x 16 cols.
__global__ __launch_bounds__(256) void out_kernel(
    const float* hn, const float* __restrict__ W,
    const float* __restrict__ b, float* out, int R)
{
    __shared__ float sW[FDIM * FDIM];
    __shared__ float sb[FDIM];
    for (int i = threadIdx.x; i < FDIM * FDIM; i += 256) sW[i] = W[i];
    if (threadIdx.x < FDIM) sb[threadIdx.x] = b[threadIdx.x];
    __syncthreads();
    int cg = threadIdx.x & 3;
    int rg = threadIdx.x >> 2;
    long base = (long)blockIdx.x * 256 + rg * 4;
    const float4* sW4 = (const float4*)sW;
    const float4* hn4 = (const float4*)hn;
    float acc[4][16];
#pragma unroll
    for (int i = 0; i < 4; ++i)
#pragma unroll
        for (int c = 0; c < 16; ++c) acc[i][c] = sb[cg * 16 + c];

    for (int fs = 0; fs < FDIM; fs += 4) {
        float4 hv[4];
#pragma unroll
        for (int i = 0; i < 4; ++i) {
            long r = base + i; if (r >= R) r = R - 1;
            hv[i] = hn4[r * 16 + (fs >> 2)];
        }
#pragma unroll
        for (int fi = 0; fi < 4; ++fi) {
            int f = fs + fi;
            float4 w0 = sW4[f * 16 + cg * 4 + 0];
            float4 w1 = sW4[f * 16 + cg * 4 + 1];
            float4 w2 = sW4[f * 16 + cg * 4 + 2];
            float4 w3 = sW4[f * 16 + cg * 4 + 3];
#pragma unroll
            for (int i = 0; i < 4; ++i) {
                float hvf = (&hv[i].x)[fi];
                acc[i][0]  = fmaf(hvf, w0.x, acc[i][0]);
                acc[i][1]  = fmaf(hvf, w0.y, acc[i][1]);
                acc[i][2]  = fmaf(hvf, w0.z, acc[i][2]);
                acc[i][3]  = fmaf(hvf, w0.w, acc[i][3]);
                acc[i][4]  = fmaf(hvf, w1.x, acc[i][4]);
                acc[i][5]  = fmaf(hvf, w1.y, acc[i][5]);
                acc[i][6]  = fmaf(hvf, w1.z, acc[i][6]);
                acc[i][7]  = fmaf(hvf, w1.w, acc[i][7]);
                acc[i][8]  = fmaf(hvf, w2.x, acc[i][8]);
                acc[i][9]  = fmaf(hvf, w2.y, acc[i][9]);
                acc[i][10] = fmaf(hvf, w2.z, acc[i][10]);
                acc[i][11] = fmaf(hvf, w2.w, acc[i][11]);
                acc[i][12] = fmaf(hvf, w3.x, acc[i][12]);
                acc[i][13] = fmaf(hvf, w3.y, acc[i][13]);
                acc[i][14] = fmaf(hvf, w3.z, acc[i][14]);
                acc[i][15] = fmaf(hvf, w3.w, acc[i][15]);
            }
        }
    }
#pragma unroll
    for (int i = 0; i < 4; ++i) {
        long r = base + i;
        if (r >= R) continue;
        float4* o = (float4*)(out + (size_t)r * FDIM + cg * 16);
#pragma unroll
        for (int c4 = 0; c4 < 4; ++c4)
            o[c4] = make_float4(acc[i][c4*4], acc[i][c4*4+1], acc[i][c4*4+2], acc[i][c4*4+3]);
    }
}

extern "C" void kernel_launch(void* const* d_in, const int* in_sizes, int n_in,
                              void* d_out, int out_size, void* d_ws, size_t ws_size,
                              hipStream_t stream) {
    const float* h   = (const float*)d_in[0];
    const int*   src = (const int*)d_in[1];
    const int*   dst = (const int*)d_in[2];
    const float* Wk  = (const float*)d_in[3];
    const float* Wq  = (const float*)d_in[4];
    const float* W   = (const float*)d_in[5];
    const float* b   = (const float*)d_in[6];
    float* out = (float*)d_out;

    const int N = in_sizes[0] / FDIM;   // 100000
    const int E = in_sizes[1];          // 1600000

    // Workspace: k16 12.8MB, q16 12.8MB, h16 12.8MB,
    //            warr16[E*4 ushort] 12.8MB (ebuf 9.6MB ALIASES this region;
    //            ebuf dead before score writes warr16),
    //            srcs[E] 6.4MB, counts[N], gcnt[512], rowptr[N], bsum[256].
    __half* k16 = (__half*)d_ws;
    __half* q16 = k16 + (size_t)N * FDIM;
    __half* h16 = q16 + (size_t)N * FDIM;
    unsigned short* warr16 = (unsigned short*)(h16 + (size_t)N * FDIM);
    unsigned int* ebuf = (unsigned int*)warr16;   // alias (binA/binB only)
    int* srcs   = (int*)(warr16 + (size_t)E * 4);
    int* counts = srcs + E;
    int* gcnt   = counts + N;
    int* rowptr = gcnt + 512;
    int* bsum   = rowptr + N;

    const int NBLK  = (N + 1023) / 1024;            // 98
    const int KQB   = (N + 127) / 128;              // 782
    const int H2B   = ((N * FDIM / 8) + 255) / 256; // 3125
    const int HIB   = (E + 255) / 256;              // 6250
    const int NBUCK = (N + 255) >> 8;               // 391
    const int NTILE = (E + TILE - 1) / TILE;        // 196

    hipMemsetAsync(counts, 0, (size_t)(N + 512) * sizeof(int), stream);

    fused_pre_kernel<<<KQB + H2B + HIB, 256, 0, stream>>>(
        h, Wk, Wq, k16, q16, h16, dst, counts, N, E, KQB, H2B);
    scan1_kernel<<<NBLK, 256, 0, stream>>>(counts, rowptr, bsum, N);
    scan2_kernel<<<1, 256, 0, stream>>>(bsum, NBLK);
    scan3_kernel<<<(N + 255) / 256, 256, 0, stream>>>(rowptr, bsum, N);
    binA_kernel<<<NTILE, 256, 0, stream>>>(src, dst, gcnt, ebuf, E, NBUCK);
    binB_kernel<<<NBUCK, 256, 0, stream>>>(gcnt, ebuf, rowptr, srcs, N);
    score_kernel<<<(N + 63) / 64, 256, 0, stream>>>(
        rowptr, srcs, k16, q16, warr16, N, E);
    aggregate_kernel<<<(N + 3) / 4, 256, 0, stream>>>(
        rowptr, (const uint2*)warr16, srcs, h16, out, N, E);
    out_kernel<<<(N * NHEADS + 255) / 256, 256, 0, stream>>>(out, W, b, out, N * NHEADS);
}

// Round 7
// 413.328 us; speedup vs baseline: 1.4810x; 1.1943x over previous
//
#include <hip/hip_runtime.h>
#include <hip/hip_fp16.h>
#include <math.h>

// GAT layer: N=100000, E=1600000, F=64, H=4 (Dh=16).
//
// Pipeline: fused {kq GEMM (fp16, log2e in Wk) | hp GEMM (hp=h@W, fp16) |
// in-degree hist} -> scan -> binA/binB LDS bin-sort (srcs in CSR order,
// all global writes coalesced) -> score (CSR row-walk, fp16 dot, w=exp2,
// bf16 warr16 streaming) -> gather-aggregate writes FINAL out directly.
//
// Key algebra (R7): W distributes over the weighted sum:
//   out[n,h,:] = (sum_e w_eh h[src_e])/z_h @ W + b
//             = (sum_e w_eh hp[src_e])/z_h + b,   hp = h@W.
// So the out GEMM (101us: 102MB hn re-read + 100MB write, latency-bound)
// is deleted; aggregate gathers hp16 instead of h16 (same table size/pattern).
//
// R0-R4 law: any per-edge random-slot global store costs 100-150us (64B line
// dirtied per 4B payload, bounced across XCD L2s). All scattering happens in
// LDS; global writes are coalesced streams. BCAP overflow (32-sigma for
// random dst) is CLAMPED: graceful degradation instead of OOB.

#define FDIM 64
#define NHEADS 4
#define TILE 8192
#define BCAP 6144

// ---- K1: multi-role: [0,KQB) kq | [KQB,KQB+PB) hp=h@W | rest hist ----
__global__ __launch_bounds__(256) void fused_pre_kernel(
    const float* __restrict__ h, const float* __restrict__ Wk,
    const float* __restrict__ Wq, const float* __restrict__ Wo,
    __half* __restrict__ k16, __half* __restrict__ q16,
    __half* __restrict__ hp16, const int* __restrict__ dst,
    int* __restrict__ counts, int N, int E, int KQB, int PB)
{
    __shared__ float sWk[FDIM * FDIM];   // kq role: Wk*log2e | hp role: Wo
    __shared__ float sWq[FDIM * FDIM];
    int bid = blockIdx.x;
    if (bid < KQB) {
        for (int i = threadIdx.x; i < FDIM * FDIM; i += 256) {
            sWk[i] = Wk[i] * 1.4426950408889634f;
            sWq[i] = Wq[i];
        }
        __syncthreads();
        int cg = threadIdx.x & 3;
        int rg = threadIdx.x >> 2;
        long base = (long)bid * 128 + rg * 2;
        const float4* sWk4 = (const float4*)sWk;
        const float4* sWq4 = (const float4*)sWq;
        const float4* h4 = (const float4*)h;
        float acck[2][16], accq[2][16];
#pragma unroll
        for (int i = 0; i < 2; ++i)
#pragma unroll
            for (int c = 0; c < 16; ++c) { acck[i][c] = 0.f; accq[i][c] = 0.f; }

        for (int fs = 0; fs < FDIM; fs += 4) {
            float4 hv[2];
#pragma unroll
            for (int i = 0; i < 2; ++i) {
                long r = base + i; if (r >= N) r = N - 1;
                hv[i] = h4[r * 16 + (fs >> 2)];
            }
#pragma unroll
            for (int fi = 0; fi < 4; ++fi) {
                int f = fs + fi;
                float4 wk0 = sWk4[f * 16 + cg * 4 + 0];
                float4 wk1 = sWk4[f * 16 + cg * 4 + 1];
                float4 wk2 = sWk4[f * 16 + cg * 4 + 2];
                float4 wk3 = sWk4[f * 16 + cg * 4 + 3];
                float4 wq0 = sWq4[f * 16 + cg * 4 + 0];
                float4 wq1 = sWq4[f * 16 + cg * 4 + 1];
                float4 wq2 = sWq4[f * 16 + cg * 4 + 2];
                float4 wq3 = sWq4[f * 16 + cg * 4 + 3];
#pragma unroll
                for (int i = 0; i < 2; ++i) {
                    float hvf = (&hv[i].x)[fi];
                    acck[i][0]  = fmaf(hvf, wk0.x, acck[i][0]);
                    acck[i][1]  = fmaf(hvf, wk0.y, acck[i][1]);
                    acck[i][2]  = fmaf(hvf, wk0.z, acck[i][2]);
                    acck[i][3]  = fmaf(hvf, wk0.w, acck[i][3]);
                    acck[i][4]  = fmaf(hvf, wk1.x, acck[i][4]);
                    acck[i][5]  = fmaf(hvf, wk1.y, acck[i][5]);
                    acck[i][6]  = fmaf(hvf, wk1.z, acck[i][6]);
                    acck[i][7]  = fmaf(hvf, wk1.w, acck[i][7]);
                    acck[i][8]  = fmaf(hvf, wk2.x, acck[i][8]);
                    acck[i][9]  = fmaf(hvf, wk2.y, acck[i][9]);
                    acck[i][10] = fmaf(hvf, wk2.z, acck[i][10]);
                    acck[i][11] = fmaf(hvf, wk2.w, acck[i][11]);
                    acck[i][12] = fmaf(hvf, wk3.x, acck[i][12]);
                    acck[i][13] = fmaf(hvf, wk3.y, acck[i][13]);
                    acck[i][14] = fmaf(hvf, wk3.z, acck[i][14]);
                    acck[i][15] = fmaf(hvf, wk3.w, acck[i][15]);
                    accq[i][0]  = fmaf(hvf, wq0.x, accq[i][0]);
                    accq[i][1]  = fmaf(hvf, wq0.y, accq[i][1]);
                    accq[i][2]  = fmaf(hvf, wq0.z, accq[i][2]);
                    accq[i][3]  = fmaf(hvf, wq0.w, accq[i][3]);
                    accq[i][4]  = fmaf(hvf, wq1.x, accq[i][4]);
                    accq[i][5]  = fmaf(hvf, wq1.y, accq[i][5]);
                    accq[i][6]  = fmaf(hvf, wq1.z, accq[i][6]);
                    accq[i][7]  = fmaf(hvf, wq1.w, accq[i][7]);
                    accq[i][8]  = fmaf(hvf, wq2.x, accq[i][8]);
                    accq[i][9]  = fmaf(hvf, wq2.y, accq[i][9]);
                    accq[i][10] = fmaf(hvf, wq2.z, accq[i][10]);
                    accq[i][11] = fmaf(hvf, wq2.w, accq[i][11]);
                    accq[i][12] = fmaf(hvf, wq3.x, accq[i][12]);
                    accq[i][13] = fmaf(hvf, wq3.y, accq[i][13]);
                    accq[i][14] = fmaf(hvf, wq3.z, accq[i][14]);
                    accq[i][15] = fmaf(hvf, wq3.w, accq[i][15]);
                }
            }
        }
#pragma unroll
        for (int i = 0; i < 2; ++i) {
            long r = base + i;
            if (r >= N) continue;
            __half2 hk[8], hq[8];
#pragma unroll
            for (int c = 0; c < 8; ++c) {
                hk[c] = __floats2half2_rn(acck[i][2 * c], acck[i][2 * c + 1]);
                hq[c] = __floats2half2_rn(accq[i][2 * c], accq[i][2 * c + 1]);
            }
            float4* kout = (float4*)(k16 + (size_t)r * FDIM + cg * 16);
            float4* qout = (float4*)(q16 + (size_t)r * FDIM + cg * 16);
            kout[0] = ((float4*)hk)[0]; kout[1] = ((float4*)hk)[1];
            qout[0] = ((float4*)hq)[0]; qout[1] = ((float4*)hq)[1];
        }
    } else if (bid < KQB + PB) {
        // --- hp role: hp = h @ Wo (fp16 out), 128 rows/block ---
        for (int i = threadIdx.x; i < FDIM * FDIM; i += 256) sWk[i] = Wo[i];
        __syncthreads();
        int cg = threadIdx.x & 3;
        int rg = threadIdx.x >> 2;
        long base = (long)(bid - KQB) * 128 + rg * 2;
        const float4* sW4 = (const float4*)sWk;
        const float4* h4 = (const float4*)h;
        float accp[2][16];
#pragma unroll
        for (int i = 0; i < 2; ++i)
#pragma unroll
            for (int c = 0; c < 16; ++c) accp[i][c] = 0.f;

        for (int fs = 0; fs < FDIM; fs += 4) {
            float4 hv[2];
#pragma unroll
            for (int i = 0; i < 2; ++i) {
                long r = base + i; if (r >= N) r = N - 1;
                hv[i] = h4[r * 16 + (fs >> 2)];
            }
#pragma unroll
            for (int fi = 0; fi < 4; ++fi) {
                int f = fs + fi;
                float4 w0 = sW4[f * 16 + cg * 4 + 0];
                float4 w1 = sW4[f * 16 + cg * 4 + 1];
                float4 w2 = sW4[f * 16 + cg * 4 + 2];
                float4 w3 = sW4[f * 16 + cg * 4 + 3];
#pragma unroll
                for (int i = 0; i < 2; ++i) {
                    float hvf = (&hv[i].x)[fi];
                    accp[i][0]  = fmaf(hvf, w0.x, accp[i][0]);
                    accp[i][1]  = fmaf(hvf, w0.y, accp[i][1]);
                    accp[i][2]  = fmaf(hvf, w0.z, accp[i][2]);
                    accp[i][3]  = fmaf(hvf, w0.w, accp[i][3]);
                    accp[i][4]  = fmaf(hvf, w1.x, accp[i][4]);
                    accp[i][5]  = fmaf(hvf, w1.y, accp[i][5]);
                    accp[i][6]  = fmaf(hvf, w1.z, accp[i][6]);
                    accp[i][7]  = fmaf(hvf, w1.w, accp[i][7]);
                    accp[i][8]  = fmaf(hvf, w2.x, accp[i][8]);
                    accp[i][9]  = fmaf(hvf, w2.y, accp[i][9]);
                    accp[i][10] = fmaf(hvf, w2.z, accp[i][10]);
                    accp[i][11] = fmaf(hvf, w2.w, accp[i][11]);
                    accp[i][12] = fmaf(hvf, w3.x, accp[i][12]);
                    accp[i][13] = fmaf(hvf, w3.y, accp[i][13]);
                    accp[i][14] = fmaf(hvf, w3.z, accp[i][14]);
                    accp[i][15] = fmaf(hvf, w3.w, accp[i][15]);
                }
            }
        }
#pragma unroll
        for (int i = 0; i < 2; ++i) {
            long r = base + i;
            if (r >= N) continue;
            __half2 hp[8];
#pragma unroll
            for (int c = 0; c < 8; ++c)
                hp[c] = __floats2half2_rn(accp[i][2 * c], accp[i][2 * c + 1]);
            float4* pout = (float4*)(hp16 + (size_t)r * FDIM + cg * 16);
            pout[0] = ((float4*)hp)[0];
            pout[1] = ((float4*)hp)[1];
        }
    } else {
        // --- hist role: in-degree histogram ---
        int e = (bid - KQB - PB) * 256 + threadIdx.x;
        if (e < E) atomicAdd(&counts[dst[e]], 1);
    }
}

// K2a: per-1024-chunk exclusive scan of counts -> rowptr, block totals -> bsum.
__global__ __launch_bounds__(256) void scan1_kernel(
    const int* __restrict__ counts, int* __restrict__ rowptr,
    int* __restrict__ bsum, int N)
{
    __shared__ int sd[256];
    int base = blockIdx.x * 1024;
    int t = threadIdx.x;
    int c[4];
    int s = 0;
#pragma unroll
    for (int i = 0; i < 4; ++i) {
        int idx = base + t * 4 + i;
        c[i] = (idx < N) ? counts[idx] : 0;
        s += c[i];
    }
    sd[t] = s;
    __syncthreads();
    for (int off = 1; off < 256; off <<= 1) {
        int v = (t >= off) ? sd[t - off] : 0;
        __syncthreads();
        sd[t] += v;
        __syncthreads();
    }
    int ex = sd[t] - s;
#pragma unroll
    for (int i = 0; i < 4; ++i) {
        int idx = base + t * 4 + i;
        if (idx < N) rowptr[idx] = ex;
        ex += c[i];
    }
    if (t == 255) bsum[blockIdx.x] = sd[255];
}

// K2b: single-block exclusive scan of bsum (NBLK <= 256).
__global__ __launch_bounds__(256) void scan2_kernel(int* __restrict__ bsum, int NBLK)
{
    __shared__ int sd[256];
    int t = threadIdx.x;
    int v = (t < NBLK) ? bsum[t] : 0;
    sd[t] = v;
    __syncthreads();
    for (int off = 1; off < 256; off <<= 1) {
        int u = (t >= off) ? sd[t - off] : 0;
        __syncthreads();
        sd[t] += u;
        __syncthreads();
    }
    if (t < NBLK) bsum[t] = sd[t] - v;
}

// K2c: add chunk offsets.
__global__ __launch_bounds__(256) void scan3_kernel(
    int* __restrict__ rowptr, const int* __restrict__ bsum, int N)
{
    int i = blockIdx.x * 256 + threadIdx.x;
    if (i < N) rowptr[i] += bsum[i >> 10];
}

// K3a: bucket-binning pass. Tile of 8192 edges -> LDS counting sort by
// bucket (dst>>8, 391 buckets) -> per-bucket coalesced append to ebuf
// (contiguous ~21-edge runs; one global atomic per bucket per tile).
// Packed entry: src<<8 | (dst&255). Appends clamped to BCAP.
__global__ __launch_bounds__(256) void binA_kernel(
    const int* __restrict__ src, const int* __restrict__ dst,
    int* __restrict__ gcnt, unsigned int* __restrict__ ebuf,
    int E, int nbuck)
{
    __shared__ unsigned int bh[512];      // hist -> cursor
    __shared__ unsigned int bstart[512];  // stable exclusive offsets
    __shared__ unsigned int bbase[512];   // global base per bucket
    __shared__ unsigned int sd[256];
    __shared__ unsigned int ebuf_l[TILE];
    int t = threadIdx.x;
    long e0 = (long)blockIdx.x * TILE;
    int cnt_tile = (int)(((long)E - e0 < (long)TILE) ? ((long)E - e0) : (long)TILE);

    bh[t] = 0; bh[t + 256] = 0;
    __syncthreads();
    // phase 1: histogram (dst only)
    for (int j = t; j < cnt_tile; j += 256)
        atomicAdd(&bh[dst[e0 + j] >> 8], 1u);
    __syncthreads();
    // phase 2: exclusive scan of 512 entries (2/thread) + global reservation
    unsigned int c0 = bh[2 * t], c1 = bh[2 * t + 1];
    unsigned int s = c0 + c1;
    sd[t] = s;
    __syncthreads();
    for (int off = 1; off < 256; off <<= 1) {
        unsigned int v = (t >= off) ? sd[t - off] : 0;
        __syncthreads();
        sd[t] += v;
        __syncthreads();
    }
    unsigned int ex = sd[t] - s;
    bh[2 * t] = ex;          bstart[2 * t] = ex;
    bh[2 * t + 1] = ex + c0; bstart[2 * t + 1] = ex + c0;
    if (c0 > 0) bbase[2 * t] = (unsigned int)atomicAdd(&gcnt[2 * t], (int)c0);
    if (c1 > 0) bbase[2 * t + 1] = (unsigned int)atomicAdd(&gcnt[2 * t + 1], (int)c1);
    __syncthreads();
    // phase 3: scatter into LDS (re-read src/dst; streaming, cheap)
    for (int j = t; j < cnt_tile; j += 256) {
        int d = dst[e0 + j];
        int sv = src[e0 + j];
        unsigned int pos = atomicAdd(&bh[d >> 8], 1u);
        ebuf_l[pos] = ((unsigned int)sv << 8) | (unsigned int)(d & 255);
    }
    __syncthreads();
    // phase 4: flush per bucket; wave-parallel, lanes cover a bucket's run.
    // Clamp to BCAP (unreachable for random dst; prevents OOB if skewed).
    int wave = t >> 6, lane = t & 63;
    for (int b = wave; b < nbuck; b += 4) {
        unsigned int st = bstart[b];
        unsigned int en = bh[b];
        if (st == en) continue;
        unsigned int gb = bbase[b];
        if (gb >= (unsigned int)BCAP) continue;
        unsigned int room = (unsigned int)BCAP - gb;
        if (en - st > room) en = st + room;
        unsigned int* dstp = ebuf + (size_t)b * BCAP + gb;
        for (unsigned int j = st + lane; j < en; j += 64)
            dstp[j - st] = ebuf_l[j];
    }
}

// K3b: per-bucket LDS counting sort -> srcs streamed out coalesced in CSR
// order. Bucket = 256 consecutive nodes; global base = rowptr[n0].
__global__ __launch_bounds__(256) void binB_kernel(
    const int* __restrict__ gcnt, const unsigned int* __restrict__ ebuf,
    const int* __restrict__ rowptr, int* __restrict__ srcs, int N)
{
    __shared__ unsigned int lh[256];
    __shared__ unsigned int sd[256];
    __shared__ unsigned int srcs_l[BCAP];
    int t = threadIdx.x;
    int b = blockIdx.x;
    int cnt = gcnt[b];
    if (cnt > BCAP) cnt = BCAP;   // matches binA clamp
    int n0 = b << 8;
    int gbase = rowptr[n0];
    const unsigned int* eb = ebuf + (size_t)b * BCAP;

    lh[t] = 0;
    __syncthreads();
    for (int j = t; j < cnt; j += 256)
        atomicAdd(&lh[eb[j] & 255u], 1u);
    __syncthreads();
    unsigned int c = lh[t];
    sd[t] = c;
    __syncthreads();
    for (int off = 1; off < 256; off <<= 1) {
        unsigned int v = (t >= off) ? sd[t - off] : 0;
        __syncthreads();
        sd[t] += v;
        __syncthreads();
    }
    lh[t] = sd[t] - c;   // exclusive local row offsets -> cursors
    __syncthreads();
    for (int j = t; j < cnt; j += 256) {
        unsigned int p = eb[j];
        unsigned int pos = atomicAdd(&lh[p & 255u], 1u);
        srcs_l[pos] = p >> 8;
    }
    __syncthreads();
    for (int j = t; j < cnt; j += 256)
        srcs[gbase + j] = (int)srcs_l[j];
}

__device__ __forceinline__ float dot16(const float4* kk, const float* qf) {
    const __half2* kh = (const __half2*)kk;
    float acc = 0.f;
#pragma unroll
    for (int j = 0; j < 8; ++j) {
        float2 kf = __half22float2(kh[j]);
        acc = fmaf(kf.x, qf[2 * j], acc);
        acc = fmaf(kf.y, qf[2 * j + 1], acc);
    }
    return acc;
}

__device__ __forceinline__ unsigned short bf16_rne(float x) {
    unsigned int u = __float_as_uint(x);
    return (unsigned short)((u + 0x7fffu + ((u >> 16) & 1u)) >> 16);
}

// K4: score, CSR row-walk. 4-lane group = node (lane hh = head). q-row loaded
// once per node; per record gather k16[src], fp16 dot, w=exp2(e'),
// bf16 weight stored STREAMING at warr16[4i+hh].
__global__ __launch_bounds__(256) void score_kernel(
    const int* __restrict__ rowptr, const int* __restrict__ srcs,
    const __half* __restrict__ k16, const __half* __restrict__ q16,
    unsigned short* __restrict__ warr16, int N, int E)
{
    int hh = threadIdx.x & 3;
    int n = blockIdx.x * 64 + (threadIdx.x >> 2);
    if (n >= N) return;
    int start = rowptr[n];
    int end   = (n == N - 1) ? E : rowptr[n + 1];

    const float4* qp = (const float4*)(q16 + (size_t)n * FDIM + hh * 16);
    float4 qv[2] = { qp[0], qp[1] };
    const __half2* qh = (const __half2*)qv;
    float qf[16];
#pragma unroll
    for (int j = 0; j < 8; ++j) {
        float2 f = __half22float2(qh[j]);
        qf[2 * j] = f.x;
        qf[2 * j + 1] = f.y;
    }

    int i = start;
    for (; i + 1 < end; i += 2) {
        int s0 = srcs[i], s1 = srcs[i + 1];
        const float4* kp0 = (const float4*)(k16 + (size_t)s0 * FDIM + hh * 16);
        const float4* kp1 = (const float4*)(k16 + (size_t)s1 * FDIM + hh * 16);
        float4 ka[2] = { kp0[0], kp0[1] };
        float4 kb[2] = { kp1[0], kp1[1] };
        float w0 = __builtin_amdgcn_exp2f(dot16(ka, qf));
        float w1 = __builtin_amdgcn_exp2f(dot16(kb, qf));
        warr16[(size_t)i * 4 + hh] = bf16_rne(w0);
        warr16[(size_t)(i + 1) * 4 + hh] = bf16_rne(w1);
    }
    if (i < end) {
        int s0 = srcs[i];
        const float4* kp0 = (const float4*)(k16 + (size_t)s0 * FDIM + hh * 16);
        float4 ka[2] = { kp0[0], kp0[1] };
        float w0 = __builtin_amdgcn_exp2f(dot16(ka, qf));
        warr16[(size_t)i * 4 + hh] = bf16_rne(w0);
    }
}

// K5: gather aggregation over CSR rows -> FINAL out. One wave per node;
// lane = out-feature. bf16 weight decode = shl/mask; fp16 hp gather;
// 4-deep unroll. out[n,h,:] = (sum_e w_eh hp[src_e]) / z_h + b.
__global__ __launch_bounds__(256) void aggregate_kernel(
    const int* __restrict__ rowptr, const uint2* __restrict__ wp,
    const int* __restrict__ srcs, const __half* __restrict__ hp16,
    const float* __restrict__ b, float* __restrict__ out, int N, int E)
{
    int lane = threadIdx.x & 63;
    int n = blockIdx.x * 4 + (threadIdx.x >> 6);
    if (n >= N) return;
    int start = rowptr[n];
    int end   = (n == N - 1) ? E : rowptr[n + 1];
    float a0 = 0.f, a1 = 0.f, a2 = 0.f, a3 = 0.f;
    float z0 = 0.f, z1 = 0.f, z2 = 0.f, z3 = 0.f;

#define AGG_REC(WW, HV)                                                  \
    {   float w0_ = __uint_as_float((WW).x << 16);                       \
        float w1_ = __uint_as_float((WW).x & 0xffff0000u);               \
        float w2_ = __uint_as_float((WW).y << 16);                       \
        float w3_ = __uint_as_float((WW).y & 0xffff0000u);               \
        a0 = fmaf(w0_, (HV), a0); z0 += w0_;                             \
        a1 = fmaf(w1_, (HV), a1); z1 += w1_;                             \
        a2 = fmaf(w2_, (HV), a2); z2 += w2_;                             \
        a3 = fmaf(w3_, (HV), a3); z3 += w3_; }

    int i = start;
    for (; i + 3 < end; i += 4) {
        uint2 ww0 = wp[i], ww1 = wp[i + 1], ww2 = wp[i + 2], ww3 = wp[i + 3];
        int s0 = srcs[i], s1 = srcs[i + 1], s2 = srcs[i + 2], s3 = srcs[i + 3];
        float hv0 = __half2float(hp16[(size_t)s0 * FDIM + lane]);
        float hv1 = __half2float(hp16[(size_t)s1 * FDIM + lane]);
        float hv2 = __half2float(hp16[(size_t)s2 * FDIM + lane]);
        float hv3 = __half2float(hp16[(size_t)s3 * FDIM + lane]);
        AGG_REC(ww0, hv0);
        AGG_REC(ww1, hv1);
        AGG_REC(ww2, hv2);
        AGG_REC(ww3, hv3);
    }
    for (; i < end; ++i) {
        uint2 ww0 = wp[i];
        int s0 = srcs[i];
        float hv0 = __half2float(hp16[(size_t)s0 * FDIM + lane]);
        AGG_REC(ww0, hv0);
    }
#undef AGG_REC

    float bv = b[lane];
    float* outr = out + (size_t)n * (NHEADS * FDIM);
    if (end > start) {
        outr[lane]             = a0 / z0 + bv;
        outr[FDIM + lane]      = a1 / z1 + bv;
        outr[2 * FDIM + lane]  = a2 / z2 + bv;
        outr[3 * FDIM + lane]  = a3 / z3 + bv;
    } else {
        outr[lane] = bv;
        outr[FDIM + lane] = bv;
        outr[2 * FDIM + lane] = bv;
        outr[3 * FDIM + lane] = bv;
    }
}

extern "C" void kernel_launch(void* const* d_in, const int* in_sizes, int n_in,
                              void* d_out, int out_size, void* d_ws, size_t ws_size,
                              hipStream_t stream) {
    const float* h   = (const float*)d_in[0];
    const int*   src = (const int*)d_in[1];
    const int*   dst = (const int*)d_in[2];
    const float* Wk  = (const float*)d_in[3];
    const float* Wq  = (const float*)d_in[4];
    const float* W   = (const float*)d_in[5];
    const float* b   = (const float*)d_in[6];
    float* out = (float*)d_out;

    const int N = in_sizes[0] / FDIM;   // 100000
    const int E = in_sizes[1];          // 1600000

    // Workspace: k16 12.8MB, q16 12.8MB, hp16 12.8MB,
    //            warr16[E*4 ushort] 12.8MB (ebuf 9.6MB ALIASES this region;
    //            ebuf dead before score writes warr16),
    //            srcs[E] 6.4MB, counts[N], gcnt[512], rowptr[N], bsum[256].
    __half* k16 = (__half*)d_ws;
    __half* q16 = k16 + (size_t)N * FDIM;
    __half* hp16 = q16 + (size_t)N * FDIM;
    unsigned short* warr16 = (unsigned short*)(hp16 + (size_t)N * FDIM);
    unsigned int* ebuf = (unsigned int*)warr16;   // alias (binA/binB only)
    int* srcs   = (int*)(warr16 + (size_t)E * 4);
    int* counts = srcs + E;
    int* gcnt   = counts + N;
    int* rowptr = gcnt + 512;
    int* bsum   = rowptr + N;

    const int NBLK  = (N + 1023) / 1024;            // 98
    const int KQB   = (N + 127) / 128;              // 782
    const int PB    = (N + 127) / 128;              // 782 (hp role)
    const int HIB   = (E + 255) / 256;              // 6250
    const int NBUCK = (N + 255) >> 8;               // 391
    const int NTILE = (E + TILE - 1) / TILE;        // 196

    hipMemsetAsync(counts, 0, (size_t)(N + 512) * sizeof(int), stream);

    fused_pre_kernel<<<KQB + PB + HIB, 256, 0, stream>>>(
        h, Wk, Wq, W, k16, q16, hp16, dst, counts, N, E, KQB, PB);
    scan1_kernel<<<NBLK, 256, 0, stream>>>(counts, rowptr, bsum, N);
    scan2_kernel<<<1, 256, 0, stream>>>(bsum, NBLK);
    scan3_kernel<<<(N + 255) / 256, 256, 0, stream>>>(rowptr, bsum, N);
    binA_kernel<<<NTILE, 256, 0, stream>>>(src, dst, gcnt, ebuf, E, NBUCK);
    binB_kernel<<<NBUCK, 256, 0, stream>>>(gcnt, ebuf, rowptr, srcs, N);
    score_kernel<<<(N + 63) / 64, 256, 0, stream>>>(
        rowptr, srcs, k16, q16, warr16, N, E);
    aggregate_kernel<<<(N + 3) / 4, 256, 0, stream>>>(
        rowptr, (const uint2*)warr16, srcs, hp16, b, out, N, E);
}

// Round 8
// 362.517 us; speedup vs baseline: 1.6886x; 1.1402x over previous
//
#include <hip/hip_runtime.h>
#include <hip/hip_fp16.h>
#include <math.h>

// GAT layer: N=100000, E=1600000, F=64, H=4 (Dh=16).
//
// Pipeline: fused_pre {kq GEMM (fp16, log2e in Wk) | hp GEMM (hp=h@W, fp16)}
// -> binA (bucket edges by dst>>8, LDS tile sort, coalesced appends, gcnt) ->
// scan_gcnt (single block, 512 entries) ->
// binB (per-bucket LDS counting sort; derives AND writes rowptr from its own
// LDS histogram; srcs streamed coalesced in CSR order) ->
// score (CSR row-walk, fp16 dot, w=exp2, bf16 warr16 streaming) ->
// gather-aggregate writes FINAL out (W distributed: out = agg(hp)/z + b).
//
// R8: the in-degree histogram was redundant — binB's LDS sort hist IS the
// per-node count. R7 counters: hist role = 1.6M random device atomics =
// 49MB of line ping-pong WRITE (87.4MB total vs 38.4MB program writes).
// rowptr[n] = scan(gcnt)[n>>8] + LDS-scan(local hist)[n&255], all in-sort.
//
// R0-R4 law: any per-edge random-slot global store/atomic costs 100-150us.
// All scattering happens in LDS; global writes are coalesced streams.
// BCAP overflow (32-sigma for random dst) is CLAMPED (graceful, no OOB).

#define FDIM 64
#define NHEADS 4
#define TILE 8192
#define BCAP 6144

// ---- K1: pure GEMM: [0,KQB) kq | [KQB,KQB+PB) hp=h@W ----
__global__ __launch_bounds__(256) void fused_pre_kernel(
    const float* __restrict__ h, const float* __restrict__ Wk,
    const float* __restrict__ Wq, const float* __restrict__ Wo,
    __half* __restrict__ k16, __half* __restrict__ q16,
    __half* __restrict__ hp16, int N, int KQB)
{
    __shared__ float sWk[FDIM * FDIM];   // kq role: Wk*log2e | hp role: Wo
    __shared__ float sWq[FDIM * FDIM];
    int bid = blockIdx.x;
    if (bid < KQB) {
        for (int i = threadIdx.x; i < FDIM * FDIM; i += 256) {
            sWk[i] = Wk[i] * 1.4426950408889634f;
            sWq[i] = Wq[i];
        }
        __syncthreads();
        int cg = threadIdx.x & 3;
        int rg = threadIdx.x >> 2;
        long base = (long)bid * 128 + rg * 2;
        const float4* sWk4 = (const float4*)sWk;
        const float4* sWq4 = (const float4*)sWq;
        const float4* h4 = (const float4*)h;
        float acck[2][16], accq[2][16];
#pragma unroll
        for (int i = 0; i < 2; ++i)
#pragma unroll
            for (int c = 0; c < 16; ++c) { acck[i][c] = 0.f; accq[i][c] = 0.f; }

        for (int fs = 0; fs < FDIM; fs += 4) {
            float4 hv[2];
#pragma unroll
            for (int i = 0; i < 2; ++i) {
                long r = base + i; if (r >= N) r = N - 1;
                hv[i] = h4[r * 16 + (fs >> 2)];
            }
#pragma unroll
            for (int fi = 0; fi < 4; ++fi) {
                int f = fs + fi;
                float4 wk0 = sWk4[f * 16 + cg * 4 + 0];
                float4 wk1 = sWk4[f * 16 + cg * 4 + 1];
                float4 wk2 = sWk4[f * 16 + cg * 4 + 2];
                float4 wk3 = sWk4[f * 16 + cg * 4 + 3];
                float4 wq0 = sWq4[f * 16 + cg * 4 + 0];
                float4 wq1 = sWq4[f * 16 + cg * 4 + 1];
                float4 wq2 = sWq4[f * 16 + cg * 4 + 2];
                float4 wq3 = sWq4[f * 16 + cg * 4 + 3];
#pragma unroll
                for (int i = 0; i < 2; ++i) {
                    float hvf = (&hv[i].x)[fi];
                    acck[i][0]  = fmaf(hvf, wk0.x, acck[i][0]);
                    acck[i][1]  = fmaf(hvf, wk0.y, acck[i][1]);
                    acck[i][2]  = fmaf(hvf, wk0.z, acck[i][2]);
                    acck[i][3]  = fmaf(hvf, wk0.w, acck[i][3]);
                    acck[i][4]  = fmaf(hvf, wk1.x, acck[i][4]);
                    acck[i][5]  = fmaf(hvf, wk1.y, acck[i][5]);
                    acck[i][6]  = fmaf(hvf, wk1.z, acck[i][6]);
                    acck[i][7]  = fmaf(hvf, wk1.w, acck[i][7]);
                    acck[i][8]  = fmaf(hvf, wk2.x, acck[i][8]);
                    acck[i][9]  = fmaf(hvf, wk2.y, acck[i][9]);
                    acck[i][10] = fmaf(hvf, wk2.z, acck[i][10]);
                    acck[i][11] = fmaf(hvf, wk2.w, acck[i][11]);
                    acck[i][12] = fmaf(hvf, wk3.x, acck[i][12]);
                    acck[i][13] = fmaf(hvf, wk3.y, acck[i][13]);
                    acck[i][14] = fmaf(hvf, wk3.z, acck[i][14]);
                    acck[i][15] = fmaf(hvf, wk3.w, acck[i][15]);
                    accq[i][0]  = fmaf(hvf, wq0.x, accq[i][0]);
                    accq[i][1]  = fmaf(hvf, wq0.y, accq[i][1]);
                    accq[i][2]  = fmaf(hvf, wq0.z, accq[i][2]);
                    accq[i][3]  = fmaf(hvf, wq0.w, accq[i][3]);
                    accq[i][4]  = fmaf(hvf, wq1.x, accq[i][4]);
                    accq[i][5]  = fmaf(hvf, wq1.y, accq[i][5]);
                    accq[i][6]  = fmaf(hvf, wq1.z, accq[i][6]);
                    accq[i][7]  = fmaf(hvf, wq1.w, accq[i][7]);
                    accq[i][8]  = fmaf(hvf, wq2.x, accq[i][8]);
                    accq[i][9]  = fmaf(hvf, wq2.y, accq[i][9]);
                    accq[i][10] = fmaf(hvf, wq2.z, accq[i][10]);
                    accq[i][11] = fmaf(hvf, wq2.w, accq[i][11]);
                    accq[i][12] = fmaf(hvf, wq3.x, accq[i][12]);
                    accq[i][13] = fmaf(hvf, wq3.y, accq[i][13]);
                    accq[i][14] = fmaf(hvf, wq3.z, accq[i][14]);
                    accq[i][15] = fmaf(hvf, wq3.w, accq[i][15]);
                }
            }
        }
#pragma unroll
        for (int i = 0; i < 2; ++i) {
            long r = base + i;
            if (r >= N) continue;
            __half2 hk[8], hq[8];
#pragma unroll
            for (int c = 0; c < 8; ++c) {
                hk[c] = __floats2half2_rn(acck[i][2 * c], acck[i][2 * c + 1]);
                hq[c] = __floats2half2_rn(accq[i][2 * c], accq[i][2 * c + 1]);
            }
            float4* kout = (float4*)(k16 + (size_t)r * FDIM + cg * 16);
            float4* qout = (float4*)(q16 + (size_t)r * FDIM + cg * 16);
            kout[0] = ((float4*)hk)[0]; kout[1] = ((float4*)hk)[1];
            qout[0] = ((float4*)hq)[0]; qout[1] = ((float4*)hq)[1];
        }
    } else {
        // --- hp role: hp = h @ Wo (fp16 out), 128 rows/block ---
        for (int i = threadIdx.x; i < FDIM * FDIM; i += 256) sWk[i] = Wo[i];
        __syncthreads();
        int cg = threadIdx.x & 3;
        int rg = threadIdx.x >> 2;
        long base = (long)(bid - KQB) * 128 + rg * 2;
        const float4* sW4 = (const float4*)sWk;
        const float4* h4 = (const float4*)h;
        float accp[2][16];
#pragma unroll
        for (int i = 0; i < 2; ++i)
#pragma unroll
            for (int c = 0; c < 16; ++c) accp[i][c] = 0.f;

        for (int fs = 0; fs < FDIM; fs += 4) {
            float4 hv[2];
#pragma unroll
            for (int i = 0; i < 2; ++i) {
                long r = base + i; if (r >= N) r = N - 1;
                hv[i] = h4[r * 16 + (fs >> 2)];
            }
#pragma unroll
            for (int fi = 0; fi < 4; ++fi) {
                int f = fs + fi;
                float4 w0 = sW4[f * 16 + cg * 4 + 0];
                float4 w1 = sW4[f * 16 + cg * 4 + 1];
                float4 w2 = sW4[f * 16 + cg * 4 + 2];
                float4 w3 = sW4[f * 16 + cg * 4 + 3];
#pragma unroll
                for (int i = 0; i < 2; ++i) {
                    float hvf = (&hv[i].x)[fi];
                    accp[i][0]  = fmaf(hvf, w0.x, accp[i][0]);
                    accp[i][1]  = fmaf(hvf, w0.y, accp[i][1]);
                    accp[i][2]  = fmaf(hvf, w0.z, accp[i][2]);
                    accp[i][3]  = fmaf(hvf, w0.w, accp[i][3]);
                    accp[i][4]  = fmaf(hvf, w1.x, accp[i][4]);
                    accp[i][5]  = fmaf(hvf, w1.y, accp[i][5]);
                    accp[i][6]  = fmaf(hvf, w1.z, accp[i][6]);
                    accp[i][7]  = fmaf(hvf, w1.w, accp[i][7]);
                    accp[i][8]  = fmaf(hvf, w2.x, accp[i][8]);
                    accp[i][9]  = fmaf(hvf, w2.y, accp[i][9]);
                    accp[i][10] = fmaf(hvf, w2.z, accp[i][10]);
                    accp[i][11] = fmaf(hvf, w2.w, accp[i][11]);
                    accp[i][12] = fmaf(hvf, w3.x, accp[i][12]);
                    accp[i][13] = fmaf(hvf, w3.y, accp[i][13]);
                    accp[i][14] = fmaf(hvf, w3.z, accp[i][14]);
                    accp[i][15] = fmaf(hvf, w3.w, accp[i][15]);
                }
            }
        }
#pragma unroll
        for (int i = 0; i < 2; ++i) {
            long r = base + i;
            if (r >= N) continue;
            __half2 hp[8];
#pragma unroll
            for (int c = 0; c < 8; ++c)
                hp[c] = __floats2half2_rn(accp[i][2 * c], accp[i][2 * c + 1]);
            float4* pout = (float4*)(hp16 + (size_t)r * FDIM + cg * 16);
            pout[0] = ((float4*)hp)[0];
            pout[1] = ((float4*)hp)[1];
        }
    }
}

// K2a: bucket-binning pass. Tile of 8192 edges -> LDS counting sort by
// bucket (dst>>8, 391 buckets) -> per-bucket coalesced append to ebuf
// (contiguous ~21-edge runs; one global atomic per bucket per tile).
// Packed entry: src<<8 | (dst&255). Appends clamped to BCAP.
__global__ __launch_bounds__(256) void binA_kernel(
    const int* __restrict__ src, const int* __restrict__ dst,
    int* __restrict__ gcnt, unsigned int* __restrict__ ebuf,
    int E, int nbuck)
{
    __shared__ unsigned int bh[512];      // hist -> cursor
    __shared__ unsigned int bstart[512];  // stable exclusive offsets
    __shared__ unsigned int bbase[512];   // global base per bucket
    __shared__ unsigned int sd[256];
    __shared__ unsigned int ebuf_l[TILE];
    int t = threadIdx.x;
    long e0 = (long)blockIdx.x * TILE;
    int cnt_tile = (int)(((long)E - e0 < (long)TILE) ? ((long)E - e0) : (long)TILE);

    bh[t] = 0; bh[t + 256] = 0;
    __syncthreads();
    // phase 1: histogram (dst only)
    for (int j = t; j < cnt_tile; j += 256)
        atomicAdd(&bh[dst[e0 + j] >> 8], 1u);
    __syncthreads();
    // phase 2: exclusive scan of 512 entries (2/thread) + global reservation
    unsigned int c0 = bh[2 * t], c1 = bh[2 * t + 1];
    unsigned int s = c0 + c1;
    sd[t] = s;
    __syncthreads();
    for (int off = 1; off < 256; off <<= 1) {
        unsigned int v = (t >= off) ? sd[t - off] : 0;
        __syncthreads();
        sd[t] += v;
        __syncthreads();
    }
    unsigned int ex = sd[t] - s;
    bh[2 * t] = ex;          bstart[2 * t] = ex;
    bh[2 * t + 1] = ex + c0; bstart[2 * t + 1] = ex + c0;
    if (c0 > 0) bbase[2 * t] = (unsigned int)atomicAdd(&gcnt[2 * t], (int)c0);
    if (c1 > 0) bbase[2 * t + 1] = (unsigned int)atomicAdd(&gcnt[2 * t + 1], (int)c1);
    __syncthreads();
    // phase 3: scatter into LDS (re-read src/dst; streaming, cheap)
    for (int j = t; j < cnt_tile; j += 256) {
        int d = dst[e0 + j];
        int sv = src[e0 + j];
        unsigned int pos = atomicAdd(&bh[d >> 8], 1u);
        ebuf_l[pos] = ((unsigned int)sv << 8) | (unsigned int)(d & 255);
    }
    __syncthreads();
    // phase 4: flush per bucket; wave-parallel, lanes cover a bucket's run.
    // Clamp to BCAP (unreachable for random dst; prevents OOB if skewed).
    int wave = t >> 6, lane = t & 63;
    for (int b = wave; b < nbuck; b += 4) {
        unsigned int st = bstart[b];
        unsigned int en = bh[b];
        if (st == en) continue;
        unsigned int gb = bbase[b];
        if (gb >= (unsigned int)BCAP) continue;
        unsigned int room = (unsigned int)BCAP - gb;
        if (en - st > room) en = st + room;
        unsigned int* dstp = ebuf + (size_t)b * BCAP + gb;
        for (unsigned int j = st + lane; j < en; j += 64)
            dstp[j - st] = ebuf_l[j];
    }
}

// K2b: single-block exclusive scan of gcnt (512 entries, 2/thread) -> gbase.
__global__ __launch_bounds__(256) void scan_gcnt_kernel(
    const int* __restrict__ gcnt, int* __restrict__ gbase)
{
    __shared__ int sd[256];
    int t = threadIdx.x;
    int c0 = gcnt[2 * t], c1 = gcnt[2 * t + 1];
    int s = c0 + c1;
    sd[t] = s;
    __syncthreads();
    for (int off = 1; off < 256; off <<= 1) {
        int v = (t >= off) ? sd[t - off] : 0;
        __syncthreads();
        sd[t] += v;
        __syncthreads();
    }
    int ex = sd[t] - s;
    gbase[2 * t] = ex;
    gbase[2 * t + 1] = ex + c0;
}

// K2c: per-bucket LDS counting sort. Derives rowptr from its own LDS hist
// (rowptr[n0+t] = gbase[b] + local exclusive scan) and streams srcs out
// coalesced in CSR order. Bucket = 256 consecutive nodes.
__global__ __launch_bounds__(256) void binB_kernel(
    const int* __restrict__ gcnt, const int* __restrict__ gbase,
    const unsigned int* __restrict__ ebuf, int* __restrict__ rowptr,
    int* __restrict__ srcs, int N)
{
    __shared__ unsigned int lh[256];
    __shared__ unsigned int sd[256];
    __shared__ unsigned int srcs_l[BCAP];
    int t = threadIdx.x;
    int b = blockIdx.x;
    int cnt = gcnt[b];
    if (cnt > BCAP) cnt = BCAP;   // matches binA clamp
    int n0 = b << 8;
    int gb = gbase[b];
    const unsigned int* eb = ebuf + (size_t)b * BCAP;

    lh[t] = 0;
    __syncthreads();
    for (int j = t; j < cnt; j += 256)
        atomicAdd(&lh[eb[j] & 255u], 1u);
    __syncthreads();
    unsigned int c = lh[t];
    sd[t] = c;
    __syncthreads();
    for (int off = 1; off < 256; off <<= 1) {
        unsigned int v = (t >= off) ? sd[t - off] : 0;
        __syncthreads();
        sd[t] += v;
        __syncthreads();
    }
    unsigned int excl = sd[t] - c;
    lh[t] = excl;        // cursors for the scatter below
    if (n0 + t < N) rowptr[n0 + t] = gb + (int)excl;   // CSR row start
    __syncthreads();
    for (int j = t; j < cnt; j += 256) {
        unsigned int p = eb[j];
        unsigned int pos = atomicAdd(&lh[p & 255u], 1u);
        srcs_l[pos] = p >> 8;
    }
    __syncthreads();
    for (int j = t; j < cnt; j += 256)
        srcs[gb + j] = (int)srcs_l[j];
}

__device__ __forceinline__ float dot16(const float4* kk, const float* qf) {
    const __half2* kh = (const __half2*)kk;
    float acc = 0.f;
#pragma unroll
    for (int j = 0; j < 8; ++j) {
        float2 kf = __half22float2(kh[j]);
        acc = fmaf(kf.x, qf[2 * j], acc);
        acc = fmaf(kf.y, qf[2 * j + 1], acc);
    }
    return acc;
}

__device__ __forceinline__ unsigned short bf16_rne(float x) {
    unsigned int u = __float_as_uint(x);
    return (unsigned short)((u + 0x7fffu + ((u >> 16) & 1u)) >> 16);
}

// K3: score, CSR row-walk. 4-lane group = node (lane hh = head). q-row loaded
// once per node; per record gather k16[src], fp16 dot, w=exp2(e'),
// bf16 weight stored STREAMING at warr16[4i+hh].
__global__ __launch_bounds__(256) void score_kernel(
    const int* __restrict__ rowptr, const int* __restrict__ srcs,
    const __half* __restrict__ k16, const __half* __restrict__ q16,
    unsigned short* __restrict__ warr16, int N, int E)
{
    int hh = threadIdx.x & 3;
    int n = blockIdx.x * 64 + (threadIdx.x >> 2);
    if (n >= N) return;
    int start = rowptr[n];
    int end   = (n == N - 1) ? E : rowptr[n + 1];

    const float4* qp = (const float4*)(q16 + (size_t)n * FDIM + hh * 16);
    float4 qv[2] = { qp[0], qp[1] };
    const __half2* qh = (const __half2*)qv;
    float qf[16];
#pragma unroll
    for (int j = 0; j < 8; ++j) {
        float2 f = __half22float2(qh[j]);
        qf[2 * j] = f.x;
        qf[2 * j + 1] = f.y;
    }

    int i = start;
    for (; i + 1 < end; i += 2) {
        int s0 = srcs[i], s1 = srcs[i + 1];
        const float4* kp0 = (const float4*)(k16 + (size_t)s0 * FDIM + hh * 16);
        const float4* kp1 = (const float4*)(k16 + (size_t)s1 * FDIM + hh * 16);
        float4 ka[2] = { kp0[0], kp0[1] };
        float4 kb[2] = { kp1[0], kp1[1] };
        float w0 = __builtin_amdgcn_exp2f(dot16(ka, qf));
        float w1 = __builtin_amdgcn_exp2f(dot16(kb, qf));
        warr16[(size_t)i * 4 + hh] = bf16_rne(w0);
        warr16[(size_t)(i + 1) * 4 + hh] = bf16_rne(w1);
    }
    if (i < end) {
        int s0 = srcs[i];
        const float4* kp0 = (const float4*)(k16 + (size_t)s0 * FDIM + hh * 16);
        float4 ka[2] = { kp0[0], kp0[1] };
        float w0 = __builtin_amdgcn_exp2f(dot16(ka, qf));
        warr16[(size_t)i * 4 + hh] = bf16_rne(w0);
    }
}

// K4: gather aggregation over CSR rows -> FINAL out. One wave per node;
// lane = out-feature. bf16 weight decode = shl/mask; fp16 hp gather;
// 4-deep unroll. out[n,h,:] = (sum_e w_eh hp[src_e]) / z_h + b.
__global__ __launch_bounds__(256) void aggregate_kernel(
    const int* __restrict__ rowptr, const uint2* __restrict__ wp,
    const int* __restrict__ srcs, const __half* __restrict__ hp16,
    const float* __restrict__ b, float* __restrict__ out, int N, int E)
{
    int lane = threadIdx.x & 63;
    int n = blockIdx.x * 4 + (threadIdx.x >> 6);
    if (n >= N) return;
    int start = rowptr[n];
    int end   = (n == N - 1) ? E : rowptr[n + 1];
    float a0 = 0.f, a1 = 0.f, a2 = 0.f, a3 = 0.f;
    float z0 = 0.f, z1 = 0.f, z2 = 0.f, z3 = 0.f;

#define AGG_REC(WW, HV)                                                  \
    {   float w0_ = __uint_as_float((WW).x << 16);                       \
        float w1_ = __uint_as_float((WW).x & 0xffff0000u);               \
        float w2_ = __uint_as_float((WW).y << 16);                       \
        float w3_ = __uint_as_float((WW).y & 0xffff0000u);               \
        a0 = fmaf(w0_, (HV), a0); z0 += w0_;                             \
        a1 = fmaf(w1_, (HV), a1); z1 += w1_;                             \
        a2 = fmaf(w2_, (HV), a2); z2 += w2_;                             \
        a3 = fmaf(w3_, (HV), a3); z3 += w3_; }

    int i = start;
    for (; i + 3 < end; i += 4) {
        uint2 ww0 = wp[i], ww1 = wp[i + 1], ww2 = wp[i + 2], ww3 = wp[i + 3];
        int s0 = srcs[i], s1 = srcs[i + 1], s2 = srcs[i + 2], s3 = srcs[i + 3];
        float hv0 = __half2float(hp16[(size_t)s0 * FDIM + lane]);
        float hv1 = __half2float(hp16[(size_t)s1 * FDIM + lane]);
        float hv2 = __half2float(hp16[(size_t)s2 * FDIM + lane]);
        float hv3 = __half2float(hp16[(size_t)s3 * FDIM + lane]);
        AGG_REC(ww0, hv0);
        AGG_REC(ww1, hv1);
        AGG_REC(ww2, hv2);
        AGG_REC(ww3, hv3);
    }
    for (; i < end; ++i) {
        uint2 ww0 = wp[i];
        int s0 = srcs[i];
        float hv0 = __half2float(hp16[(size_t)s0 * FDIM + lane]);
        AGG_REC(ww0, hv0);
    }
#undef AGG_REC

    float bv = b[lane];
    float* outr = out + (size_t)n * (NHEADS * FDIM);
    if (end > start) {
        outr[lane]             = a0 / z0 + bv;
        outr[FDIM + lane]      = a1 / z1 + bv;
        outr[2 * FDIM + lane]  = a2 / z2 + bv;
        outr[3 * FDIM + lane]  = a3 / z3 + bv;
    } else {
        outr[lane] = bv;
        outr[FDIM + lane] = bv;
        outr[2 * FDIM + lane] = bv;
        outr[3 * FDIM + lane] = bv;
    }
}

extern "C" void kernel_launch(void* const* d_in, const int* in_sizes, int n_in,
                              void* d_out, int out_size, void* d_ws, size_t ws_size,
                              hipStream_t stream) {
    const float* h   = (const float*)d_in[0];
    const int*   src = (const int*)d_in[1];
    const int*   dst = (const int*)d_in[2];
    const float* Wk  = (const float*)d_in[3];
    const float* Wq  = (const float*)d_in[4];
    const float* W   = (const float*)d_in[5];
    const float* b   = (const float*)d_in[6];
    float* out = (float*)d_out;

    const int N = in_sizes[0] / FDIM;   // 100000
    const int E = in_sizes[1];          // 1600000

    // Workspace: k16 12.8MB, q16 12.8MB, hp16 12.8MB,
    //            warr16[E*4 ushort] 12.8MB (ebuf 9.6MB ALIASES this region;
    //            ebuf dead before score writes warr16),
    //            srcs[E] 6.4MB, gcnt[512], gbase[512], rowptr[N].
    __half* k16 = (__half*)d_ws;
    __half* q16 = k16 + (size_t)N * FDIM;
    __half* hp16 = q16 + (size_t)N * FDIM;
    unsigned short* warr16 = (unsigned short*)(hp16 + (size_t)N * FDIM);
    unsigned int* ebuf = (unsigned int*)warr16;   // alias (binA/binB only)
    int* srcs   = (int*)(warr16 + (size_t)E * 4);
    int* gcnt   = srcs + E;
    int* gbase  = gcnt + 512;
    int* rowptr = gbase + 512;

    const int KQB   = (N + 127) / 128;              // 782
    const int PB    = (N + 127) / 128;              // 782 (hp role)
    const int NBUCK = (N + 255) >> 8;               // 391
    const int NTILE = (E + TILE - 1) / TILE;        // 196

    hipMemsetAsync(gcnt, 0, 512 * sizeof(int), stream);

    fused_pre_kernel<<<KQB + PB, 256, 0, stream>>>(
        h, Wk, Wq, W, k16, q16, hp16, N, KQB);
    binA_kernel<<<NTILE, 256, 0, stream>>>(src, dst, gcnt, ebuf, E, NBUCK);
    scan_gcnt_kernel<<<1, 256, 0, stream>>>(gcnt, gbase);
    binB_kernel<<<NBUCK, 256, 0, stream>>>(gcnt, gbase, ebuf, rowptr, srcs, N);
    score_kernel<<<(N + 63) / 64, 256, 0, stream>>>(
        rowptr, srcs, k16, q16, warr16, N, E);
    aggregate_kernel<<<(N + 3) / 4, 256, 0, stream>>>(
        rowptr, (const uint2*)warr16, srcs, hp16, b, out, N, E);
}

// Round 9
// 348.275 us; speedup vs baseline: 1.7576x; 1.0409x over previous
//
#include <hip/hip_runtime.h>
#include <hip/hip_fp16.h>
#include <math.h>

// GAT layer: N=100000, E=1600000, F=64, H=4 (Dh=16).
//
// Pipeline: fused_pre {kq GEMM (fp16, log2e in Wk) | hp GEMM (hp=h@W, fp16)}
// -> binA (bucket edges by dst>>8, LDS tile sort, coalesced appends, gcnt) ->
// scan_gcnt -> binB (per-bucket LDS counting sort; derives rowptr; srcs
// streamed coalesced) -> score (CSR row-walk, fp16 dot, w=exp2, bf16 warr16
// streaming, accumulates z_h per node -> zarr) ->
// aggregate (2 records/wave: 32 lanes x half2 per record, pk-f32 math,
// z precomputed, cross-half shfl reduce) writes FINAL out.
//
// R9: aggregate was 61% VALU with 64 lanes redundantly decoding weights and
// summing z per record. z moved to score (free: it walks rows with 4-lane
// groups, 1 add/record at 7.6% VALU); records packed 2/wave so per-record
// wave-instructions drop ~17 -> ~7 and gather instructions halve.
//
// R0-R4 law: any per-edge random-slot global store/atomic costs 100-150us.
// All scattering happens in LDS; global writes are coalesced streams.
// BCAP overflow (32-sigma for random dst) is CLAMPED (graceful, no OOB).

#define FDIM 64
#define NHEADS 4
#define TILE 8192
#define BCAP 6144

typedef float f32x2 __attribute__((ext_vector_type(2)));

// ---- K1: pure GEMM: [0,KQB) kq | [KQB,KQB+PB) hp=h@W ----
__global__ __launch_bounds__(256) void fused_pre_kernel(
    const float* __restrict__ h, const float* __restrict__ Wk,
    const float* __restrict__ Wq, const float* __restrict__ Wo,
    __half* __restrict__ k16, __half* __restrict__ q16,
    __half* __restrict__ hp16, int N, int KQB)
{
    __shared__ float sWk[FDIM * FDIM];   // kq role: Wk*log2e | hp role: Wo
    __shared__ float sWq[FDIM * FDIM];
    int bid = blockIdx.x;
    if (bid < KQB) {
        for (int i = threadIdx.x; i < FDIM * FDIM; i += 256) {
            sWk[i] = Wk[i] * 1.4426950408889634f;
            sWq[i] = Wq[i];
        }
        __syncthreads();
        int cg = threadIdx.x & 3;
        int rg = threadIdx.x >> 2;
        long base = (long)bid * 128 + rg * 2;
        const float4* sWk4 = (const float4*)sWk;
        const float4* sWq4 = (const float4*)sWq;
        const float4* h4 = (const float4*)h;
        float acck[2][16], accq[2][16];
#pragma unroll
        for (int i = 0; i < 2; ++i)
#pragma unroll
            for (int c = 0; c < 16; ++c) { acck[i][c] = 0.f; accq[i][c] = 0.f; }

        for (int fs = 0; fs < FDIM; fs += 4) {
            float4 hv[2];
#pragma unroll
            for (int i = 0; i < 2; ++i) {
                long r = base + i; if (r >= N) r = N - 1;
                hv[i] = h4[r * 16 + (fs >> 2)];
            }
#pragma unroll
            for (int fi = 0; fi < 4; ++fi) {
                int f = fs + fi;
                float4 wk0 = sWk4[f * 16 + cg * 4 + 0];
                float4 wk1 = sWk4[f * 16 + cg * 4 + 1];
                float4 wk2 = sWk4[f * 16 + cg * 4 + 2];
                float4 wk3 = sWk4[f * 16 + cg * 4 + 3];
                float4 wq0 = sWq4[f * 16 + cg * 4 + 0];
                float4 wq1 = sWq4[f * 16 + cg * 4 + 1];
                float4 wq2 = sWq4[f * 16 + cg * 4 + 2];
                float4 wq3 = sWq4[f * 16 + cg * 4 + 3];
#pragma unroll
                for (int i = 0; i < 2; ++i) {
                    float hvf = (&hv[i].x)[fi];
                    acck[i][0]  = fmaf(hvf, wk0.x, acck[i][0]);
                    acck[i][1]  = fmaf(hvf, wk0.y, acck[i][1]);
                    acck[i][2]  = fmaf(hvf, wk0.z, acck[i][2]);
                    acck[i][3]  = fmaf(hvf, wk0.w, acck[i][3]);
                    acck[i][4]  = fmaf(hvf, wk1.x, acck[i][4]);
                    acck[i][5]  = fmaf(hvf, wk1.y, acck[i][5]);
                    acck[i][6]  = fmaf(hvf, wk1.z, acck[i][6]);
                    acck[i][7]  = fmaf(hvf, wk1.w, acck[i][7]);
                    acck[i][8]  = fmaf(hvf, wk2.x, acck[i][8]);
                    acck[i][9]  = fmaf(hvf, wk2.y, acck[i][9]);
                    acck[i][10] = fmaf(hvf, wk2.z, acck[i][10]);
                    acck[i][11] = fmaf(hvf, wk2.w, acck[i][11]);
                    acck[i][12] = fmaf(hvf, wk3.x, acck[i][12]);
                    acck[i][13] = fmaf(hvf, wk3.y, acck[i][13]);
                    acck[i][14] = fmaf(hvf, wk3.z, acck[i][14]);
                    acck[i][15] = fmaf(hvf, wk3.w, acck[i][15]);
                    accq[i][0]  = fmaf(hvf, wq0.x, accq[i][0]);
                    accq[i][1]  = fmaf(hvf, wq0.y, accq[i][1]);
                    accq[i][2]  = fmaf(hvf, wq0.z, accq[i][2]);
                    accq[i][3]  = fmaf(hvf, wq0.w, accq[i][3]);
                    accq[i][4]  = fmaf(hvf, wq1.x, accq[i][4]);
                    accq[i][5]  = fmaf(hvf, wq1.y, accq[i][5]);
                    accq[i][6]  = fmaf(hvf, wq1.z, accq[i][6]);
                    accq[i][7]  = fmaf(hvf, wq1.w, accq[i][7]);
                    accq[i][8]  = fmaf(hvf, wq2.x, accq[i][8]);
                    accq[i][9]  = fmaf(hvf, wq2.y, accq[i][9]);
                    accq[i][10] = fmaf(hvf, wq2.z, accq[i][10]);
                    accq[i][11] = fmaf(hvf, wq2.w, accq[i][11]);
                    accq[i][12] = fmaf(hvf, wq3.x, accq[i][12]);
                    accq[i][13] = fmaf(hvf, wq3.y, accq[i][13]);
                    accq[i][14] = fmaf(hvf, wq3.z, accq[i][14]);
                    accq[i][15] = fmaf(hvf, wq3.w, accq[i][15]);
                }
            }
        }
#pragma unroll
        for (int i = 0; i < 2; ++i) {
            long r = base + i;
            if (r >= N) continue;
            __half2 hk[8], hq[8];
#pragma unroll
            for (int c = 0; c < 8; ++c) {
                hk[c] = __floats2half2_rn(acck[i][2 * c], acck[i][2 * c + 1]);
                hq[c] = __floats2half2_rn(accq[i][2 * c], accq[i][2 * c + 1]);
            }
            float4* kout = (float4*)(k16 + (size_t)r * FDIM + cg * 16);
            float4* qout = (float4*)(q16 + (size_t)r * FDIM + cg * 16);
            kout[0] = ((float4*)hk)[0]; kout[1] = ((float4*)hk)[1];
            qout[0] = ((float4*)hq)[0]; qout[1] = ((float4*)hq)[1];
        }
    } else {
        // --- hp role: hp = h @ Wo (fp16 out), 128 rows/block ---
        for (int i = threadIdx.x; i < FDIM * FDIM; i += 256) sWk[i] = Wo[i];
        __syncthreads();
        int cg = threadIdx.x & 3;
        int rg = threadIdx.x >> 2;
        long base = (long)(bid - KQB) * 128 + rg * 2;
        const float4* sW4 = (const float4*)sWk;
        const float4* h4 = (const float4*)h;
        float accp[2][16];
#pragma unroll
        for (int i = 0; i < 2; ++i)
#pragma unroll
            for (int c = 0; c < 16; ++c) accp[i][c] = 0.f;

        for (int fs = 0; fs < FDIM; fs += 4) {
            float4 hv[2];
#pragma unroll
            for (int i = 0; i < 2; ++i) {
                long r = base + i; if (r >= N) r = N - 1;
                hv[i] = h4[r * 16 + (fs >> 2)];
            }
#pragma unroll
            for (int fi = 0; fi < 4; ++fi) {
                int f = fs + fi;
                float4 w0 = sW4[f * 16 + cg * 4 + 0];
                float4 w1 = sW4[f * 16 + cg * 4 + 1];
                float4 w2 = sW4[f * 16 + cg * 4 + 2];
                float4 w3 = sW4[f * 16 + cg * 4 + 3];
#pragma unroll
                for (int i = 0; i < 2; ++i) {
                    float hvf = (&hv[i].x)[fi];
                    accp[i][0]  = fmaf(hvf, w0.x, accp[i][0]);
                    accp[i][1]  = fmaf(hvf, w0.y, accp[i][1]);
                    accp[i][2]  = fmaf(hvf, w0.z, accp[i][2]);
                    accp[i][3]  = fmaf(hvf, w0.w, accp[i][3]);
                    accp[i][4]  = fmaf(hvf, w1.x, accp[i][4]);
                    accp[i][5]  = fmaf(hvf, w1.y, accp[i][5]);
                    accp[i][6]  = fmaf(hvf, w1.z, accp[i][6]);
                    accp[i][7]  = fmaf(hvf, w1.w, accp[i][7]);
                    accp[i][8]  = fmaf(hvf, w2.x, accp[i][8]);
                    accp[i][9]  = fmaf(hvf, w2.y, accp[i][9]);
                    accp[i][10] = fmaf(hvf, w2.z, accp[i][10]);
                    accp[i][11] = fmaf(hvf, w2.w, accp[i][11]);
                    accp[i][12] = fmaf(hvf, w3.x, accp[i][12]);
                    accp[i][13] = fmaf(hvf, w3.y, accp[i][13]);
                    accp[i][14] = fmaf(hvf, w3.z, accp[i][14]);
                    accp[i][15] = fmaf(hvf, w3.w, accp[i][15]);
                }
            }
        }
#pragma unroll
        for (int i = 0; i < 2; ++i) {
            long r = base + i;
            if (r >= N) continue;
            __half2 hp[8];
#pragma unroll
            for (int c = 0; c < 8; ++c)
                hp[c] = __floats2half2_rn(accp[i][2 * c], accp[i][2 * c + 1]);
            float4* pout = (float4*)(hp16 + (size_t)r * FDIM + cg * 16);
            pout[0] = ((float4*)hp)[0];
            pout[1] = ((float4*)hp)[1];
        }
    }
}

// K2a: bucket-binning pass. Tile of 8192 edges -> LDS counting sort by
// bucket (dst>>8) -> per-bucket coalesced append to ebuf. Packed entry:
// src<<8 | (dst&255). Appends clamped to BCAP.
__global__ __launch_bounds__(256) void binA_kernel(
    const int* __restrict__ src, const int* __restrict__ dst,
    int* __restrict__ gcnt, unsigned int* __restrict__ ebuf,
    int E, int nbuck)
{
    __shared__ unsigned int bh[512];      // hist -> cursor
    __shared__ unsigned int bstart[512];  // stable exclusive offsets
    __shared__ unsigned int bbase[512];   // global base per bucket
    __shared__ unsigned int sd[256];
    __shared__ unsigned int ebuf_l[TILE];
    int t = threadIdx.x;
    long e0 = (long)blockIdx.x * TILE;
    int cnt_tile = (int)(((long)E - e0 < (long)TILE) ? ((long)E - e0) : (long)TILE);

    bh[t] = 0; bh[t + 256] = 0;
    __syncthreads();
    for (int j = t; j < cnt_tile; j += 256)
        atomicAdd(&bh[dst[e0 + j] >> 8], 1u);
    __syncthreads();
    unsigned int c0 = bh[2 * t], c1 = bh[2 * t + 1];
    unsigned int s = c0 + c1;
    sd[t] = s;
    __syncthreads();
    for (int off = 1; off < 256; off <<= 1) {
        unsigned int v = (t >= off) ? sd[t - off] : 0;
        __syncthreads();
        sd[t] += v;
        __syncthreads();
    }
    unsigned int ex = sd[t] - s;
    bh[2 * t] = ex;          bstart[2 * t] = ex;
    bh[2 * t + 1] = ex + c0; bstart[2 * t + 1] = ex + c0;
    if (c0 > 0) bbase[2 * t] = (unsigned int)atomicAdd(&gcnt[2 * t], (int)c0);
    if (c1 > 0) bbase[2 * t + 1] = (unsigned int)atomicAdd(&gcnt[2 * t + 1], (int)c1);
    __syncthreads();
    for (int j = t; j < cnt_tile; j += 256) {
        int d = dst[e0 + j];
        int sv = src[e0 + j];
        unsigned int pos = atomicAdd(&bh[d >> 8], 1u);
        ebuf_l[pos] = ((unsigned int)sv << 8) | (unsigned int)(d & 255);
    }
    __syncthreads();
    int wave = t >> 6, lane = t & 63;
    for (int b = wave; b < nbuck; b += 4) {
        unsigned int st = bstart[b];
        unsigned int en = bh[b];
        if (st == en) continue;
        unsigned int gb = bbase[b];
        if (gb >= (unsigned int)BCAP) continue;
        unsigned int room = (unsigned int)BCAP - gb;
        if (en - st > room) en = st + room;
        unsigned int* dstp = ebuf + (size_t)b * BCAP + gb;
        for (unsigned int j = st + lane; j < en; j += 64)
            dstp[j - st] = ebuf_l[j];
    }
}

// K2b: single-block exclusive scan of gcnt (512 entries, 2/thread) -> gbase.
__global__ __launch_bounds__(256) void scan_gcnt_kernel(
    const int* __restrict__ gcnt, int* __restrict__ gbase)
{
    __shared__ int sd[256];
    int t = threadIdx.x;
    int c0 = gcnt[2 * t], c1 = gcnt[2 * t + 1];
    int s = c0 + c1;
    sd[t] = s;
    __syncthreads();
    for (int off = 1; off < 256; off <<= 1) {
        int v = (t >= off) ? sd[t - off] : 0;
        __syncthreads();
        sd[t] += v;
        __syncthreads();
    }
    int ex = sd[t] - s;
    gbase[2 * t] = ex;
    gbase[2 * t + 1] = ex + c0;
}

// K2c: per-bucket LDS counting sort. Derives rowptr from its own LDS hist
// and streams srcs out coalesced in CSR order.
__global__ __launch_bounds__(256) void binB_kernel(
    const int* __restrict__ gcnt, const int* __restrict__ gbase,
    const unsigned int* __restrict__ ebuf, int* __restrict__ rowptr,
    int* __restrict__ srcs, int N)
{
    __shared__ unsigned int lh[256];
    __shared__ unsigned int sd[256];
    __shared__ unsigned int srcs_l[BCAP];
    int t = threadIdx.x;
    int b = blockIdx.x;
    int cnt = gcnt[b];
    if (cnt > BCAP) cnt = BCAP;   // matches binA clamp
    int n0 = b << 8;
    int gb = gbase[b];
    const unsigned int* eb = ebuf + (size_t)b * BCAP;

    lh[t] = 0;
    __syncthreads();
    for (int j = t; j < cnt; j += 256)
        atomicAdd(&lh[eb[j] & 255u], 1u);
    __syncthreads();
    unsigned int c = lh[t];
    sd[t] = c;
    __syncthreads();
    for (int off = 1; off < 256; off <<= 1) {
        unsigned int v = (t >= off) ? sd[t - off] : 0;
        __syncthreads();
        sd[t] += v;
        __syncthreads();
    }
    unsigned int excl = sd[t] - c;
    lh[t] = excl;
    if (n0 + t < N) rowptr[n0 + t] = gb + (int)excl;
    __syncthreads();
    for (int j = t; j < cnt; j += 256) {
        unsigned int p = eb[j];
        unsigned int pos = atomicAdd(&lh[p & 255u], 1u);
        srcs_l[pos] = p >> 8;
    }
    __syncthreads();
    for (int j = t; j < cnt; j += 256)
        srcs[gb + j] = (int)srcs_l[j];
}

__device__ __forceinline__ float dot16(const float4* kk, const float* qf) {
    const __half2* kh = (const __half2*)kk;
    float acc = 0.f;
#pragma unroll
    for (int j = 0; j < 8; ++j) {
        float2 kf = __half22float2(kh[j]);
        acc = fmaf(kf.x, qf[2 * j], acc);
        acc = fmaf(kf.y, qf[2 * j + 1], acc);
    }
    return acc;
}

__device__ __forceinline__ unsigned short bf16_rne(float x) {
    unsigned int u = __float_as_uint(x);
    return (unsigned short)((u + 0x7fffu + ((u >> 16) & 1u)) >> 16);
}

// K3: score, CSR row-walk. 4-lane group = node (lane hh = head). q-row loaded
// once per node; per record gather k16[src], fp16 dot, w=exp2(e'),
// bf16 weight stored STREAMING at warr16[4i+hh]. Accumulates z_h (sum of the
// ROUNDED weights, matching what aggregate decodes) -> zarr[n*4+hh]
// (coalesced: block covers contiguous (n,hh) range).
__global__ __launch_bounds__(256) void score_kernel(
    const int* __restrict__ rowptr, const int* __restrict__ srcs,
    const __half* __restrict__ k16, const __half* __restrict__ q16,
    unsigned short* __restrict__ warr16, float* __restrict__ zarr,
    int N, int E)
{
    int hh = threadIdx.x & 3;
    int n = blockIdx.x * 64 + (threadIdx.x >> 2);
    if (n >= N) return;
    int start = rowptr[n];
    int end   = (n == N - 1) ? E : rowptr[n + 1];

    const float4* qp = (const float4*)(q16 + (size_t)n * FDIM + hh * 16);
    float4 qv[2] = { qp[0], qp[1] };
    const __half2* qh = (const __half2*)qv;
    float qf[16];
#pragma unroll
    for (int j = 0; j < 8; ++j) {
        float2 f = __half22float2(qh[j]);
        qf[2 * j] = f.x;
        qf[2 * j + 1] = f.y;
    }

    float zacc = 0.f;
    int i = start;
    for (; i + 1 < end; i += 2) {
        int s0 = srcs[i], s1 = srcs[i + 1];
        const float4* kp0 = (const float4*)(k16 + (size_t)s0 * FDIM + hh * 16);
        const float4* kp1 = (const float4*)(k16 + (size_t)s1 * FDIM + hh * 16);
        float4 ka[2] = { kp0[0], kp0[1] };
        float4 kb[2] = { kp1[0], kp1[1] };
        float w0 = __builtin_amdgcn_exp2f(dot16(ka, qf));
        float w1 = __builtin_amdgcn_exp2f(dot16(kb, qf));
        unsigned short r0 = bf16_rne(w0);
        unsigned short r1 = bf16_rne(w1);
        warr16[(size_t)i * 4 + hh] = r0;
        warr16[(size_t)(i + 1) * 4 + hh] = r1;
        zacc += __uint_as_float((unsigned int)r0 << 16);
        zacc += __uint_as_float((unsigned int)r1 << 16);
    }
    if (i < end) {
        int s0 = srcs[i];
        const float4* kp0 = (const float4*)(k16 + (size_t)s0 * FDIM + hh * 16);
        float4 ka[2] = { kp0[0], kp0[1] };
        float w0 = __builtin_amdgcn_exp2f(dot16(ka, qf));
        unsigned short r0 = bf16_rne(w0);
        warr16[(size_t)i * 4 + hh] = r0;
        zacc += __uint_as_float((unsigned int)r0 << 16);
    }
    zarr[(size_t)n * 4 + hh] = zacc;
}

// K4: gather aggregation -> FINAL out. One wave per node; 32 lanes per
// record (lane fl handles features 2fl,2fl+1 via half2), wave processes 2
// records at once (half = record parity). z precomputed by score. Per
// record: 4 bf16 decode + 2 cvt + 4 pk-fma, shared over 2 records/wave.
// Epilogue: cross-half shfl_xor reduce, 32-lane float2 stores.
__global__ __launch_bounds__(256) void aggregate_kernel(
    const int* __restrict__ rowptr, const uint2* __restrict__ wp,
    const int* __restrict__ srcs, const __half* __restrict__ hp16,
    const float* __restrict__ zarr, const float* __restrict__ bvec,
    float* __restrict__ out, int N, int E)
{
    int lane = threadIdx.x & 63;
    int n = blockIdx.x * 4 + (threadIdx.x >> 6);
    if (n >= N) return;
    int start = rowptr[n];
    int end   = (n == N - 1) ? E : rowptr[n + 1];
    int half = lane >> 5;     // record parity handled by this lane
    int fl   = lane & 31;     // feature pair: 2fl, 2fl+1

    f32x2 a0 = {0.f, 0.f}, a1 = {0.f, 0.f}, a2 = {0.f, 0.f}, a3 = {0.f, 0.f};

#define AGG2(WW, G)                                                        \
    {   float2 f2_ = __half22float2(G);                                    \
        f32x2 hv_; hv_.x = f2_.x; hv_.y = f2_.y;                           \
        float w0_ = __uint_as_float((WW).x << 16);                         \
        float w1_ = __uint_as_float((WW).x & 0xffff0000u);                 \
        float w2_ = __uint_as_float((WW).y << 16);                         \
        float w3_ = __uint_as_float((WW).y & 0xffff0000u);                 \
        f32x2 wv_;                                                         \
        wv_.x = w0_; wv_.y = w0_; a0 = __builtin_elementwise_fma(wv_, hv_, a0); \
        wv_.x = w1_; wv_.y = w1_; a1 = __builtin_elementwise_fma(wv_, hv_, a1); \
        wv_.x = w2_; wv_.y = w2_; a2 = __builtin_elementwise_fma(wv_, hv_, a2); \
        wv_.x = w3_; wv_.y = w3_; a3 = __builtin_elementwise_fma(wv_, hv_, a3); }

    int base = start;
    for (; base + 8 <= end; base += 8) {
        int i0 = base + half;              // records i0, i0+2, i0+4, i0+6
        int s0 = srcs[i0],     s1 = srcs[i0 + 2];
        int s2 = srcs[i0 + 4], s3 = srcs[i0 + 6];
        uint2 ww0 = wp[i0],     ww1 = wp[i0 + 2];
        uint2 ww2 = wp[i0 + 4], ww3 = wp[i0 + 6];
        __half2 g0 = *((const __half2*)(hp16 + (size_t)s0 * FDIM) + fl);
        __half2 g1 = *((const __half2*)(hp16 + (size_t)s1 * FDIM) + fl);
        __half2 g2 = *((const __half2*)(hp16 + (size_t)s2 * FDIM) + fl);
        __half2 g3 = *((const __half2*)(hp16 + (size_t)s3 * FDIM) + fl);
        AGG2(ww0, g0);
        AGG2(ww1, g1);
        AGG2(ww2, g2);
        AGG2(ww3, g3);
    }
    for (; base < end; base += 2) {
        int i0 = base + half;
        bool valid = (i0 < end);
        int ic = valid ? i0 : base;        // base < end here, safe
        int s0 = srcs[ic];
        uint2 ww0 = wp[ic];
        if (!valid) { ww0.x = 0u; ww0.y = 0u; }   // decodes to w=0
        __half2 g0 = *((const __half2*)(hp16 + (size_t)s0 * FDIM) + fl);
        AGG2(ww0, g0);
    }
#undef AGG2

    // merge the two record-parity partial sums (lane l <-> l^32)
    a0.x += __shfl_xor(a0.x, 32, 64); a0.y += __shfl_xor(a0.y, 32, 64);
    a1.x += __shfl_xor(a1.x, 32, 64); a1.y += __shfl_xor(a1.y, 32, 64);
    a2.x += __shfl_xor(a2.x, 32, 64); a2.y += __shfl_xor(a2.y, 32, 64);
    a3.x += __shfl_xor(a3.x, 32, 64); a3.y += __shfl_xor(a3.y, 32, 64);

    if (half != 0) return;
    float bv0 = bvec[2 * fl], bv1 = bvec[2 * fl + 1];
    float2* o = (float2*)(out + (size_t)n * (NHEADS * FDIM));
    if (end > start) {
        const float* zp = zarr + (size_t)n * 4;
        float rz0 = 1.f / zp[0];
        float rz1 = 1.f / zp[1];
        float rz2 = 1.f / zp[2];
        float rz3 = 1.f / zp[3];
        o[fl]      = make_float2(fmaf(a0.x, rz0, bv0), fmaf(a0.y, rz0, bv1));
        o[32 + fl] = make_float2(fmaf(a1.x, rz1, bv0), fmaf(a1.y, rz1, bv1));
        o[64 + fl] = make_float2(fmaf(a2.x, rz2, bv0), fmaf(a2.y, rz2, bv1));
        o[96 + fl] = make_float2(fmaf(a3.x, rz3, bv0), fmaf(a3.y, rz3, bv1));
    } else {
        float2 bz = make_float2(bv0, bv1);
        o[fl] = bz; o[32 + fl] = bz; o[64 + fl] = bz; o[96 + fl] = bz;
    }
}

extern "C" void kernel_launch(void* const* d_in, const int* in_sizes, int n_in,
                              void* d_out, int out_size, void* d_ws, size_t ws_size,
                              hipStream_t stream) {
    const float* h   = (const float*)d_in[0];
    const int*   src = (const int*)d_in[1];
    const int*   dst = (const int*)d_in[2];
    const float* Wk  = (const float*)d_in[3];
    const float* Wq  = (const float*)d_in[4];
    const float* W   = (const float*)d_in[5];
    const float* b   = (const float*)d_in[6];
    float* out = (float*)d_out;

    const int N = in_sizes[0] / FDIM;   // 100000
    const int E = in_sizes[1];          // 1600000

    // Workspace: k16 12.8MB, q16 12.8MB, hp16 12.8MB,
    //            warr16[E*4 ushort] 12.8MB (ebuf 9.6MB ALIASES this region;
    //            ebuf dead before score writes warr16),
    //            srcs[E] 6.4MB, gcnt[512], gbase[512], rowptr[N],
    //            zarr[N*4 f32] 1.6MB.  (~60 MB)
    __half* k16 = (__half*)d_ws;
    __half* q16 = k16 + (size_t)N * FDIM;
    __half* hp16 = q16 + (size_t)N * FDIM;
    unsigned short* warr16 = (unsigned short*)(hp16 + (size_t)N * FDIM);
    unsigned int* ebuf = (unsigned int*)warr16;   // alias (binA/binB only)
    int* srcs   = (int*)(warr16 + (size_t)E * 4);
    int* gcnt   = srcs + E;
    int* gbase  = gcnt + 512;
    int* rowptr = gbase + 512;
    float* zarr = (float*)(rowptr + N);

    const int KQB   = (N + 127) / 128;              // 782
    const int PB    = (N + 127) / 128;              // 782 (hp role)
    const int NBUCK = (N + 255) >> 8;               // 391
    const int NTILE = (E + TILE - 1) / TILE;        // 196

    hipMemsetAsync(gcnt, 0, 512 * sizeof(int), stream);

    fused_pre_kernel<<<KQB + PB, 256, 0, stream>>>(
        h, Wk, Wq, W, k16, q16, hp16, N, KQB);
    binA_kernel<<<NTILE, 256, 0, stream>>>(src, dst, gcnt, ebuf, E, NBUCK);
    scan_gcnt_kernel<<<1, 256, 0, stream>>>(gcnt, gbase);
    binB_kernel<<<NBUCK, 256, 0, stream>>>(gcnt, gbase, ebuf, rowptr, srcs, N);
    score_kernel<<<(N + 63) / 64, 256, 0, stream>>>(
        rowptr, srcs, k16, q16, warr16, zarr, N, E);
    aggregate_kernel<<<(N + 3) / 4, 256, 0, stream>>>(
        rowptr, (const uint2*)warr16, srcs, hp16, zarr, b, out, N, E);
}

// Round 10
// 344.655 us; speedup vs baseline: 1.7761x; 1.0105x over previous
//
#include <hip/hip_runtime.h>
#include <hip/hip_fp16.h>
#include <math.h>

// GAT layer: N=100000, E=1600000, F=64, H=4 (Dh=16).
//
// Pipeline: fused_pre {kq GEMM (fp16, log2e in Wk) | hp GEMM (hp=h@W, fp16)}
// -> binA (bucket edges by dst>>8, LDS tile sort, coalesced appends, gcnt) ->
// scan_gcnt -> binB (per-bucket LDS counting sort; derives rowptr; srcs
// streamed coalesced) -> fused_sa: score+aggregate in ONE wave-per-node pass:
//   phase A (chunk of 16 records): lane=(record rr, head hh) computes the
//     full fp16 dot k16[src].q16[n] edge-parallel (no cross-lane reduce,
//     the R3 trap) -> w = exp2(e') held in a REGISTER;
//   phase B: R9's parity-packed PV (32 lanes x half2, 2 records/wave-inst),
//     weights fetched from phase-A lanes via __shfl (ds_bpermute, no LDS,
//     no barrier); z folds with 4 shfl_xor per node. Writes FINAL out.
// Tail slots clamp gather index to end-1 (same cache line as a real record)
// with w=0, so phase B needs no tail branches beyond an 8-granule skip.
//
// R10 deletes: warr16 write+read (25.6MB), zarr round-trip, second srcs
// pass, one launch; weights stay f32 (no bf16 round/decode); k-gather
// latency overlaps PV compute within the wave.
//
// R0-R4 law: any per-edge random-slot global store/atomic costs 100-150us.
// All scattering happens in LDS; global writes are coalesced streams.
// BCAP overflow (32-sigma for random dst) is CLAMPED (graceful, no OOB).

#define FDIM 64
#define NHEADS 4
#define TILE 8192
#define BCAP 6144

typedef float f32x2 __attribute__((ext_vector_type(2)));

// ---- K1: pure GEMM: [0,KQB) kq | [KQB,KQB+PB) hp=h@W ----
__global__ __launch_bounds__(256) void fused_pre_kernel(
    const float* __restrict__ h, const float* __restrict__ Wk,
    const float* __restrict__ Wq, const float* __restrict__ Wo,
    __half* __restrict__ k16, __half* __restrict__ q16,
    __half* __restrict__ hp16, int N, int KQB)
{
    __shared__ float sWk[FDIM * FDIM];   // kq role: Wk*log2e | hp role: Wo
    __shared__ float sWq[FDIM * FDIM];
    int bid = blockIdx.x;
    if (bid < KQB) {
        for (int i = threadIdx.x; i < FDIM * FDIM; i += 256) {
            sWk[i] = Wk[i] * 1.4426950408889634f;
            sWq[i] = Wq[i];
        }
        __syncthreads();
        int cg = threadIdx.x & 3;
        int rg = threadIdx.x >> 2;
        long base = (long)bid * 128 + rg * 2;
        const float4* sWk4 = (const float4*)sWk;
        const float4* sWq4 = (const float4*)sWq;
        const float4* h4 = (const float4*)h;
        float acck[2][16], accq[2][16];
#pragma unroll
        for (int i = 0; i < 2; ++i)
#pragma unroll
            for (int c = 0; c < 16; ++c) { acck[i][c] = 0.f; accq[i][c] = 0.f; }

        for (int fs = 0; fs < FDIM; fs += 4) {
            float4 hv[2];
#pragma unroll
            for (int i = 0; i < 2; ++i) {
                long r = base + i; if (r >= N) r = N - 1;
                hv[i] = h4[r * 16 + (fs >> 2)];
            }
#pragma unroll
            for (int fi = 0; fi < 4; ++fi) {
                int f = fs + fi;
                float4 wk0 = sWk4[f * 16 + cg * 4 + 0];
                float4 wk1 = sWk4[f * 16 + cg * 4 + 1];
                float4 wk2 = sWk4[f * 16 + cg * 4 + 2];
                float4 wk3 = sWk4[f * 16 + cg * 4 + 3];
                float4 wq0 = sWq4[f * 16 + cg * 4 + 0];
                float4 wq1 = sWq4[f * 16 + cg * 4 + 1];
                float4 wq2 = sWq4[f * 16 + cg * 4 + 2];
                float4 wq3 = sWq4[f * 16 + cg * 4 + 3];
#pragma unroll
                for (int i = 0; i < 2; ++i) {
                    float hvf = (&hv[i].x)[fi];
                    acck[i][0]  = fmaf(hvf, wk0.x, acck[i][0]);
                    acck[i][1]  = fmaf(hvf, wk0.y, acck[i][1]);
                    acck[i][2]  = fmaf(hvf, wk0.z, acck[i][2]);
                    acck[i][3]  = fmaf(hvf, wk0.w, acck[i][3]);
                    acck[i][4]  = fmaf(hvf, wk1.x, acck[i][4]);
                    acck[i][5]  = fmaf(hvf, wk1.y, acck[i][5]);
                    acck[i][6]  = fmaf(hvf, wk1.z, acck[i][6]);
                    acck[i][7]  = fmaf(hvf, wk1.w, acck[i][7]);
                    acck[i][8]  = fmaf(hvf, wk2.x, acck[i][8]);
                    acck[i][9]  = fmaf(hvf, wk2.y, acck[i][9]);
                    acck[i][10] = fmaf(hvf, wk2.z, acck[i][10]);
                    acck[i][11] = fmaf(hvf, wk2.w, acck[i][11]);
                    acck[i][12] = fmaf(hvf, wk3.x, acck[i][12]);
                    acck[i][13] = fmaf(hvf, wk3.y, acck[i][13]);
                    acck[i][14] = fmaf(hvf, wk3.z, acck[i][14]);
                    acck[i][15] = fmaf(hvf, wk3.w, acck[i][15]);
                    accq[i][0]  = fmaf(hvf, wq0.x, accq[i][0]);
                    accq[i][1]  = fmaf(hvf, wq0.y, accq[i][1]);
                    accq[i][2]  = fmaf(hvf, wq0.z, accq[i][2]);
                    accq[i][3]  = fmaf(hvf, wq0.w, accq[i][3]);
                    accq[i][4]  = fmaf(hvf, wq1.x, accq[i][4]);
                    accq[i][5]  = fmaf(hvf, wq1.y, accq[i][5]);
                    accq[i][6]  = fmaf(hvf, wq1.z, accq[i][6]);
                    accq[i][7]  = fmaf(hvf, wq1.w, accq[i][7]);
                    accq[i][8]  = fmaf(hvf, wq2.x, accq[i][8]);
                    accq[i][9]  = fmaf(hvf, wq2.y, accq[i][9]);
                    accq[i][10] = fmaf(hvf, wq2.z, accq[i][10]);
                    accq[i][11] = fmaf(hvf, wq2.w, accq[i][11]);
                    accq[i][12] = fmaf(hvf, wq3.x, accq[i][12]);
                    accq[i][13] = fmaf(hvf, wq3.y, accq[i][13]);
                    accq[i][14] = fmaf(hvf, wq3.z, accq[i][14]);
                    accq[i][15] = fmaf(hvf, wq3.w, accq[i][15]);
                }
            }
        }
#pragma unroll
        for (int i = 0; i < 2; ++i) {
            long r = base + i;
            if (r >= N) continue;
            __half2 hk[8], hq[8];
#pragma unroll
            for (int c = 0; c < 8; ++c) {
                hk[c] = __floats2half2_rn(acck[i][2 * c], acck[i][2 * c + 1]);
                hq[c] = __floats2half2_rn(accq[i][2 * c], accq[i][2 * c + 1]);
            }
            float4* kout = (float4*)(k16 + (size_t)r * FDIM + cg * 16);
            float4* qout = (float4*)(q16 + (size_t)r * FDIM + cg * 16);
            kout[0] = ((float4*)hk)[0]; kout[1] = ((float4*)hk)[1];
            qout[0] = ((float4*)hq)[0]; qout[1] = ((float4*)hq)[1];
        }
    } else {
        // --- hp role: hp = h @ Wo (fp16 out), 128 rows/block ---
        for (int i = threadIdx.x; i < FDIM * FDIM; i += 256) sWk[i] = Wo[i];
        __syncthreads();
        int cg = threadIdx.x & 3;
        int rg = threadIdx.x >> 2;
        long base = (long)(bid - KQB) * 128 + rg * 2;
        const float4* sW4 = (const float4*)sWk;
        const float4* h4 = (const float4*)h;
        float accp[2][16];
#pragma unroll
        for (int i = 0; i < 2; ++i)
#pragma unroll
            for (int c = 0; c < 16; ++c) accp[i][c] = 0.f;

        for (int fs = 0; fs < FDIM; fs += 4) {
            float4 hv[2];
#pragma unroll
            for (int i = 0; i < 2; ++i) {
                long r = base + i; if (r >= N) r = N - 1;
                hv[i] = h4[r * 16 + (fs >> 2)];
            }
#pragma unroll
            for (int fi = 0; fi < 4; ++fi) {
                int f = fs + fi;
                float4 w0 = sW4[f * 16 + cg * 4 + 0];
                float4 w1 = sW4[f * 16 + cg * 4 + 1];
                float4 w2 = sW4[f * 16 + cg * 4 + 2];
                float4 w3 = sW4[f * 16 + cg * 4 + 3];
#pragma unroll
                for (int i = 0; i < 2; ++i) {
                    float hvf = (&hv[i].x)[fi];
                    accp[i][0]  = fmaf(hvf, w0.x, accp[i][0]);
                    accp[i][1]  = fmaf(hvf, w0.y, accp[i][1]);
                    accp[i][2]  = fmaf(hvf, w0.z, accp[i][2]);
                    accp[i][3]  = fmaf(hvf, w0.w, accp[i][3]);
                    accp[i][4]  = fmaf(hvf, w1.x, accp[i][4]);
                    accp[i][5]  = fmaf(hvf, w1.y, accp[i][5]);
                    accp[i][6]  = fmaf(hvf, w1.z, accp[i][6]);
                    accp[i][7]  = fmaf(hvf, w1.w, accp[i][7]);
                    accp[i][8]  = fmaf(hvf, w2.x, accp[i][8]);
                    accp[i][9]  = fmaf(hvf, w2.y, accp[i][9]);
                    accp[i][10] = fmaf(hvf, w2.z, accp[i][10]);
                    accp[i][11] = fmaf(hvf, w2.w, accp[i][11]);
                    accp[i][12] = fmaf(hvf, w3.x, accp[i][12]);
                    accp[i][13] = fmaf(hvf, w3.y, accp[i][13]);
                    accp[i][14] = fmaf(hvf, w3.z, accp[i][14]);
                    accp[i][15] = fmaf(hvf, w3.w, accp[i][15]);
                }
            }
        }
#pragma unroll
        for (int i = 0; i < 2; ++i) {
            long r = base + i;
            if (r >= N) continue;
            __half2 hp[8];
#pragma unroll
            for (int c = 0; c < 8; ++c)
                hp[c] = __floats2half2_rn(accp[i][2 * c], accp[i][2 * c + 1]);
            float4* pout = (float4*)(hp16 + (size_t)r * FDIM + cg * 16);
            pout[0] = ((float4*)hp)[0];
            pout[1] = ((float4*)hp)[1];
        }
    }
}

// K2a: bucket-binning pass. Tile of 8192 edges -> LDS counting sort by
// bucket (dst>>8) -> per-bucket coalesced append to ebuf. Packed entry:
// src<<8 | (dst&255). Appends clamped to BCAP.
__global__ __launch_bounds__(256) void binA_kernel(
    const int* __restrict__ src, const int* __restrict__ dst,
    int* __restrict__ gcnt, unsigned int* __restrict__ ebuf,
    int E, int nbuck)
{
    __shared__ unsigned int bh[512];      // hist -> cursor
    __shared__ unsigned int bstart[512];  // stable exclusive offsets
    __shared__ unsigned int bbase[512];   // global base per bucket
    __shared__ unsigned int sd[256];
    __shared__ unsigned int ebuf_l[TILE];
    int t = threadIdx.x;
    long e0 = (long)blockIdx.x * TILE;
    int cnt_tile = (int)(((long)E - e0 < (long)TILE) ? ((long)E - e0) : (long)TILE);

    bh[t] = 0; bh[t + 256] = 0;
    __syncthreads();
    for (int j = t; j < cnt_tile; j += 256)
        atomicAdd(&bh[dst[e0 + j] >> 8], 1u);
    __syncthreads();
    unsigned int c0 = bh[2 * t], c1 = bh[2 * t + 1];
    unsigned int s = c0 + c1;
    sd[t] = s;
    __syncthreads();
    for (int off = 1; off < 256; off <<= 1) {
        unsigned int v = (t >= off) ? sd[t - off] : 0;
        __syncthreads();
        sd[t] += v;
        __syncthreads();
    }
    unsigned int ex = sd[t] - s;
    bh[2 * t] = ex;          bstart[2 * t] = ex;
    bh[2 * t + 1] = ex + c0; bstart[2 * t + 1] = ex + c0;
    if (c0 > 0) bbase[2 * t] = (unsigned int)atomicAdd(&gcnt[2 * t], (int)c0);
    if (c1 > 0) bbase[2 * t + 1] = (unsigned int)atomicAdd(&gcnt[2 * t + 1], (int)c1);
    __syncthreads();
    for (int j = t; j < cnt_tile; j += 256) {
        int d = dst[e0 + j];
        int sv = src[e0 + j];
        unsigned int pos = atomicAdd(&bh[d >> 8], 1u);
        ebuf_l[pos] = ((unsigned int)sv << 8) | (unsigned int)(d & 255);
    }
    __syncthreads();
    int wave = t >> 6, lane = t & 63;
    for (int b = wave; b < nbuck; b += 4) {
        unsigned int st = bstart[b];
        unsigned int en = bh[b];
        if (st == en) continue;
        unsigned int gb = bbase[b];
        if (gb >= (unsigned int)BCAP) continue;
        unsigned int room = (unsigned int)BCAP - gb;
        if (en - st > room) en = st + room;
        unsigned int* dstp = ebuf + (size_t)b * BCAP + gb;
        for (unsigned int j = st + lane; j < en; j += 64)
            dstp[j - st] = ebuf_l[j];
    }
}

// K2b: single-block exclusive scan of gcnt (512 entries, 2/thread) -> gbase.
__global__ __launch_bounds__(256) void scan_gcnt_kernel(
    const int* __restrict__ gcnt, int* __restrict__ gbase)
{
    __shared__ int sd[256];
    int t = threadIdx.x;
    int c0 = gcnt[2 * t], c1 = gcnt[2 * t + 1];
    int s = c0 + c1;
    sd[t] = s;
    __syncthreads();
    for (int off = 1; off < 256; off <<= 1) {
        int v = (t >= off) ? sd[t - off] : 0;
        __syncthreads();
        sd[t] += v;
        __syncthreads();
    }
    int ex = sd[t] - s;
    gbase[2 * t] = ex;
    gbase[2 * t + 1] = ex + c0;
}

// K2c: per-bucket LDS counting sort. Derives rowptr from its own LDS hist
// and streams srcs out coalesced in CSR order.
__global__ __launch_bounds__(256) void binB_kernel(
    const int* __restrict__ gcnt, const int* __restrict__ gbase,
    const unsigned int* __restrict__ ebuf, int* __restrict__ rowptr,
    int* __restrict__ srcs, int N)
{
    __shared__ unsigned int lh[256];
    __shared__ unsigned int sd[256];
    __shared__ unsigned int srcs_l[BCAP];
    int t = threadIdx.x;
    int b = blockIdx.x;
    int cnt = gcnt[b];
    if (cnt > BCAP) cnt = BCAP;   // matches binA clamp
    int n0 = b << 8;
    int gb = gbase[b];
    const unsigned int* eb = ebuf + (size_t)b * BCAP;

    lh[t] = 0;
    __syncthreads();
    for (int j = t; j < cnt; j += 256)
        atomicAdd(&lh[eb[j] & 255u], 1u);
    __syncthreads();
    unsigned int c = lh[t];
    sd[t] = c;
    __syncthreads();
    for (int off = 1; off < 256; off <<= 1) {
        unsigned int v = (t >= off) ? sd[t - off] : 0;
        __syncthreads();
        sd[t] += v;
        __syncthreads();
    }
    unsigned int excl = sd[t] - c;
    lh[t] = excl;
    if (n0 + t < N) rowptr[n0 + t] = gb + (int)excl;
    __syncthreads();
    for (int j = t; j < cnt; j += 256) {
        unsigned int p = eb[j];
        unsigned int pos = atomicAdd(&lh[p & 255u], 1u);
        srcs_l[pos] = p >> 8;
    }
    __syncthreads();
    for (int j = t; j < cnt; j += 256)
        srcs[gb + j] = (int)srcs_l[j];
}

__device__ __forceinline__ float dot16(const float4* kk, const float* qf) {
    const __half2* kh = (const __half2*)kk;
    float acc = 0.f;
#pragma unroll
    for (int j = 0; j < 8; ++j) {
        float2 kf = __half22float2(kh[j]);
        acc = fmaf(kf.x, qf[2 * j], acc);
        acc = fmaf(kf.y, qf[2 * j + 1], acc);
    }
    return acc;
}

__device__ __forceinline__ void agg2f(
    float w0, float w1, float w2, float w3, __half2 g,
    f32x2& a0, f32x2& a1, f32x2& a2, f32x2& a3)
{
    float2 f2 = __half22float2(g);
    f32x2 hv; hv.x = f2.x; hv.y = f2.y;
    f32x2 wv;
    wv.x = w0; wv.y = w0; a0 = __builtin_elementwise_fma(wv, hv, a0);
    wv.x = w1; wv.y = w1; a1 = __builtin_elementwise_fma(wv, hv, a1);
    wv.x = w2; wv.y = w2; a2 = __builtin_elementwise_fma(wv, hv, a2);
    wv.x = w3; wv.y = w3; a3 = __builtin_elementwise_fma(wv, hv, a3);
}

// K3: fused score+aggregate. One wave per node (4 waves/block).
// Per 16-record chunk:
//   phase A: lane = (rr=record, hh=head) computes w = exp2(k16[src].q)
//            edge-parallel, f32 weight stays in a register; z += w.
//   phase B: 32 lanes x half2 features, 2 records per wave-inst (parity);
//            weights fetched from phase-A lanes via __shfl (ds_bpermute).
// Tail slots clamp gather index to end-1 (same cache line, free) with w=0.
__global__ __launch_bounds__(256) void fused_sa_kernel(
    const int* __restrict__ rowptr, const int* __restrict__ srcs,
    const __half* __restrict__ k16, const __half* __restrict__ q16,
    const __half* __restrict__ hp16, const float* __restrict__ bvec,
    float* __restrict__ out, int N, int E)
{
    int lane = threadIdx.x & 63;
    int n = blockIdx.x * 4 + (threadIdx.x >> 6);
    if (n >= N) return;
    int start = rowptr[n];
    int end   = (n == N - 1) ? E : rowptr[n + 1];

    int hh   = lane & 3;    // phase A: head
    int rr   = lane >> 2;   // phase A: record slot 0..15
    int half = lane >> 5;   // phase B: record parity
    int fl   = lane & 31;   // phase B: feature pair 2fl, 2fl+1

    // q fragment for head hh (redundant across rr groups; cache-served)
    const float4* qp = (const float4*)(q16 + (size_t)n * FDIM + hh * 16);
    float4 qv[2] = { qp[0], qp[1] };
    const __half2* qh = (const __half2*)qv;
    float qf[16];
#pragma unroll
    for (int j = 0; j < 8; ++j) {
        float2 f = __half22float2(qh[j]);
        qf[2 * j] = f.x;
        qf[2 * j + 1] = f.y;
    }

    float zacc = 0.f;
    f32x2 a0 = {0.f, 0.f}, a1 = {0.f, 0.f}, a2 = {0.f, 0.f}, a3 = {0.f, 0.f};

    for (int base = start; base < end; base += 16) {
        // ---- phase A ----
        int idx = base + rr;
        bool valid = (idx < end);
        int ic = valid ? idx : (end - 1);
        int sA = srcs[ic];
        const float4* kp = (const float4*)(k16 + (size_t)sA * FDIM + hh * 16);
        float4 ka[2] = { kp[0], kp[1] };
        float w = __builtin_amdgcn_exp2f(dot16(ka, qf));
        w = valid ? w : 0.f;
        zacc += w;

        // ---- phase B: two 8-record groups ----
#pragma unroll
        for (int j = 0; j < 2; ++j) {
            int g0i = base + j * 8;
            if (g0i < end) {
                int i0 = g0i + half;
                int t0 = (i0     < end) ? i0     : end - 1;
                int t1 = (i0 + 2 < end) ? i0 + 2 : end - 1;
                int t2 = (i0 + 4 < end) ? i0 + 4 : end - 1;
                int t3 = (i0 + 6 < end) ? i0 + 6 : end - 1;
                int s0 = srcs[t0], s1 = srcs[t1], s2 = srcs[t2], s3 = srcs[t3];
                __half2 g0 = *((const __half2*)(hp16 + (size_t)s0 * FDIM) + fl);
                __half2 g1 = *((const __half2*)(hp16 + (size_t)s1 * FDIM) + fl);
                __half2 g2 = *((const __half2*)(hp16 + (size_t)s2 * FDIM) + fl);
                __half2 g3 = *((const __half2*)(hp16 + (size_t)s3 * FDIM) + fl);
                int rb = j * 8 + half;   // local record index of this half's 1st record
                float wa0 = __shfl(w, (rb + 0) * 4 + 0, 64);
                float wa1 = __shfl(w, (rb + 0) * 4 + 1, 64);
                float wa2 = __shfl(w, (rb + 0) * 4 + 2, 64);
                float wa3 = __shfl(w, (rb + 0) * 4 + 3, 64);
                agg2f(wa0, wa1, wa2, wa3, g0, a0, a1, a2, a3);
                float wb0 = __shfl(w, (rb + 2) * 4 + 0, 64);
                float wb1 = __shfl(w, (rb + 2) * 4 + 1, 64);
                float wb2 = __shfl(w, (rb + 2) * 4 + 2, 64);
                float wb3 = __shfl(w, (rb + 2) * 4 + 3, 64);
                agg2f(wb0, wb1, wb2, wb3, g1, a0, a1, a2, a3);
                float wc0 = __shfl(w, (rb + 4) * 4 + 0, 64);
                float wc1 = __shfl(w, (rb + 4) * 4 + 1, 64);
                float wc2 = __shfl(w, (rb + 4) * 4 + 2, 64);
                float wc3 = __shfl(w, (rb + 4) * 4 + 3, 64);
                agg2f(wc0, wc1, wc2, wc3, g2, a0, a1, a2, a3);
                float wd0 = __shfl(w, (rb + 6) * 4 + 0, 64);
                float wd1 = __shfl(w, (rb + 6) * 4 + 1, 64);
                float wd2 = __shfl(w, (rb + 6) * 4 + 2, 64);
                float wd3 = __shfl(w, (rb + 6) * 4 + 3, 64);
                agg2f(wd0, wd1, wd2, wd3, g3, a0, a1, a2, a3);
            }
        }
    }

    // fold z over record slots (lanes sharing hh differ in bits 2..5)
    zacc += __shfl_xor(zacc, 4, 64);
    zacc += __shfl_xor(zacc, 8, 64);
    zacc += __shfl_xor(zacc, 16, 64);
    zacc += __shfl_xor(zacc, 32, 64);
    float z0 = __shfl(zacc, 0, 64);
    float z1 = __shfl(zacc, 1, 64);
    float z2 = __shfl(zacc, 2, 64);
    float z3 = __shfl(zacc, 3, 64);

    // merge the two record-parity partial sums (lane l <-> l^32)
    a0.x += __shfl_xor(a0.x, 32, 64); a0.y += __shfl_xor(a0.y, 32, 64);
    a1.x += __shfl_xor(a1.x, 32, 64); a1.y += __shfl_xor(a1.y, 32, 64);
    a2.x += __shfl_xor(a2.x, 32, 64); a2.y += __shfl_xor(a2.y, 32, 64);
    a3.x += __shfl_xor(a3.x, 32, 64); a3.y += __shfl_xor(a3.y, 32, 64);

    if (half != 0) return;
    float bv0 = bvec[2 * fl], bv1 = bvec[2 * fl + 1];
    float2* o = (float2*)(out + (size_t)n * (NHEADS * FDIM));
    if (end > start) {
        float rz0 = 1.f / z0;
        float rz1 = 1.f / z1;
        float rz2 = 1.f / z2;
        float rz3 = 1.f / z3;
        o[fl]      = make_float2(fmaf(a0.x, rz0, bv0), fmaf(a0.y, rz0, bv1));
        o[32 + fl] = make_float2(fmaf(a1.x, rz1, bv0), fmaf(a1.y, rz1, bv1));
        o[64 + fl] = make_float2(fmaf(a2.x, rz2, bv0), fmaf(a2.y, rz2, bv1));
        o[96 + fl] = make_float2(fmaf(a3.x, rz3, bv0), fmaf(a3.y, rz3, bv1));
    } else {
        float2 bz = make_float2(bv0, bv1);
        o[fl] = bz; o[32 + fl] = bz; o[64 + fl] = bz; o[96 + fl] = bz;
    }
}

extern "C" void kernel_launch(void* const* d_in, const int* in_sizes, int n_in,
                              void* d_out, int out_size, void* d_ws, size_t ws_size,
                              hipStream_t stream) {
    const float* h   = (const float*)d_in[0];
    const int*   src = (const int*)d_in[1];
    const int*   dst = (const int*)d_in[2];
    const float* Wk  = (const float*)d_in[3];
    const float* Wq  = (const float*)d_in[4];
    const float* W   = (const float*)d_in[5];
    const float* b   = (const float*)d_in[6];
    float* out = (float*)d_out;

    const int N = in_sizes[0] / FDIM;   // 100000
    const int E = in_sizes[1];          // 1600000

    const int NBUCK = (N + 255) >> 8;               // 391
    const int NTILE = (E + TILE - 1) / TILE;        // 196
    const int KQB   = (N + 127) / 128;              // 782
    const int PB    = (N + 127) / 128;              // 782 (hp role)

    // Workspace: k16 12.8MB, q16 12.8MB, hp16 12.8MB,
    //            ebuf[NBUCK*BCAP u32] 9.6MB, srcs[E] 6.4MB,
    //            gcnt[512], gbase[512], rowptr[N].  (~55 MB)
    __half* k16 = (__half*)d_ws;
    __half* q16 = k16 + (size_t)N * FDIM;
    __half* hp16 = q16 + (size_t)N * FDIM;
    unsigned int* ebuf = (unsigned int*)(hp16 + (size_t)N * FDIM);
    int* srcs   = (int*)(ebuf + (size_t)NBUCK * BCAP);
    int* gcnt   = srcs + E;
    int* gbase  = gcnt + 512;
    int* rowptr = gbase + 512;

    hipMemsetAsync(gcnt, 0, 512 * sizeof(int), stream);

    fused_pre_kernel<<<KQB + PB, 256, 0, stream>>>(
        h, Wk, Wq, W, k16, q16, hp16, N, KQB);
    binA_kernel<<<NTILE, 256, 0, stream>>>(src, dst, gcnt, ebuf, E, NBUCK);
    scan_gcnt_kernel<<<1, 256, 0, stream>>>(gcnt, gbase);
    binB_kernel<<<NBUCK, 256, 0, stream>>>(gcnt, gbase, ebuf, rowptr, srcs, N);
    fused_sa_kernel<<<(N + 3) / 4, 256, 0, stream>>>(
        rowptr, srcs, k16, q16, hp16, b, out, N, E);
}

// Round 11
// 332.528 us; speedup vs baseline: 1.8409x; 1.0365x over previous
//
#include <hip/hip_runtime.h>
#include <hip/hip_fp16.h>
#include <math.h>

// GAT layer: N=100000, E=1600000, F=64, H=4 (Dh=16).
//
// Pipeline (4 dispatches): memset(gcnt) ->
// K1 {kq GEMM | hp GEMM (hp=h@W) | binA bucket-sort}  (roles independent:
//   GEMM reads h/W*, binA reads src/dst; binA overlaps GEMM instead of
//   serializing after it; LDS is a union across roles, 39.9KB) ->
// binB (inline 512-entry gcnt scan per block; per-bucket LDS counting sort;
//   derives rowptr; srcs streamed coalesced) ->
// fused_sa (score+aggregate one pass; phase A edge-parallel dot in regs,
//   phase B parity-packed PV with w AND srcs via __shfl from phase-A lanes).
//
// R11: binA was on the serial critical path (sort chain binA->scan->binB
// between GEMM and fused_sa). Role-fusing binA into K1 hides its ~40-50us
// under GEMM; binB self-scans gcnt (kills the scan launch + bubble);
// fused_sa phase B gets srcs by shfl (deletes 6.4MB of re-reads).
//
// R0-R4 law: any per-edge random-slot global store/atomic costs 100-150us.
// All scattering happens in LDS; global writes are coalesced streams.
// BCAP overflow (32-sigma for random dst) is CLAMPED (graceful, no OOB).

#define FDIM 64
#define NHEADS 4
#define TILE 8192
#define BCAP 6144

typedef float f32x2 __attribute__((ext_vector_type(2)));

// ---- K1: multi-role: [0,KQB) kq | [KQB,KQB+PB) hp | [KQB+PB,+NTILE) binA --
// LDS union: GEMM roles use 32KB (two 64x64 f32 mats); binA uses 39.9KB
// (512*3 u32 tables + 256 u32 scan + 8192 u32 tile buffer).
__global__ __launch_bounds__(256) void k1_kernel(
    const float* __restrict__ h, const float* __restrict__ Wk,
    const float* __restrict__ Wq, const float* __restrict__ Wo,
    const int* __restrict__ src, const int* __restrict__ dst,
    __half* __restrict__ k16, __half* __restrict__ q16,
    __half* __restrict__ hp16, int* __restrict__ gcnt,
    unsigned int* __restrict__ ebuf,
    int N, int E, int KQB, int PB, int nbuck)
{
    __shared__ __align__(16) unsigned char smem_raw[39936];
    int bid = blockIdx.x;
    int t = threadIdx.x;
    if (bid < KQB) {
        // ---- kq role: k = h@(Wk*log2e), q = h@Wq, fp16 out ----
        float* sWk = (float*)smem_raw;
        float* sWq = (float*)(smem_raw + 16384);
        for (int i = t; i < FDIM * FDIM; i += 256) {
            sWk[i] = Wk[i] * 1.4426950408889634f;
            sWq[i] = Wq[i];
        }
        __syncthreads();
        int cg = t & 3;
        int rg = t >> 2;
        long base = (long)bid * 128 + rg * 2;
        const float4* sWk4 = (const float4*)sWk;
        const float4* sWq4 = (const float4*)sWq;
        const float4* h4 = (const float4*)h;
        float acck[2][16], accq[2][16];
#pragma unroll
        for (int i = 0; i < 2; ++i)
#pragma unroll
            for (int c = 0; c < 16; ++c) { acck[i][c] = 0.f; accq[i][c] = 0.f; }

        for (int fs = 0; fs < FDIM; fs += 4) {
            float4 hv[2];
#pragma unroll
            for (int i = 0; i < 2; ++i) {
                long r = base + i; if (r >= N) r = N - 1;
                hv[i] = h4[r * 16 + (fs >> 2)];
            }
#pragma unroll
            for (int fi = 0; fi < 4; ++fi) {
                int f = fs + fi;
                float4 wk0 = sWk4[f * 16 + cg * 4 + 0];
                float4 wk1 = sWk4[f * 16 + cg * 4 + 1];
                float4 wk2 = sWk4[f * 16 + cg * 4 + 2];
                float4 wk3 = sWk4[f * 16 + cg * 4 + 3];
                float4 wq0 = sWq4[f * 16 + cg * 4 + 0];
                float4 wq1 = sWq4[f * 16 + cg * 4 + 1];
                float4 wq2 = sWq4[f * 16 + cg * 4 + 2];
                float4 wq3 = sWq4[f * 16 + cg * 4 + 3];
#pragma unroll
                for (int i = 0; i < 2; ++i) {
                    float hvf = (&hv[i].x)[fi];
                    acck[i][0]  = fmaf(hvf, wk0.x, acck[i][0]);
                    acck[i][1]  = fmaf(hvf, wk0.y, acck[i][1]);
                    acck[i][2]  = fmaf(hvf, wk0.z, acck[i][2]);
                    acck[i][3]  = fmaf(hvf, wk0.w, acck[i][3]);
                    acck[i][4]  = fmaf(hvf, wk1.x, acck[i][4]);
                    acck[i][5]  = fmaf(hvf, wk1.y, acck[i][5]);
                    acck[i][6]  = fmaf(hvf, wk1.z, acck[i][6]);
                    acck[i][7]  = fmaf(hvf, wk1.w, acck[i][7]);
                    acck[i][8]  = fmaf(hvf, wk2.x, acck[i][8]);
                    acck[i][9]  = fmaf(hvf, wk2.y, acck[i][9]);
                    acck[i][10] = fmaf(hvf, wk2.z, acck[i][10]);
                    acck[i][11] = fmaf(hvf, wk2.w, acck[i][11]);
                    acck[i][12] = fmaf(hvf, wk3.x, acck[i][12]);
                    acck[i][13] = fmaf(hvf, wk3.y, acck[i][13]);
                    acck[i][14] = fmaf(hvf, wk3.z, acck[i][14]);
                    acck[i][15] = fmaf(hvf, wk3.w, acck[i][15]);
                    accq[i][0]  = fmaf(hvf, wq0.x, accq[i][0]);
                    accq[i][1]  = fmaf(hvf, wq0.y, accq[i][1]);
                    accq[i][2]  = fmaf(hvf, wq0.z, accq[i][2]);
                    accq[i][3]  = fmaf(hvf, wq0.w, accq[i][3]);
                    accq[i][4]  = fmaf(hvf, wq1.x, accq[i][4]);
                    accq[i][5]  = fmaf(hvf, wq1.y, accq[i][5]);
                    accq[i][6]  = fmaf(hvf, wq1.z, accq[i][6]);
                    accq[i][7]  = fmaf(hvf, wq1.w, accq[i][7]);
                    accq[i][8]  = fmaf(hvf, wq2.x, accq[i][8]);
                    accq[i][9]  = fmaf(hvf, wq2.y, accq[i][9]);
                    accq[i][10] = fmaf(hvf, wq2.z, accq[i][10]);
                    accq[i][11] = fmaf(hvf, wq2.w, accq[i][11]);
                    accq[i][12] = fmaf(hvf, wq3.x, accq[i][12]);
                    accq[i][13] = fmaf(hvf, wq3.y, accq[i][13]);
                    accq[i][14] = fmaf(hvf, wq3.z, accq[i][14]);
                    accq[i][15] = fmaf(hvf, wq3.w, accq[i][15]);
                }
            }
        }
#pragma unroll
        for (int i = 0; i < 2; ++i) {
            long r = base + i;
            if (r >= N) continue;
            __half2 hk[8], hq[8];
#pragma unroll
            for (int c = 0; c < 8; ++c) {
                hk[c] = __floats2half2_rn(acck[i][2 * c], acck[i][2 * c + 1]);
                hq[c] = __floats2half2_rn(accq[i][2 * c], accq[i][2 * c + 1]);
            }
            float4* kout = (float4*)(k16 + (size_t)r * FDIM + cg * 16);
            float4* qout = (float4*)(q16 + (size_t)r * FDIM + cg * 16);
            kout[0] = ((float4*)hk)[0]; kout[1] = ((float4*)hk)[1];
            qout[0] = ((float4*)hq)[0]; qout[1] = ((float4*)hq)[1];
        }
    } else if (bid < KQB + PB) {
        // ---- hp role: hp = h @ Wo (fp16 out), 128 rows/block ----
        float* sW = (float*)smem_raw;
        for (int i = t; i < FDIM * FDIM; i += 256) sW[i] = Wo[i];
        __syncthreads();
        int cg = t & 3;
        int rg = t >> 2;
        long base = (long)(bid - KQB) * 128 + rg * 2;
        const float4* sW4 = (const float4*)sW;
        const float4* h4 = (const float4*)h;
        float accp[2][16];
#pragma unroll
        for (int i = 0; i < 2; ++i)
#pragma unroll
            for (int c = 0; c < 16; ++c) accp[i][c] = 0.f;

        for (int fs = 0; fs < FDIM; fs += 4) {
            float4 hv[2];
#pragma unroll
            for (int i = 0; i < 2; ++i) {
                long r = base + i; if (r >= N) r = N - 1;
                hv[i] = h4[r * 16 + (fs >> 2)];
            }
#pragma unroll
            for (int fi = 0; fi < 4; ++fi) {
                int f = fs + fi;
                float4 w0 = sW4[f * 16 + cg * 4 + 0];
                float4 w1 = sW4[f * 16 + cg * 4 + 1];
                float4 w2 = sW4[f * 16 + cg * 4 + 2];
                float4 w3 = sW4[f * 16 + cg * 4 + 3];
#pragma unroll
                for (int i = 0; i < 2; ++i) {
                    float hvf = (&hv[i].x)[fi];
                    accp[i][0]  = fmaf(hvf, w0.x, accp[i][0]);
                    accp[i][1]  = fmaf(hvf, w0.y, accp[i][1]);
                    accp[i][2]  = fmaf(hvf, w0.z, accp[i][2]);
                    accp[i][3]  = fmaf(hvf, w0.w, accp[i][3]);
                    accp[i][4]  = fmaf(hvf, w1.x, accp[i][4]);
                    accp[i][5]  = fmaf(hvf, w1.y, accp[i][5]);
                    accp[i][6]  = fmaf(hvf, w1.z, accp[i][6]);
                    accp[i][7]  = fmaf(hvf, w1.w, accp[i][7]);
                    accp[i][8]  = fmaf(hvf, w2.x, accp[i][8]);
                    accp[i][9]  = fmaf(hvf, w2.y, accp[i][9]);
                    accp[i][10] = fmaf(hvf, w2.z, accp[i][10]);
                    accp[i][11] = fmaf(hvf, w2.w, accp[i][11]);
                    accp[i][12] = fmaf(hvf, w3.x, accp[i][12]);
                    accp[i][13] = fmaf(hvf, w3.y, accp[i][13]);
                    accp[i][14] = fmaf(hvf, w3.z, accp[i][14]);
                    accp[i][15] = fmaf(hvf, w3.w, accp[i][15]);
                }
            }
        }
#pragma unroll
        for (int i = 0; i < 2; ++i) {
            long r = base + i;
            if (r >= N) continue;
            __half2 hp[8];
#pragma unroll
            for (int c = 0; c < 8; ++c)
                hp[c] = __floats2half2_rn(accp[i][2 * c], accp[i][2 * c + 1]);
            float4* pout = (float4*)(hp16 + (size_t)r * FDIM + cg * 16);
            pout[0] = ((float4*)hp)[0];
            pout[1] = ((float4*)hp)[1];
        }
    } else {
        // ---- binA role: tile of 8192 edges -> LDS counting sort by bucket
        // (dst>>8) -> per-bucket coalesced append to ebuf. Packed entry:
        // src<<8 | (dst&255). Appends clamped to BCAP.
        unsigned int* bh     = (unsigned int*)smem_raw;          // 512
        unsigned int* bstart = bh + 512;                          // 512
        unsigned int* bbase  = bstart + 512;                      // 512
        unsigned int* sd     = bbase + 512;                       // 256
        unsigned int* ebuf_l = sd + 256;                          // 8192
        long e0 = (long)(bid - KQB - PB) * TILE;
        int cnt_tile = (int)(((long)E - e0 < (long)TILE) ? ((long)E - e0) : (long)TILE);

        bh[t] = 0; bh[t + 256] = 0;
        __syncthreads();
        for (int j = t; j < cnt_tile; j += 256)
            atomicAdd(&bh[dst[e0 + j] >> 8], 1u);
        __syncthreads();
        unsigned int c0 = bh[2 * t], c1 = bh[2 * t + 1];
        unsigned int s = c0 + c1;
        sd[t] = s;
        __syncthreads();
        for (int off = 1; off < 256; off <<= 1) {
            unsigned int v = (t >= off) ? sd[t - off] : 0;
            __syncthreads();
            sd[t] += v;
            __syncthreads();
        }
        unsigned int ex = sd[t] - s;
        bh[2 * t] = ex;          bstart[2 * t] = ex;
        bh[2 * t + 1] = ex + c0; bstart[2 * t + 1] = ex + c0;
        if (c0 > 0) bbase[2 * t] = (unsigned int)atomicAdd(&gcnt[2 * t], (int)c0);
        if (c1 > 0) bbase[2 * t + 1] = (unsigned int)atomicAdd(&gcnt[2 * t + 1], (int)c1);
        __syncthreads();
        for (int j = t; j < cnt_tile; j += 256) {
            int d = dst[e0 + j];
            int sv = src[e0 + j];
            unsigned int pos = atomicAdd(&bh[d >> 8], 1u);
            ebuf_l[pos] = ((unsigned int)sv << 8) | (unsigned int)(d & 255);
        }
        __syncthreads();
        int wave = t >> 6, lane = t & 63;
        for (int b = wave; b < nbuck; b += 4) {
            unsigned int st = bstart[b];
            unsigned int en = bh[b];
            if (st == en) continue;
            unsigned int gb = bbase[b];
            if (gb >= (unsigned int)BCAP) continue;
            unsigned int room = (unsigned int)BCAP - gb;
            if (en - st > room) en = st + room;
            unsigned int* dstp = ebuf + (size_t)b * BCAP + gb;
            for (unsigned int j = st + lane; j < en; j += 64)
                dstp[j - st] = ebuf_l[j];
        }
    }
}

// K2: binB with INLINE gcnt scan. Each block redundantly scans the 512-entry
// gcnt in LDS (~2us, parallel across blocks) to get its global base, then
// per-bucket LDS counting sort; derives rowptr; streams srcs coalesced.
__global__ __launch_bounds__(256) void binB_kernel(
    const int* __restrict__ gcnt, const unsigned int* __restrict__ ebuf,
    int* __restrict__ rowptr, int* __restrict__ srcs, int N)
{
    __shared__ int sg[512];
    __shared__ unsigned int lh[256];
    __shared__ unsigned int sd[256];
    __shared__ unsigned int srcs_l[BCAP];
    int t = threadIdx.x;
    int b = blockIdx.x;

    // inline exclusive scan of gcnt (2 entries/thread)
    int c0 = gcnt[2 * t], c1 = gcnt[2 * t + 1];
    int ssum = c0 + c1;
    sd[t] = (unsigned int)ssum;
    __syncthreads();
    for (int off = 1; off < 256; off <<= 1) {
        unsigned int v = (t >= off) ? sd[t - off] : 0;
        __syncthreads();
        sd[t] += v;
        __syncthreads();
    }
    int ex = (int)sd[t] - ssum;
    sg[2 * t] = ex;
    sg[2 * t + 1] = ex + c0;
    __syncthreads();
    int gb = sg[b];
    int cnt = gcnt[b];
    if (cnt > BCAP) cnt = BCAP;   // matches binA clamp
    int n0 = b << 8;
    const unsigned int* eb = ebuf + (size_t)b * BCAP;

    lh[t] = 0;
    __syncthreads();
    for (int j = t; j < cnt; j += 256)
        atomicAdd(&lh[eb[j] & 255u], 1u);
    __syncthreads();
    unsigned int c = lh[t];
    sd[t] = c;
    __syncthreads();
    for (int off = 1; off < 256; off <<= 1) {
        unsigned int v = (t >= off) ? sd[t - off] : 0;
        __syncthreads();
        sd[t] += v;
        __syncthreads();
    }
    unsigned int excl = sd[t] - c;
    lh[t] = excl;
    if (n0 + t < N) rowptr[n0 + t] = gb + (int)excl;
    __syncthreads();
    for (int j = t; j < cnt; j += 256) {
        unsigned int p = eb[j];
        unsigned int pos = atomicAdd(&lh[p & 255u], 1u);
        srcs_l[pos] = p >> 8;
    }
    __syncthreads();
    for (int j = t; j < cnt; j += 256)
        srcs[gb + j] = (int)srcs_l[j];
}

__device__ __forceinline__ float dot16(const float4* kk, const float* qf) {
    const __half2* kh = (const __half2*)kk;
    float acc = 0.f;
#pragma unroll
    for (int j = 0; j < 8; ++j) {
        float2 kf = __half22float2(kh[j]);
        acc = fmaf(kf.x, qf[2 * j], acc);
        acc = fmaf(kf.y, qf[2 * j + 1], acc);
    }
    return acc;
}

__device__ __forceinline__ void agg2f(
    float w0, float w1, float w2, float w3, __half2 g,
    f32x2& a0, f32x2& a1, f32x2& a2, f32x2& a3)
{
    float2 f2 = __half22float2(g);
    f32x2 hv; hv.x = f2.x; hv.y = f2.y;
    f32x2 wv;
    wv.x = w0; wv.y = w0; a0 = __builtin_elementwise_fma(wv, hv, a0);
    wv.x = w1; wv.y = w1; a1 = __builtin_elementwise_fma(wv, hv, a1);
    wv.x = w2; wv.y = w2; a2 = __builtin_elementwise_fma(wv, hv, a2);
    wv.x = w3; wv.y = w3; a3 = __builtin_elementwise_fma(wv, hv, a3);
}

// K3: fused score+aggregate. One wave per node (4 waves/block).
// Phase A: lane=(rr,hh) computes w = exp2(k16[src].q) edge-parallel, w AND
// src stay in registers. Phase B: 32 lanes x half2, 2 records/wave-inst;
// w and srcs both fetched from phase-A lanes via __shfl (no re-reads).
// Tail slots clamp gather index to end-1 with w=0.
__global__ __launch_bounds__(256) void fused_sa_kernel(
    const int* __restrict__ rowptr, const int* __restrict__ srcs,
    const __half* __restrict__ k16, const __half* __restrict__ q16,
    const __half* __restrict__ hp16, const float* __restrict__ bvec,
    float* __restrict__ out, int N, int E)
{
    int lane = threadIdx.x & 63;
    int n = blockIdx.x * 4 + (threadIdx.x >> 6);
    if (n >= N) return;
    int start = rowptr[n];
    int end   = (n == N - 1) ? E : rowptr[n + 1];

    int hh   = lane & 3;    // phase A: head
    int rr   = lane >> 2;   // phase A: record slot 0..15
    int half = lane >> 5;   // phase B: record parity
    int fl   = lane & 31;   // phase B: feature pair 2fl, 2fl+1

    const float4* qp = (const float4*)(q16 + (size_t)n * FDIM + hh * 16);
    float4 qv[2] = { qp[0], qp[1] };
    const __half2* qh = (const __half2*)qv;
    float qf[16];
#pragma unroll
    for (int j = 0; j < 8; ++j) {
        float2 f = __half22float2(qh[j]);
        qf[2 * j] = f.x;
        qf[2 * j + 1] = f.y;
    }

    float zacc = 0.f;
    f32x2 a0 = {0.f, 0.f}, a1 = {0.f, 0.f}, a2 = {0.f, 0.f}, a3 = {0.f, 0.f};

    for (int base = start; base < end; base += 16) {
        // ---- phase A ----
        int idx = base + rr;
        bool valid = (idx < end);
        int ic = valid ? idx : (end - 1);
        int sA = srcs[ic];
        const float4* kp = (const float4*)(k16 + (size_t)sA * FDIM + hh * 16);
        float4 ka[2] = { kp[0], kp[1] };
        float w = __builtin_amdgcn_exp2f(dot16(ka, qf));
        w = valid ? w : 0.f;
        zacc += w;

        // ---- phase B: two 8-record groups; w and src via shfl ----
#pragma unroll
        for (int j = 0; j < 2; ++j) {
            int g0i = base + j * 8;
            if (g0i < end) {
                int rb = j * 8 + half;   // local record of this half's 1st rec
                int s0 = __shfl(sA, (rb + 0) * 4, 64);
                int s1 = __shfl(sA, (rb + 2) * 4, 64);
                int s2 = __shfl(sA, (rb + 4) * 4, 64);
                int s3 = __shfl(sA, (rb + 6) * 4, 64);
                __half2 g0 = *((const __half2*)(hp16 + (size_t)s0 * FDIM) + fl);
                __half2 g1 = *((const __half2*)(hp16 + (size_t)s1 * FDIM) + fl);
                __half2 g2 = *((const __half2*)(hp16 + (size_t)s2 * FDIM) + fl);
                __half2 g3 = *((const __half2*)(hp16 + (size_t)s3 * FDIM) + fl);
                float wa0 = __shfl(w, (rb + 0) * 4 + 0, 64);
                float wa1 = __shfl(w, (rb + 0) * 4 + 1, 64);
                float wa2 = __shfl(w, (rb + 0) * 4 + 2, 64);
                float wa3 = __shfl(w, (rb + 0) * 4 + 3, 64);
                agg2f(wa0, wa1, wa2, wa3, g0, a0, a1, a2, a3);
                float wb0 = __shfl(w, (rb + 2) * 4 + 0, 64);
                float wb1 = __shfl(w, (rb + 2) * 4 + 1, 64);
                float wb2 = __shfl(w, (rb + 2) * 4 + 2, 64);
                float wb3 = __shfl(w, (rb + 2) * 4 + 3, 64);
                agg2f(wb0, wb1, wb2, wb3, g1, a0, a1, a2, a3);
                float wc0 = __shfl(w, (rb + 4) * 4 + 0, 64);
                float wc1 = __shfl(w, (rb + 4) * 4 + 1, 64);
                float wc2 = __shfl(w, (rb + 4) * 4 + 2, 64);
                float wc3 = __shfl(w, (rb + 4) * 4 + 3, 64);
                agg2f(wc0, wc1, wc2, wc3, g2, a0, a1, a2, a3);
                float wd0 = __shfl(w, (rb + 6) * 4 + 0, 64);
                float wd1 = __shfl(w, (rb + 6) * 4 + 1, 64);
                float wd2 = __shfl(w, (rb + 6) * 4 + 2, 64);
                float wd3 = __shfl(w, (rb + 6) * 4 + 3, 64);
                agg2f(wd0, wd1, wd2, wd3, g3, a0, a1, a2, a3);
            }
        }
    }

    // fold z over record slots (lanes sharing hh differ in bits 2..5)
    zacc += __shfl_xor(zacc, 4, 64);
    zacc += __shfl_xor(zacc, 8, 64);
    zacc += __shfl_xor(zacc, 16, 64);
    zacc += __shfl_xor(zacc, 32, 64);
    float z0 = __shfl(zacc, 0, 64);
    float z1 = __shfl(zacc, 1, 64);
    float z2 = __shfl(zacc, 2, 64);
    float z3 = __shfl(zacc, 3, 64);

    // merge the two record-parity partial sums (lane l <-> l^32)
    a0.x += __shfl_xor(a0.x, 32, 64); a0.y += __shfl_xor(a0.y, 32, 64);
    a1.x += __shfl_xor(a1.x, 32, 64); a1.y += __shfl_xor(a1.y, 32, 64);
    a2.x += __shfl_xor(a2.x, 32, 64); a2.y += __shfl_xor(a2.y, 32, 64);
    a3.x += __shfl_xor(a3.x, 32, 64); a3.y += __shfl_xor(a3.y, 32, 64);

    if (half != 0) return;
    float bv0 = bvec[2 * fl], bv1 = bvec[2 * fl + 1];
    float2* o = (float2*)(out + (size_t)n * (NHEADS * FDIM));
    if (end > start) {
        float rz0 = 1.f / z0;
        float rz1 = 1.f / z1;
        float rz2 = 1.f / z2;
        float rz3 = 1.f / z3;
        o[fl]      = make_float2(fmaf(a0.x, rz0, bv0), fmaf(a0.y, rz0, bv1));
        o[32 + fl] = make_float2(fmaf(a1.x, rz1, bv0), fmaf(a1.y, rz1, bv1));
        o[64 + fl] = make_float2(fmaf(a2.x, rz2, bv0), fmaf(a2.y, rz2, bv1));
        o[96 + fl] = make_float2(fmaf(a3.x, rz3, bv0), fmaf(a3.y, rz3, bv1));
    } else {
        float2 bz = make_float2(bv0, bv1);
        o[fl] = bz; o[32 + fl] = bz; o[64 + fl] = bz; o[96 + fl] = bz;
    }
}

extern "C" void kernel_launch(void* const* d_in, const int* in_sizes, int n_in,
                              void* d_out, int out_size, void* d_ws, size_t ws_size,
                              hipStream_t stream) {
    const float* h   = (const float*)d_in[0];
    const int*   src = (const int*)d_in[1];
    const int*   dst = (const int*)d_in[2];
    const float* Wk  = (const float*)d_in[3];
    const float* Wq  = (const float*)d_in[4];
    const float* W   = (const float*)d_in[5];
    const float* b   = (const float*)d_in[6];
    float* out = (float*)d_out;

    const int N = in_sizes[0] / FDIM;   // 100000
    const int E = in_sizes[1];          // 1600000

    const int NBUCK = (N + 255) >> 8;               // 391
    const int NTILE = (E + TILE - 1) / TILE;        // 196
    const int KQB   = (N + 127) / 128;              // 782
    const int PB    = (N + 127) / 128;              // 782 (hp role)

    // Workspace: k16 12.8MB, q16 12.8MB, hp16 12.8MB,
    //            ebuf[NBUCK*BCAP u32] 9.6MB, srcs[E] 6.4MB,
    //            gcnt[512], rowptr[N].  (~55 MB)
    __half* k16 = (__half*)d_ws;
    __half* q16 = k16 + (size_t)N * FDIM;
    __half* hp16 = q16 + (size_t)N * FDIM;
    unsigned int* ebuf = (unsigned int*)(hp16 + (size_t)N * FDIM);
    int* srcs   = (int*)(ebuf + (size_t)NBUCK * BCAP);
    int* gcnt   = srcs + E;
    int* rowptr = gcnt + 512;

    hipMemsetAsync(gcnt, 0, 512 * sizeof(int), stream);

    k1_kernel<<<KQB + PB + NTILE, 256, 0, stream>>>(
        h, Wk, Wq, W, src, dst, k16, q16, hp16, gcnt, ebuf,
        N, E, KQB, PB, NBUCK);
    binB_kernel<<<NBUCK, 256, 0, stream>>>(gcnt, ebuf, rowptr, srcs, N);
    fused_sa_kernel<<<(N + 3) / 4, 256, 0, stream>>>(
        rowptr, srcs, k16, q16, hp16, b, out, N, E);
}

// Round 12
// 317.370 us; speedup vs baseline: 1.9288x; 1.0478x over previous
//
#include <hip/hip_runtime.h>
#include <hip/hip_fp16.h>
#include <math.h>

// GAT layer: N=100000, E=1600000, F=64, H=4 (Dh=16).
//
// Pipeline (4 dispatches): memset(gcnt) ->
// K1 {kq GEMM | hp GEMM (hp=h@W) | binA bucket-sort} ->
// binB (inline gcnt scan; LDS-staged per-bucket counting sort; rowptr; srcs)->
// fused_sa (score+aggregate one pass):
//   phase A: lane=(rr,hh) edge-parallel fp16 dot -> w=exp2(e') in REGISTER;
//   phase B: QUARTER-packed PV: lane=(qt,fq), each lane loads uint2
//     (4 feats, 8B) so one gather inst covers 4 records; one per-lane-indexed
//     shfl delivers 4 records' w/src at once. ~5 wave-inst/record (was 7.5).
//
// R12: fused_sa was issue+latency bound (43% VALU, 30% HBM, no pipe
// saturated); phase B's 4B gathers and 2.5 shfl/record were the issue load.
// binB now stages ebuf in LDS during the hist pass (kills the 9.6MB global
// re-read in the scatter pass).
//
// R0-R4 law: any per-edge random-slot global store/atomic costs 100-150us.
// All scattering happens in LDS; global writes are coalesced streams.
// BCAP overflow (32-sigma for random dst) is CLAMPED (graceful, no OOB).

#define FDIM 64
#define NHEADS 4
#define TILE 8192
#define BCAP 6144

typedef float f32x2 __attribute__((ext_vector_type(2)));

// ---- K1: multi-role: [0,KQB) kq | [KQB,KQB+PB) hp | [KQB+PB,+NTILE) binA --
__global__ __launch_bounds__(256) void k1_kernel(
    const float* __restrict__ h, const float* __restrict__ Wk,
    const float* __restrict__ Wq, const float* __restrict__ Wo,
    const int* __restrict__ src, const int* __restrict__ dst,
    __half* __restrict__ k16, __half* __restrict__ q16,
    __half* __restrict__ hp16, int* __restrict__ gcnt,
    unsigned int* __restrict__ ebuf,
    int N, int E, int KQB, int PB, int nbuck)
{
    __shared__ __align__(16) unsigned char smem_raw[39936];
    int bid = blockIdx.x;
    int t = threadIdx.x;
    if (bid < KQB) {
        // ---- kq role: k = h@(Wk*log2e), q = h@Wq, fp16 out ----
        float* sWk = (float*)smem_raw;
        float* sWq = (float*)(smem_raw + 16384);
        for (int i = t; i < FDIM * FDIM; i += 256) {
            sWk[i] = Wk[i] * 1.4426950408889634f;
            sWq[i] = Wq[i];
        }
        __syncthreads();
        int cg = t & 3;
        int rg = t >> 2;
        long base = (long)bid * 128 + rg * 2;
        const float4* sWk4 = (const float4*)sWk;
        const float4* sWq4 = (const float4*)sWq;
        const float4* h4 = (const float4*)h;
        float acck[2][16], accq[2][16];
#pragma unroll
        for (int i = 0; i < 2; ++i)
#pragma unroll
            for (int c = 0; c < 16; ++c) { acck[i][c] = 0.f; accq[i][c] = 0.f; }

        for (int fs = 0; fs < FDIM; fs += 4) {
            float4 hv[2];
#pragma unroll
            for (int i = 0; i < 2; ++i) {
                long r = base + i; if (r >= N) r = N - 1;
                hv[i] = h4[r * 16 + (fs >> 2)];
            }
#pragma unroll
            for (int fi = 0; fi < 4; ++fi) {
                int f = fs + fi;
                float4 wk0 = sWk4[f * 16 + cg * 4 + 0];
                float4 wk1 = sWk4[f * 16 + cg * 4 + 1];
                float4 wk2 = sWk4[f * 16 + cg * 4 + 2];
                float4 wk3 = sWk4[f * 16 + cg * 4 + 3];
                float4 wq0 = sWq4[f * 16 + cg * 4 + 0];
                float4 wq1 = sWq4[f * 16 + cg * 4 + 1];
                float4 wq2 = sWq4[f * 16 + cg * 4 + 2];
                float4 wq3 = sWq4[f * 16 + cg * 4 + 3];
#pragma unroll
                for (int i = 0; i < 2; ++i) {
                    float hvf = (&hv[i].x)[fi];
                    acck[i][0]  = fmaf(hvf, wk0.x, acck[i][0]);
                    acck[i][1]  = fmaf(hvf, wk0.y, acck[i][1]);
                    acck[i][2]  = fmaf(hvf, wk0.z, acck[i][2]);
                    acck[i][3]  = fmaf(hvf, wk0.w, acck[i][3]);
                    acck[i][4]  = fmaf(hvf, wk1.x, acck[i][4]);
                    acck[i][5]  = fmaf(hvf, wk1.y, acck[i][5]);
                    acck[i][6]  = fmaf(hvf, wk1.z, acck[i][6]);
                    acck[i][7]  = fmaf(hvf, wk1.w, acck[i][7]);
                    acck[i][8]  = fmaf(hvf, wk2.x, acck[i][8]);
                    acck[i][9]  = fmaf(hvf, wk2.y, acck[i][9]);
                    acck[i][10] = fmaf(hvf, wk2.z, acck[i][10]);
                    acck[i][11] = fmaf(hvf, wk2.w, acck[i][11]);
                    acck[i][12] = fmaf(hvf, wk3.x, acck[i][12]);
                    acck[i][13] = fmaf(hvf, wk3.y, acck[i][13]);
                    acck[i][14] = fmaf(hvf, wk3.z, acck[i][14]);
                    acck[i][15] = fmaf(hvf, wk3.w, acck[i][15]);
                    accq[i][0]  = fmaf(hvf, wq0.x, accq[i][0]);
                    accq[i][1]  = fmaf(hvf, wq0.y, accq[i][1]);
                    accq[i][2]  = fmaf(hvf, wq0.z, accq[i][2]);
                    accq[i][3]  = fmaf(hvf, wq0.w, accq[i][3]);
                    accq[i][4]  = fmaf(hvf, wq1.x, accq[i][4]);
                    accq[i][5]  = fmaf(hvf, wq1.y, accq[i][5]);
                    accq[i][6]  = fmaf(hvf, wq1.z, accq[i][6]);
                    accq[i][7]  = fmaf(hvf, wq1.w, accq[i][7]);
                    accq[i][8]  = fmaf(hvf, wq2.x, accq[i][8]);
                    accq[i][9]  = fmaf(hvf, wq2.y, accq[i][9]);
                    accq[i][10] = fmaf(hvf, wq2.z, accq[i][10]);
                    accq[i][11] = fmaf(hvf, wq2.w, accq[i][11]);
                    accq[i][12] = fmaf(hvf, wq3.x, accq[i][12]);
                    accq[i][13] = fmaf(hvf, wq3.y, accq[i][13]);
                    accq[i][14] = fmaf(hvf, wq3.z, accq[i][14]);
                    accq[i][15] = fmaf(hvf, wq3.w, accq[i][15]);
                }
            }
        }
#pragma unroll
        for (int i = 0; i < 2; ++i) {
            long r = base + i;
            if (r >= N) continue;
            __half2 hk[8], hq[8];
#pragma unroll
            for (int c = 0; c < 8; ++c) {
                hk[c] = __floats2half2_rn(acck[i][2 * c], acck[i][2 * c + 1]);
                hq[c] = __floats2half2_rn(accq[i][2 * c], accq[i][2 * c + 1]);
            }
            float4* kout = (float4*)(k16 + (size_t)r * FDIM + cg * 16);
            float4* qout = (float4*)(q16 + (size_t)r * FDIM + cg * 16);
            kout[0] = ((float4*)hk)[0]; kout[1] = ((float4*)hk)[1];
            qout[0] = ((float4*)hq)[0]; qout[1] = ((float4*)hq)[1];
        }
    } else if (bid < KQB + PB) {
        // ---- hp role: hp = h @ Wo (fp16 out), 128 rows/block ----
        float* sW = (float*)smem_raw;
        for (int i = t; i < FDIM * FDIM; i += 256) sW[i] = Wo[i];
        __syncthreads();
        int cg = t & 3;
        int rg = t >> 2;
        long base = (long)(bid - KQB) * 128 + rg * 2;
        const float4* sW4 = (const float4*)sW;
        const float4* h4 = (const float4*)h;
        float accp[2][16];
#pragma unroll
        for (int i = 0; i < 2; ++i)
#pragma unroll
            for (int c = 0; c < 16; ++c) accp[i][c] = 0.f;

        for (int fs = 0; fs < FDIM; fs += 4) {
            float4 hv[2];
#pragma unroll
            for (int i = 0; i < 2; ++i) {
                long r = base + i; if (r >= N) r = N - 1;
                hv[i] = h4[r * 16 + (fs >> 2)];
            }
#pragma unroll
            for (int fi = 0; fi < 4; ++fi) {
                int f = fs + fi;
                float4 w0 = sW4[f * 16 + cg * 4 + 0];
                float4 w1 = sW4[f * 16 + cg * 4 + 1];
                float4 w2 = sW4[f * 16 + cg * 4 + 2];
                float4 w3 = sW4[f * 16 + cg * 4 + 3];
#pragma unroll
                for (int i = 0; i < 2; ++i) {
                    float hvf = (&hv[i].x)[fi];
                    accp[i][0]  = fmaf(hvf, w0.x, accp[i][0]);
                    accp[i][1]  = fmaf(hvf, w0.y, accp[i][1]);
                    accp[i][2]  = fmaf(hvf, w0.z, accp[i][2]);
                    accp[i][3]  = fmaf(hvf, w0.w, accp[i][3]);
                    accp[i][4]  = fmaf(hvf, w1.x, accp[i][4]);
                    accp[i][5]  = fmaf(hvf, w1.y, accp[i][5]);
                    accp[i][6]  = fmaf(hvf, w1.z, accp[i][6]);
                    accp[i][7]  = fmaf(hvf, w1.w, accp[i][7]);
                    accp[i][8]  = fmaf(hvf, w2.x, accp[i][8]);
                    accp[i][9]  = fmaf(hvf, w2.y, accp[i][9]);
                    accp[i][10] = fmaf(hvf, w2.z, accp[i][10]);
                    accp[i][11] = fmaf(hvf, w2.w, accp[i][11]);
                    accp[i][12] = fmaf(hvf, w3.x, accp[i][12]);
                    accp[i][13] = fmaf(hvf, w3.y, accp[i][13]);
                    accp[i][14] = fmaf(hvf, w3.z, accp[i][14]);
                    accp[i][15] = fmaf(hvf, w3.w, accp[i][15]);
                }
            }
        }
#pragma unroll
        for (int i = 0; i < 2; ++i) {
            long r = base + i;
            if (r >= N) continue;
            __half2 hp[8];
#pragma unroll
            for (int c = 0; c < 8; ++c)
                hp[c] = __floats2half2_rn(accp[i][2 * c], accp[i][2 * c + 1]);
            float4* pout = (float4*)(hp16 + (size_t)r * FDIM + cg * 16);
            pout[0] = ((float4*)hp)[0];
            pout[1] = ((float4*)hp)[1];
        }
    } else {
        // ---- binA role: tile of 8192 edges -> LDS counting sort by bucket
        // (dst>>8) -> per-bucket coalesced append to ebuf. Packed entry:
        // src<<8 | (dst&255). Appends clamped to BCAP.
        unsigned int* bh     = (unsigned int*)smem_raw;          // 512
        unsigned int* bstart = bh + 512;                          // 512
        unsigned int* bbase  = bstart + 512;                      // 512
        unsigned int* sd     = bbase + 512;                       // 256
        unsigned int* ebuf_l = sd + 256;                          // 8192
        long e0 = (long)(bid - KQB - PB) * TILE;
        int cnt_tile = (int)(((long)E - e0 < (long)TILE) ? ((long)E - e0) : (long)TILE);

        bh[t] = 0; bh[t + 256] = 0;
        __syncthreads();
        for (int j = t; j < cnt_tile; j += 256)
            atomicAdd(&bh[dst[e0 + j] >> 8], 1u);
        __syncthreads();
        unsigned int c0 = bh[2 * t], c1 = bh[2 * t + 1];
        unsigned int s = c0 + c1;
        sd[t] = s;
        __syncthreads();
        for (int off = 1; off < 256; off <<= 1) {
            unsigned int v = (t >= off) ? sd[t - off] : 0;
            __syncthreads();
            sd[t] += v;
            __syncthreads();
        }
        unsigned int ex = sd[t] - s;
        bh[2 * t] = ex;          bstart[2 * t] = ex;
        bh[2 * t + 1] = ex + c0; bstart[2 * t + 1] = ex + c0;
        if (c0 > 0) bbase[2 * t] = (unsigned int)atomicAdd(&gcnt[2 * t], (int)c0);
        if (c1 > 0) bbase[2 * t + 1] = (unsigned int)atomicAdd(&gcnt[2 * t + 1], (int)c1);
        __syncthreads();
        for (int j = t; j < cnt_tile; j += 256) {
            int d = dst[e0 + j];
            int sv = src[e0 + j];
            unsigned int pos = atomicAdd(&bh[d >> 8], 1u);
            ebuf_l[pos] = ((unsigned int)sv << 8) | (unsigned int)(d & 255);
        }
        __syncthreads();
        int wave = t >> 6, lane = t & 63;
        for (int b = wave; b < nbuck; b += 4) {
            unsigned int st = bstart[b];
            unsigned int en = bh[b];
            if (st == en) continue;
            unsigned int gb = bbase[b];
            if (gb >= (unsigned int)BCAP) continue;
            unsigned int room = (unsigned int)BCAP - gb;
            if (en - st > room) en = st + room;
            unsigned int* dstp = ebuf + (size_t)b * BCAP + gb;
            for (unsigned int j = st + lane; j < en; j += 64)
                dstp[j - st] = ebuf_l[j];
        }
    }
}

// K2: binB with inline gcnt scan + LDS-staged entries (single global read
// of ebuf; scatter pass runs from LDS). Derives rowptr; streams srcs.
__global__ __launch_bounds__(256) void binB_kernel(
    const int* __restrict__ gcnt, const unsigned int* __restrict__ ebuf,
    int* __restrict__ rowptr, int* __restrict__ srcs, int N)
{
    __shared__ int sg[512];
    __shared__ unsigned int lh[256];
    __shared__ unsigned int sd[256];
    __shared__ unsigned int ebuf_l[BCAP];
    __shared__ unsigned int srcs_l[BCAP];
    int t = threadIdx.x;
    int b = blockIdx.x;

    // inline exclusive scan of gcnt (2 entries/thread)
    int c0 = gcnt[2 * t], c1 = gcnt[2 * t + 1];
    int ssum = c0 + c1;
    sd[t] = (unsigned int)ssum;
    lh[t] = 0;
    __syncthreads();
    for (int off = 1; off < 256; off <<= 1) {
        unsigned int v = (t >= off) ? sd[t - off] : 0;
        __syncthreads();
        sd[t] += v;
        __syncthreads();
    }
    int ex = (int)sd[t] - ssum;
    sg[2 * t] = ex;
    sg[2 * t + 1] = ex + c0;
    __syncthreads();
    int gb = sg[b];
    int cnt = gcnt[b];
    if (cnt > BCAP) cnt = BCAP;   // matches binA clamp
    int n0 = b << 8;
    const unsigned int* eb = ebuf + (size_t)b * BCAP;

    // single global pass: stage into LDS + histogram
    for (int j = t; j < cnt; j += 256) {
        unsigned int p = eb[j];
        ebuf_l[j] = p;
        atomicAdd(&lh[p & 255u], 1u);
    }
    __syncthreads();
    unsigned int c = lh[t];
    sd[t] = c;
    __syncthreads();
    for (int off = 1; off < 256; off <<= 1) {
        unsigned int v = (t >= off) ? sd[t - off] : 0;
        __syncthreads();
        sd[t] += v;
        __syncthreads();
    }
    unsigned int excl = sd[t] - c;
    lh[t] = excl;
    if (n0 + t < N) rowptr[n0 + t] = gb + (int)excl;
    __syncthreads();
    for (int j = t; j < cnt; j += 256) {
        unsigned int p = ebuf_l[j];
        unsigned int pos = atomicAdd(&lh[p & 255u], 1u);
        srcs_l[pos] = p >> 8;
    }
    __syncthreads();
    for (int j = t; j < cnt; j += 256)
        srcs[gb + j] = (int)srcs_l[j];
}

__device__ __forceinline__ float dot16(const float4* kk, const float* qf) {
    const __half2* kh = (const __half2*)kk;
    float acc = 0.f;
#pragma unroll
    for (int j = 0; j < 8; ++j) {
        float2 kf = __half22float2(kh[j]);
        acc = fmaf(kf.x, qf[2 * j], acc);
        acc = fmaf(kf.y, qf[2 * j + 1], acc);
    }
    return acc;
}

// K3: fused score+aggregate. One wave per node (4 waves/block).
// Phase A: lane=(rr,hh) computes w = exp2(k16[src].q) edge-parallel; w and
// src stay in registers. Phase B: QUARTER-packed PV: lane=(qt=lane>>4,
// fq=lane&15); each lane loads uint2 (features 4fq..4fq+3, 8B) of its
// quarter's record -> one gather inst covers 4 records; per-lane-indexed
// shfl delivers 4 records' w/src in one inst. Tail records: w=0, src
// clamped to end-1 (safe address).
__global__ __launch_bounds__(256) void fused_sa_kernel(
    const int* __restrict__ rowptr, const int* __restrict__ srcs,
    const __half* __restrict__ k16, const __half* __restrict__ q16,
    const __half* __restrict__ hp16, const float* __restrict__ bvec,
    float* __restrict__ out, int N, int E)
{
    int lane = threadIdx.x & 63;
    int n = blockIdx.x * 4 + (threadIdx.x >> 6);
    if (n >= N) return;
    int start = rowptr[n];
    int end   = (n == N - 1) ? E : rowptr[n + 1];

    int hh = lane & 3;     // phase A: head
    int rr = lane >> 2;    // phase A: record slot 0..15
    int qt = lane >> 4;    // phase B: quarter 0..3
    int fq = lane & 15;    // phase B: feature quad 4fq..4fq+3

    const float4* qp = (const float4*)(q16 + (size_t)n * FDIM + hh * 16);
    float4 qv[2] = { qp[0], qp[1] };
    const __half2* qh = (const __half2*)qv;
    float qf[16];
#pragma unroll
    for (int j = 0; j < 8; ++j) {
        float2 f = __half22float2(qh[j]);
        qf[2 * j] = f.x;
        qf[2 * j + 1] = f.y;
    }

    float zacc = 0.f;
    // acc[head][lo/hi]: features 4fq+{0,1} / 4fq+{2,3}
    f32x2 a00 = {0.f,0.f}, a01 = {0.f,0.f};
    f32x2 a10 = {0.f,0.f}, a11 = {0.f,0.f};
    f32x2 a20 = {0.f,0.f}, a21 = {0.f,0.f};
    f32x2 a30 = {0.f,0.f}, a31 = {0.f,0.f};

    for (int base = start; base < end; base += 16) {
        // ---- phase A ----
        int idx = base + rr;
        bool valid = (idx < end);
        int ic = valid ? idx : (end - 1);
        int sA = srcs[ic];
        const float4* kp = (const float4*)(k16 + (size_t)sA * FDIM + hh * 16);
        float4 ka[2] = { kp[0], kp[1] };
        float w = __builtin_amdgcn_exp2f(dot16(ka, qf));
        w = valid ? w : 0.f;
        zacc += w;

        // ---- phase B: 4 slots x 4 records (one per quarter) ----
#pragma unroll
        for (int k = 0; k < 4; ++k) {
            if (base + k * 4 < end) {
                int rloc = k * 4 + qt;             // record slot for my quarter
                int sB = __shfl(sA, rloc * 4, 64);
                uint2 g = *(const uint2*)(hp16 + (size_t)sB * FDIM + fq * 4);
                float w0 = __shfl(w, rloc * 4 + 0, 64);
                float w1 = __shfl(w, rloc * 4 + 1, 64);
                float w2 = __shfl(w, rloc * 4 + 2, 64);
                float w3 = __shfl(w, rloc * 4 + 3, 64);
                float2 flo = __half22float2(*(__half2*)&g.x);
                float2 fhi = __half22float2(*(__half2*)&g.y);
                f32x2 vlo; vlo.x = flo.x; vlo.y = flo.y;
                f32x2 vhi; vhi.x = fhi.x; vhi.y = fhi.y;
                f32x2 wv;
                wv.x = w0; wv.y = w0;
                a00 = __builtin_elementwise_fma(wv, vlo, a00);
                a01 = __builtin_elementwise_fma(wv, vhi, a01);
                wv.x = w1; wv.y = w1;
                a10 = __builtin_elementwise_fma(wv, vlo, a10);
                a11 = __builtin_elementwise_fma(wv, vhi, a11);
                wv.x = w2; wv.y = w2;
                a20 = __builtin_elementwise_fma(wv, vlo, a20);
                a21 = __builtin_elementwise_fma(wv, vhi, a21);
                wv.x = w3; wv.y = w3;
                a30 = __builtin_elementwise_fma(wv, vlo, a30);
                a31 = __builtin_elementwise_fma(wv, vhi, a31);
            }
        }
    }

    // fold z over record slots (lanes sharing hh differ in bits 2..5)
    zacc += __shfl_xor(zacc, 4, 64);
    zacc += __shfl_xor(zacc, 8, 64);
    zacc += __shfl_xor(zacc, 16, 64);
    zacc += __shfl_xor(zacc, 32, 64);
    float z0 = __shfl(zacc, 0, 64);
    float z1 = __shfl(zacc, 1, 64);
    float z2 = __shfl(zacc, 2, 64);
    float z3 = __shfl(zacc, 3, 64);

    // merge the 4 quarter partial sums (xor 16, then 32)
#define MQ(A) \
    (A).x += __shfl_xor((A).x, 16, 64); (A).y += __shfl_xor((A).y, 16, 64); \
    (A).x += __shfl_xor((A).x, 32, 64); (A).y += __shfl_xor((A).y, 32, 64);
    MQ(a00) MQ(a01) MQ(a10) MQ(a11) MQ(a20) MQ(a21) MQ(a30) MQ(a31)
#undef MQ

    if (qt != 0) return;
    float4 bv = *(const float4*)(bvec + fq * 4);
    float4* o = (float4*)(out + (size_t)n * (NHEADS * FDIM));
    if (end > start) {
        float rz0 = 1.f / z0;
        float rz1 = 1.f / z1;
        float rz2 = 1.f / z2;
        float rz3 = 1.f / z3;
        o[fq] = make_float4(fmaf(a00.x, rz0, bv.x), fmaf(a00.y, rz0, bv.y),
                            fmaf(a01.x, rz0, bv.z), fmaf(a01.y, rz0, bv.w));
        o[16 + fq] = make_float4(fmaf(a10.x, rz1, bv.x), fmaf(a10.y, rz1, bv.y),
                                 fmaf(a11.x, rz1, bv.z), fmaf(a11.y, rz1, bv.w));
        o[32 + fq] = make_float4(fmaf(a20.x, rz2, bv.x), fmaf(a20.y, rz2, bv.y),
                                 fmaf(a21.x, rz2, bv.z), fmaf(a21.y, rz2, bv.w));
        o[48 + fq] = make_float4(fmaf(a30.x, rz3, bv.x), fmaf(a30.y, rz3, bv.y),
                                 fmaf(a31.x, rz3, bv.z), fmaf(a31.y, rz3, bv.w));
    } else {
        o[fq] = bv; o[16 + fq] = bv; o[32 + fq] = bv; o[48 + fq] = bv;
    }
}

extern "C" void kernel_launch(void* const* d_in, const int* in_sizes, int n_in,
                              void* d_out, int out_size, void* d_ws, size_t ws_size,
                              hipStream_t stream) {
    const float* h   = (const float*)d_in[0];
    const int*   src = (const int*)d_in[1];
    const int*   dst = (const int*)d_in[2];
    const float* Wk  = (const float*)d_in[3];
    const float* Wq  = (const float*)d_in[4];
    const float* W   = (const float*)d_in[5];
    const float* b   = (const float*)d_in[6];
    float* out = (float*)d_out;

    const int N = in_sizes[0] / FDIM;   // 100000
    const int E = in_sizes[1];          // 1600000

    const int NBUCK = (N + 255) >> 8;               // 391
    const int NTILE = (E + TILE - 1) / TILE;        // 196
    const int KQB   = (N + 127) / 128;              // 782
    const int PB    = (N + 127) / 128;              // 782 (hp role)

    // Workspace: k16 12.8MB, q16 12.8MB, hp16 12.8MB,
    //            ebuf[NBUCK*BCAP u32] 9.6MB, srcs[E] 6.4MB,
    //            gcnt[512], rowptr[N].  (~55 MB)
    __half* k16 = (__half*)d_ws;
    __half* q16 = k16 + (size_t)N * FDIM;
    __half* hp16 = q16 + (size_t)N * FDIM;
    unsigned int* ebuf = (unsigned int*)(hp16 + (size_t)N * FDIM);
    int* srcs   = (int*)(ebuf + (size_t)NBUCK * BCAP);
    int* gcnt   = srcs + E;
    int* rowptr = gcnt + 512;

    hipMemsetAsync(gcnt, 0, 512 * sizeof(int), stream);

    k1_kernel<<<KQB + PB + NTILE, 256, 0, stream>>>(
        h, Wk, Wq, W, src, dst, k16, q16, hp16, gcnt, ebuf,
        N, E, KQB, PB, NBUCK);
    binB_kernel<<<NBUCK, 256, 0, stream>>>(gcnt, ebuf, rowptr, srcs, N);
    fused_sa_kernel<<<(N + 3) / 4, 256, 0, stream>>>(
        rowptr, srcs, k16, q16, hp16, b, out, N, E);
}

// Round 14
// 314.995 us; speedup vs baseline: 1.9433x; 1.0075x over previous
//
#include <hip/hip_runtime.h>
#include <hip/hip_fp16.h>
#include <math.h>

// GAT layer: N=100000, E=1600000, F=64, H=4 (Dh=16).
//
// Pipeline (4 dispatches): memset(gcnt) ->
// K1 {kq GEMM | hp GEMM (hp=h@W) | binA bucket-sort} ->
// binB (1024 thr/block: inline gcnt scan; LDS-staged counting sort; rowptr;
//   srcs streamed coalesced) ->
// fused_sa (score+aggregate one pass):
//   phase A: lane=(rr,hh) edge-parallel fp16 dot -> w=exp2(e') in REGISTER;
//   phase B: QUARTER-packed PV (lane=(qt,fq), uint2 loads, per-lane shfl).
//   R13: ALL gathers (k row + 4 hp rows) are issued BEFORE dot/exp — the
//   hp addresses depend only on srcs-shfl, so the two gather streams fly
//   concurrently (chain was srcs->k->dot->exp->shfl->hp->fma: 2 serial
//   memory round-trips; now 1).
//
// R0-R4 law: any per-edge random-slot global store/atomic costs 100-150us.
// All scattering happens in LDS; global writes are coalesced streams.
// BCAP overflow (32-sigma for random dst) is CLAMPED (graceful, no OOB).

#define FDIM 64
#define NHEADS 4
#define TILE 8192
#define BCAP 6144

typedef float f32x2 __attribute__((ext_vector_type(2)));

// ---- K1: multi-role: [0,KQB) kq | [KQB,KQB+PB) hp | [KQB+PB,+NTILE) binA --
__global__ __launch_bounds__(256) void k1_kernel(
    const float* __restrict__ h, const float* __restrict__ Wk,
    const float* __restrict__ Wq, const float* __restrict__ Wo,
    const int* __restrict__ src, const int* __restrict__ dst,
    __half* __restrict__ k16, __half* __restrict__ q16,
    __half* __restrict__ hp16, int* __restrict__ gcnt,
    unsigned int* __restrict__ ebuf,
    int N, int E, int KQB, int PB, int nbuck)
{
    __shared__ __align__(16) unsigned char smem_raw[39936];
    int bid = blockIdx.x;
    int t = threadIdx.x;
    if (bid < KQB) {
        // ---- kq role: k = h@(Wk*log2e), q = h@Wq, fp16 out ----
        float* sWk = (float*)smem_raw;
        float* sWq = (float*)(smem_raw + 16384);
        for (int i = t; i < FDIM * FDIM; i += 256) {
            sWk[i] = Wk[i] * 1.4426950408889634f;
            sWq[i] = Wq[i];
        }
        __syncthreads();
        int cg = t & 3;
        int rg = t >> 2;
        long base = (long)bid * 128 + rg * 2;
        const float4* sWk4 = (const float4*)sWk;
        const float4* sWq4 = (const float4*)sWq;
        const float4* h4 = (const float4*)h;
        float acck[2][16], accq[2][16];
#pragma unroll
        for (int i = 0; i < 2; ++i)
#pragma unroll
            for (int c = 0; c < 16; ++c) { acck[i][c] = 0.f; accq[i][c] = 0.f; }

        for (int fs = 0; fs < FDIM; fs += 4) {
            float4 hv[2];
#pragma unroll
            for (int i = 0; i < 2; ++i) {
                long r = base + i; if (r >= N) r = N - 1;
                hv[i] = h4[r * 16 + (fs >> 2)];
            }
#pragma unroll
            for (int fi = 0; fi < 4; ++fi) {
                int f = fs + fi;
                float4 wk0 = sWk4[f * 16 + cg * 4 + 0];
                float4 wk1 = sWk4[f * 16 + cg * 4 + 1];
                float4 wk2 = sWk4[f * 16 + cg * 4 + 2];
                float4 wk3 = sWk4[f * 16 + cg * 4 + 3];
                float4 wq0 = sWq4[f * 16 + cg * 4 + 0];
                float4 wq1 = sWq4[f * 16 + cg * 4 + 1];
                float4 wq2 = sWq4[f * 16 + cg * 4 + 2];
                float4 wq3 = sWq4[f * 16 + cg * 4 + 3];
#pragma unroll
                for (int i = 0; i < 2; ++i) {
                    float hvf = (&hv[i].x)[fi];
                    acck[i][0]  = fmaf(hvf, wk0.x, acck[i][0]);
                    acck[i][1]  = fmaf(hvf, wk0.y, acck[i][1]);
                    acck[i][2]  = fmaf(hvf, wk0.z, acck[i][2]);
                    acck[i][3]  = fmaf(hvf, wk0.w, acck[i][3]);
                    acck[i][4]  = fmaf(hvf, wk1.x, acck[i][4]);
                    acck[i][5]  = fmaf(hvf, wk1.y, acck[i][5]);
                    acck[i][6]  = fmaf(hvf, wk1.z, acck[i][6]);
                    acck[i][7]  = fmaf(hvf, wk1.w, acck[i][7]);
                    acck[i][8]  = fmaf(hvf, wk2.x, acck[i][8]);
                    acck[i][9]  = fmaf(hvf, wk2.y, acck[i][9]);
                    acck[i][10] = fmaf(hvf, wk2.z, acck[i][10]);
                    acck[i][11] = fmaf(hvf, wk2.w, acck[i][11]);
                    acck[i][12] = fmaf(hvf, wk3.x, acck[i][12]);
                    acck[i][13] = fmaf(hvf, wk3.y, acck[i][13]);
                    acck[i][14] = fmaf(hvf, wk3.z, acck[i][14]);
                    acck[i][15] = fmaf(hvf, wk3.w, acck[i][15]);
                    accq[i][0]  = fmaf(hvf, wq0.x, accq[i][0]);
                    accq[i][1]  = fmaf(hvf, wq0.y, accq[i][1]);
                    accq[i][2]  = fmaf(hvf, wq0.z, accq[i][2]);
                    accq[i][3]  = fmaf(hvf, wq0.w, accq[i][3]);
                    accq[i][4]  = fmaf(hvf, wq1.x, accq[i][4]);
                    accq[i][5]  = fmaf(hvf, wq1.y, accq[i][5]);
                    accq[i][6]  = fmaf(hvf, wq1.z, accq[i][6]);
                    accq[i][7]  = fmaf(hvf, wq1.w, accq[i][7]);
                    accq[i][8]  = fmaf(hvf, wq2.x, accq[i][8]);
                    accq[i][9]  = fmaf(hvf, wq2.y, accq[i][9]);
                    accq[i][10] = fmaf(hvf, wq2.z, accq[i][10]);
                    accq[i][11] = fmaf(hvf, wq2.w, accq[i][11]);
                    accq[i][12] = fmaf(hvf, wq3.x, accq[i][12]);
                    accq[i][13] = fmaf(hvf, wq3.y, accq[i][13]);
                    accq[i][14] = fmaf(hvf, wq3.z, accq[i][14]);
                    accq[i][15] = fmaf(hvf, wq3.w, accq[i][15]);
                }
            }
        }
#pragma unroll
        for (int i = 0; i < 2; ++i) {
            long r = base + i;
            if (r >= N) continue;
            __half2 hk[8], hq[8];
#pragma unroll
            for (int c = 0; c < 8; ++c) {
                hk[c] = __floats2half2_rn(acck[i][2 * c], acck[i][2 * c + 1]);
                hq[c] = __floats2half2_rn(accq[i][2 * c], accq[i][2 * c + 1]);
            }
            float4* kout = (float4*)(k16 + (size_t)r * FDIM + cg * 16);
            float4* qout = (float4*)(q16 + (size_t)r * FDIM + cg * 16);
            kout[0] = ((float4*)hk)[0]; kout[1] = ((float4*)hk)[1];
            qout[0] = ((float4*)hq)[0]; qout[1] = ((float4*)hq)[1];
        }
    } else if (bid < KQB + PB) {
        // ---- hp role: hp = h @ Wo (fp16 out), 128 rows/block ----
        float* sW = (float*)smem_raw;
        for (int i = t; i < FDIM * FDIM; i += 256) sW[i] = Wo[i];
        __syncthreads();
        int cg = t & 3;
        int rg = t >> 2;
        long base = (long)(bid - KQB) * 128 + rg * 2;
        const float4* sW4 = (const float4*)sW;
        const float4* h4 = (const float4*)h;
        float accp[2][16];
#pragma unroll
        for (int i = 0; i < 2; ++i)
#pragma unroll
            for (int c = 0; c < 16; ++c) accp[i][c] = 0.f;

        for (int fs = 0; fs < FDIM; fs += 4) {
            float4 hv[2];
#pragma unroll
            for (int i = 0; i < 2; ++i) {
                long r = base + i; if (r >= N) r = N - 1;
                hv[i] = h4[r * 16 + (fs >> 2)];
            }
#pragma unroll
            for (int fi = 0; fi < 4; ++fi) {
                int f = fs + fi;
                float4 w0 = sW4[f * 16 + cg * 4 + 0];
                float4 w1 = sW4[f * 16 + cg * 4 + 1];
                float4 w2 = sW4[f * 16 + cg * 4 + 2];
                float4 w3 = sW4[f * 16 + cg * 4 + 3];
#pragma unroll
                for (int i = 0; i < 2; ++i) {
                    float hvf = (&hv[i].x)[fi];
                    accp[i][0]  = fmaf(hvf, w0.x, accp[i][0]);
                    accp[i][1]  = fmaf(hvf, w0.y, accp[i][1]);
                    accp[i][2]  = fmaf(hvf, w0.z, accp[i][2]);
                    accp[i][3]  = fmaf(hvf, w0.w, accp[i][3]);
                    accp[i][4]  = fmaf(hvf, w1.x, accp[i][4]);
                    accp[i][5]  = fmaf(hvf, w1.y, accp[i][5]);
                    accp[i][6]  = fmaf(hvf, w1.z, accp[i][6]);
                    accp[i][7]  = fmaf(hvf, w1.w, accp[i][7]);
                    accp[i][8]  = fmaf(hvf, w2.x, accp[i][8]);
                    accp[i][9]  = fmaf(hvf, w2.y, accp[i][9]);
                    accp[i][10] = fmaf(hvf, w2.z, accp[i][10]);
                    accp[i][11] = fmaf(hvf, w2.w, accp[i][11]);
                    accp[i][12] = fmaf(hvf, w3.x, accp[i][12]);
                    accp[i][13] = fmaf(hvf, w3.y, accp[i][13]);
                    accp[i][14] = fmaf(hvf, w3.z, accp[i][14]);
                    accp[i][15] = fmaf(hvf, w3.w, accp[i][15]);
                }
            }
        }
#pragma unroll
        for (int i = 0; i < 2; ++i) {
            long r = base + i;
            if (r >= N) continue;
            __half2 hp[8];
#pragma unroll
            for (int c = 0; c < 8; ++c)
                hp[c] = __floats2half2_rn(accp[i][2 * c], accp[i][2 * c + 1]);
            float4* pout = (float4*)(hp16 + (size_t)r * FDIM + cg * 16);
            pout[0] = ((float4*)hp)[0];
            pout[1] = ((float4*)hp)[1];
        }
    } else {
        // ---- binA role: tile of 8192 edges -> LDS counting sort by bucket
        // (dst>>8) -> per-bucket coalesced append to ebuf. Packed entry:
        // src<<8 | (dst&255). Appends clamped to BCAP.
        unsigned int* bh     = (unsigned int*)smem_raw;          // 512
        unsigned int* bstart = bh + 512;                          // 512
        unsigned int* bbase  = bstart + 512;                      // 512
        unsigned int* sd     = bbase + 512;                       // 256
        unsigned int* ebuf_l = sd + 256;                          // 8192
        long e0 = (long)(bid - KQB - PB) * TILE;
        int cnt_tile = (int)(((long)E - e0 < (long)TILE) ? ((long)E - e0) : (long)TILE);

        bh[t] = 0; bh[t + 256] = 0;
        __syncthreads();
        for (int j = t; j < cnt_tile; j += 256)
            atomicAdd(&bh[dst[e0 + j] >> 8], 1u);
        __syncthreads();
        unsigned int c0 = bh[2 * t], c1 = bh[2 * t + 1];
        unsigned int s = c0 + c1;
        sd[t] = s;
        __syncthreads();
        for (int off = 1; off < 256; off <<= 1) {
            unsigned int v = (t >= off) ? sd[t - off] : 0;
            __syncthreads();
            sd[t] += v;
            __syncthreads();
        }
        unsigned int ex = sd[t] - s;
        bh[2 * t] = ex;          bstart[2 * t] = ex;
        bh[2 * t + 1] = ex + c0; bstart[2 * t + 1] = ex + c0;
        if (c0 > 0) bbase[2 * t] = (unsigned int)atomicAdd(&gcnt[2 * t], (int)c0);
        if (c1 > 0) bbase[2 * t + 1] = (unsigned int)atomicAdd(&gcnt[2 * t + 1], (int)c1);
        __syncthreads();
        for (int j = t; j < cnt_tile; j += 256) {
            int d = dst[e0 + j];
            int sv = src[e0 + j];
            unsigned int pos = atomicAdd(&bh[d >> 8], 1u);
            ebuf_l[pos] = ((unsigned int)sv << 8) | (unsigned int)(d & 255);
        }
        __syncthreads();
        int wave = t >> 6, lane = t & 63;
        for (int b = wave; b < nbuck; b += 4) {
            unsigned int st = bstart[b];
            unsigned int en = bh[b];
            if (st == en) continue;
            unsigned int gb = bbase[b];
            if (gb >= (unsigned int)BCAP) continue;
            unsigned int room = (unsigned int)BCAP - gb;
            if (en - st > room) en = st + room;
            unsigned int* dstp = ebuf + (size_t)b * BCAP + gb;
            for (unsigned int j = st + lane; j < en; j += 64)
                dstp[j - st] = ebuf_l[j];
        }
    }
}

// K2: binB, 1024 threads/block (16 waves: 4x the latency hiding for the
// 6144-element staging/scatter loops). Inline gcnt scan on first 256
// threads (all-thread barriers); LDS-staged counting sort; rowptr; srcs.
__global__ __launch_bounds__(1024) void binB_kernel(
    const int* __restrict__ gcnt, const unsigned int* __restrict__ ebuf,
    int* __restrict__ rowptr, int* __restrict__ srcs, int N)
{
    __shared__ int sg[512];
    __shared__ unsigned int lh[256];
    __shared__ unsigned int sd[256];
    __shared__ unsigned int ebuf_l[BCAP];
    __shared__ unsigned int srcs_l[BCAP];
    int t = threadIdx.x;
    int b = blockIdx.x;

    // inline exclusive scan of gcnt (first 256 threads, 2 entries each)
    int c0 = 0, c1 = 0;
    if (t < 256) {
        c0 = gcnt[2 * t]; c1 = gcnt[2 * t + 1];
        sd[t] = (unsigned int)(c0 + c1);
        lh[t] = 0;
    }
    __syncthreads();
    for (int off = 1; off < 256; off <<= 1) {
        unsigned int v = (t < 256 && t >= off) ? sd[t - off] : 0;
        __syncthreads();
        if (t < 256) sd[t] += v;
        __syncthreads();
    }
    if (t < 256) {
        int ex = (int)sd[t] - (c0 + c1);
        sg[2 * t] = ex;
        sg[2 * t + 1] = ex + c0;
    }
    __syncthreads();
    int gb = sg[b];
    int cnt = gcnt[b];
    if (cnt > BCAP) cnt = BCAP;   // matches binA clamp
    int n0 = b << 8;
    const unsigned int* eb = ebuf + (size_t)b * BCAP;

    // single global pass: stage into LDS + histogram
    for (int j = t; j < cnt; j += 1024) {
        unsigned int p = eb[j];
        ebuf_l[j] = p;
        atomicAdd(&lh[p & 255u], 1u);
    }
    __syncthreads();
    unsigned int c = 0;
    if (t < 256) { c = lh[t]; sd[t] = c; }
    __syncthreads();
    for (int off = 1; off < 256; off <<= 1) {
        unsigned int v = (t < 256 && t >= off) ? sd[t - off] : 0;
        __syncthreads();
        if (t < 256) sd[t] += v;
        __syncthreads();
    }
    if (t < 256) {
        unsigned int excl = sd[t] - c;
        lh[t] = excl;
        if (n0 + t < N) rowptr[n0 + t] = gb + (int)excl;
    }
    __syncthreads();
    for (int j = t; j < cnt; j += 1024) {
        unsigned int p = ebuf_l[j];
        unsigned int pos = atomicAdd(&lh[p & 255u], 1u);
        srcs_l[pos] = p >> 8;
    }
    __syncthreads();
    for (int j = t; j < cnt; j += 1024)
        srcs[gb + j] = (int)srcs_l[j];
}

__device__ __forceinline__ float dot16(const float4* kk, const float* qf) {
    const __half2* kh = (const __half2*)kk;
    float acc = 0.f;
#pragma unroll
    for (int j = 0; j < 8; ++j) {
        float2 kf = __half22float2(kh[j]);
        acc = fmaf(kf.x, qf[2 * j], acc);
        acc = fmaf(kf.y, qf[2 * j + 1], acc);
    }
    return acc;
}

// K3: fused score+aggregate. One wave per node (4 waves/block).
// Phase A: lane=(rr,hh) computes w = exp2(k16[src].q) edge-parallel.
// Phase B: QUARTER-packed PV: lane=(qt,fq), uint2 loads cover 4 records
// per gather inst. R13: all 5 gathers (k row + 4 hp rows) issue BEFORE
// the dot/exp — hp addresses come from srcs-shfl only, so both gather
// streams are in flight concurrently.
__global__ __launch_bounds__(256) void fused_sa_kernel(
    const int* __restrict__ rowptr, const int* __restrict__ srcs,
    const __half* __restrict__ k16, const __half* __restrict__ q16,
    const __half* __restrict__ hp16, const float* __restrict__ bvec,
    float* __restrict__ out, int N, int E)
{
    int lane = threadIdx.x & 63;
    int n = blockIdx.x * 4 + (threadIdx.x >> 6);
    if (n >= N) return;
    int start = rowptr[n];
    int end   = (n == N - 1) ? E : rowptr[n + 1];

    int hh = lane & 3;     // phase A: head
    int rr = lane >> 2;    // phase A: record slot 0..15
    int qt = lane >> 4;    // phase B: quarter 0..3
    int fq = lane & 15;    // phase B: feature quad 4fq..4fq+3

    const float4* qp = (const float4*)(q16 + (size_t)n * FDIM + hh * 16);
    float4 qv[2] = { qp[0], qp[1] };
    const __half2* qh = (const __half2*)qv;
    float qf[16];
#pragma unroll
    for (int j = 0; j < 8; ++j) {
        float2 f = __half22float2(qh[j]);
        qf[2 * j] = f.x;
        qf[2 * j + 1] = f.y;
    }

    float zacc = 0.f;
    // acc[head][lo/hi]: features 4fq+{0,1} / 4fq+{2,3}
    f32x2 a00 = {0.f,0.f}, a01 = {0.f,0.f};
    f32x2 a10 = {0.f,0.f}, a11 = {0.f,0.f};
    f32x2 a20 = {0.f,0.f}, a21 = {0.f,0.f};
    f32x2 a30 = {0.f,0.f}, a31 = {0.f,0.f};

    for (int base = start; base < end; base += 16) {
        // ---- issue ALL gathers first ----
        int idx = base + rr;
        bool valid = (idx < end);
        int ic = valid ? idx : (end - 1);
        int sA = srcs[ic];
        // distribute srcs for phase B (depends only on sA)
        int sB0 = __shfl(sA, 4 * qt,      64);
        int sB1 = __shfl(sA, 16 + 4 * qt, 64);
        int sB2 = __shfl(sA, 32 + 4 * qt, 64);
        int sB3 = __shfl(sA, 48 + 4 * qt, 64);
        const float4* kp = (const float4*)(k16 + (size_t)sA * FDIM + hh * 16);
        float4 ka0 = kp[0], ka1 = kp[1];
        uint2 g0 = *(const uint2*)(hp16 + (size_t)sB0 * FDIM + fq * 4);
        uint2 g1 = *(const uint2*)(hp16 + (size_t)sB1 * FDIM + fq * 4);
        uint2 g2 = *(const uint2*)(hp16 + (size_t)sB2 * FDIM + fq * 4);
        uint2 g3 = *(const uint2*)(hp16 + (size_t)sB3 * FDIM + fq * 4);

        // ---- phase A compute (k gather + hp gathers in flight) ----
        float4 ka[2] = { ka0, ka1 };
        float w = __builtin_amdgcn_exp2f(dot16(ka, qf));
        w = valid ? w : 0.f;
        zacc += w;

        // ---- phase B: fma groups (work-skip guards kept) ----
#define GRP(G, LBASE)                                                      \
    {   float w0 = __shfl(w, (LBASE) + 0, 64);                             \
        float w1 = __shfl(w, (LBASE) + 1, 64);                             \
        float w2 = __shfl(w, (LBASE) + 2, 64);                             \
        float w3 = __shfl(w, (LBASE) + 3, 64);                             \
        float2 flo = __half22float2(*(__half2*)&(G).x);                    \
        float2 fhi = __half22float2(*(__half2*)&(G).y);                    \
        f32x2 vlo; vlo.x = flo.x; vlo.y = flo.y;                           \
        f32x2 vhi; vhi.x = fhi.x; vhi.y = fhi.y;                           \
        f32x2 wv;                                                          \
        wv.x = w0; wv.y = w0;                                              \
        a00 = __builtin_elementwise_fma(wv, vlo, a00);                     \
        a01 = __builtin_elementwise_fma(wv, vhi, a01);                     \
        wv.x = w1; wv.y = w1;                                              \
        a10 = __builtin_elementwise_fma(wv, vlo, a10);                     \
        a11 = __builtin_elementwise_fma(wv, vhi, a11);                     \
        wv.x = w2; wv.y = w2;                                              \
        a20 = __builtin_elementwise_fma(wv, vlo, a20);                     \
        a21 = __builtin_elementwise_fma(wv, vhi, a21);                     \
        wv.x = w3; wv.y = w3;                                              \
        a30 = __builtin_elementwise_fma(wv, vlo, a30);                     \
        a31 = __builtin_elementwise_fma(wv, vhi, a31);                     }

        GRP(g0, 4 * qt)
        if (base + 4 < end)  { GRP(g1, 16 + 4 * qt) }
        if (base + 8 < end)  { GRP(g2, 32 + 4 * qt) }
        if (base + 12 < end) { GRP(g3, 48 + 4 * qt) }
#undef GRP
    }

    // fold z over record slots (lanes sharing hh differ in bits 2..5)
    zacc += __shfl_xor(zacc, 4, 64);
    zacc += __shfl_xor(zacc, 8, 64);
    zacc += __shfl_xor(zacc, 16, 64);
    zacc += __shfl_xor(zacc, 32, 64);
    float z0 = __shfl(zacc, 0, 64);
    float z1 = __shfl(zacc, 1, 64);
    float z2 = __shfl(zacc, 2, 64);
    float z3 = __shfl(zacc, 3, 64);

    // merge the 4 quarter partial sums (xor 16, then 32)
#define MQ(A) \
    (A).x += __shfl_xor((A).x, 16, 64); (A).y += __shfl_xor((A).y, 16, 64); \
    (A).x += __shfl_xor((A).x, 32, 64); (A).y += __shfl_xor((A).y, 32, 64);
    MQ(a00) MQ(a01) MQ(a10) MQ(a11) MQ(a20) MQ(a21) MQ(a30) MQ(a31)
#undef MQ

    if (qt != 0) return;
    float4 bv = *(const float4*)(bvec + fq * 4);
    float4* o = (float4*)(out + (size_t)n * (NHEADS * FDIM));
    if (end > start) {
        float rz0 = 1.f / z0;
        float rz1 = 1.f / z1;
        float rz2 = 1.f / z2;
        float rz3 = 1.f / z3;
        o[fq] = make_float4(fmaf(a00.x, rz0, bv.x), fmaf(a00.y, rz0, bv.y),
                            fmaf(a01.x, rz0, bv.z), fmaf(a01.y, rz0, bv.w));
        o[16 + fq] = make_float4(fmaf(a10.x, rz1, bv.x), fmaf(a10.y, rz1, bv.y),
                                 fmaf(a11.x, rz1, bv.z), fmaf(a11.y, rz1, bv.w));
        o[32 + fq] = make_float4(fmaf(a20.x, rz2, bv.x), fmaf(a20.y, rz2, bv.y),
                                 fmaf(a21.x, rz2, bv.z), fmaf(a21.y, rz2, bv.w));
        o[48 + fq] = make_float4(fmaf(a30.x, rz3, bv.x), fmaf(a30.y, rz3, bv.y),
                                 fmaf(a31.x, rz3, bv.z), fmaf(a31.y, rz3, bv.w));
    } else {
        o[fq] = bv; o[16 + fq] = bv; o[32 + fq] = bv; o[48 + fq] = bv;
    }
}

extern "C" void kernel_launch(void* const* d_in, const int* in_sizes, int n_in,
                              void* d_out, int out_size, void* d_ws, size_t ws_size,
                              hipStream_t stream) {
    const float* h   = (const float*)d_in[0];
    const int*   src = (const int*)d_in[1];
    const int*   dst = (const int*)d_in[2];
    const float* Wk  = (const float*)d_in[3];
    const float* Wq  = (const float*)d_in[4];
    const float* W   = (const float*)d_in[5];
    const float* b   = (const float*)d_in[6];
    float* out = (float*)d_out;

    const int N = in_sizes[0] / FDIM;   // 100000
    const int E = in_sizes[1];          // 1600000

    const int NBUCK = (N + 255) >> 8;               // 391
    const int NTILE = (E + TILE - 1) / TILE;        // 196
    const int KQB   = (N + 127) / 128;              // 782
    const int PB    = (N + 127) / 128;              // 782 (hp role)

    // Workspace: k16 12.8MB, q16 12.8MB, hp16 12.8MB,
    //            ebuf[NBUCK*BCAP u32] 9.6MB, srcs[E] 6.4MB,
    //            gcnt[512], rowptr[N].  (~55 MB)
    __half* k16 = (__half*)d_ws;
    __half* q16 = k16 + (size_t)N * FDIM;
    __half* hp16 = q16 + (size_t)N * FDIM;
    unsigned int* ebuf = (unsigned int*)(hp16 + (size_t)N * FDIM);
    int* srcs   = (int*)(ebuf + (size_t)NBUCK * BCAP);
    int* gcnt   = srcs + E;
    int* rowptr = gcnt + 512;

    hipMemsetAsync(gcnt, 0, 512 * sizeof(int), stream);

    k1_kernel<<<KQB + PB + NTILE, 256, 0, stream>>>(
        h, Wk, Wq, W, src, dst, k16, q16, hp16, gcnt, ebuf,
        N, E, KQB, PB, NBUCK);
    binB_kernel<<<NBUCK, 1024, 0, stream>>>(gcnt, ebuf, rowptr, srcs, N);
    fused_sa_kernel<<<(N + 3) / 4, 256, 0, stream>>>(
        rowptr, srcs, k16, q16, hp16, b, out, N, E);
}

// Round 15
// 294.804 us; speedup vs baseline: 2.0764x; 1.0685x over previous
//
#include <hip/hip_runtime.h>
#include <hip/hip_fp16.h>
#include <math.h>

// GAT layer: N=100000, E=1600000, F=64, H=4 (Dh=16).
//
// Pipeline (4 dispatches): memset(gcnt) ->
// K1 {kq GEMM | hp GEMM (hp=h@W) | binA bucket-sort} ->
// binB (1024 thr/block: inline gcnt scan; LDS-staged counting sort; rowptr;
//   srcs streamed coalesced) ->
// fused_sa QUARTER-PER-NODE (R15): each 16-lane quarter owns one node
//   (4 nodes/wave). Phase A: ql=(rr,hh) does 4 records x 4 heads per chunk
//   (granularity 16->4: dummy tail work -30%). Phase B: lane owns feature
//   quad 4ql..4ql+3 for ALL heads -> NO cross-lane accumulator merge
//   epilogue (was 32 shfl + 32 add per node); z-fold is 2 shfl_xor. Wave
//   carries 4 independent node chains (latency overlap).
//
// R0-R4 law: any per-edge random-slot global store/atomic costs 100-150us.
// All scattering happens in LDS; global writes are coalesced streams.
// BCAP overflow (32-sigma for random dst) is CLAMPED (graceful, no OOB).

#define FDIM 64
#define NHEADS 4
#define TILE 8192
#define BCAP 6144

typedef float f32x2 __attribute__((ext_vector_type(2)));

// ---- K1: multi-role: [0,KQB) kq | [KQB,KQB+PB) hp | [KQB+PB,+NTILE) binA --
__global__ __launch_bounds__(256) void k1_kernel(
    const float* __restrict__ h, const float* __restrict__ Wk,
    const float* __restrict__ Wq, const float* __restrict__ Wo,
    const int* __restrict__ src, const int* __restrict__ dst,
    __half* __restrict__ k16, __half* __restrict__ q16,
    __half* __restrict__ hp16, int* __restrict__ gcnt,
    unsigned int* __restrict__ ebuf,
    int N, int E, int KQB, int PB, int nbuck)
{
    __shared__ __align__(16) unsigned char smem_raw[39936];
    int bid = blockIdx.x;
    int t = threadIdx.x;
    if (bid < KQB) {
        // ---- kq role: k = h@(Wk*log2e), q = h@Wq, fp16 out ----
        float* sWk = (float*)smem_raw;
        float* sWq = (float*)(smem_raw + 16384);
        for (int i = t; i < FDIM * FDIM; i += 256) {
            sWk[i] = Wk[i] * 1.4426950408889634f;
            sWq[i] = Wq[i];
        }
        __syncthreads();
        int cg = t & 3;
        int rg = t >> 2;
        long base = (long)bid * 128 + rg * 2;
        const float4* sWk4 = (const float4*)sWk;
        const float4* sWq4 = (const float4*)sWq;
        const float4* h4 = (const float4*)h;
        float acck[2][16], accq[2][16];
#pragma unroll
        for (int i = 0; i < 2; ++i)
#pragma unroll
            for (int c = 0; c < 16; ++c) { acck[i][c] = 0.f; accq[i][c] = 0.f; }

        for (int fs = 0; fs < FDIM; fs += 4) {
            float4 hv[2];
#pragma unroll
            for (int i = 0; i < 2; ++i) {
                long r = base + i; if (r >= N) r = N - 1;
                hv[i] = h4[r * 16 + (fs >> 2)];
            }
#pragma unroll
            for (int fi = 0; fi < 4; ++fi) {
                int f = fs + fi;
                float4 wk0 = sWk4[f * 16 + cg * 4 + 0];
                float4 wk1 = sWk4[f * 16 + cg * 4 + 1];
                float4 wk2 = sWk4[f * 16 + cg * 4 + 2];
                float4 wk3 = sWk4[f * 16 + cg * 4 + 3];
                float4 wq0 = sWq4[f * 16 + cg * 4 + 0];
                float4 wq1 = sWq4[f * 16 + cg * 4 + 1];
                float4 wq2 = sWq4[f * 16 + cg * 4 + 2];
                float4 wq3 = sWq4[f * 16 + cg * 4 + 3];
#pragma unroll
                for (int i = 0; i < 2; ++i) {
                    float hvf = (&hv[i].x)[fi];
                    acck[i][0]  = fmaf(hvf, wk0.x, acck[i][0]);
                    acck[i][1]  = fmaf(hvf, wk0.y, acck[i][1]);
                    acck[i][2]  = fmaf(hvf, wk0.z, acck[i][2]);
                    acck[i][3]  = fmaf(hvf, wk0.w, acck[i][3]);
                    acck[i][4]  = fmaf(hvf, wk1.x, acck[i][4]);
                    acck[i][5]  = fmaf(hvf, wk1.y, acck[i][5]);
                    acck[i][6]  = fmaf(hvf, wk1.z, acck[i][6]);
                    acck[i][7]  = fmaf(hvf, wk1.w, acck[i][7]);
                    acck[i][8]  = fmaf(hvf, wk2.x, acck[i][8]);
                    acck[i][9]  = fmaf(hvf, wk2.y, acck[i][9]);
                    acck[i][10] = fmaf(hvf, wk2.z, acck[i][10]);
                    acck[i][11] = fmaf(hvf, wk2.w, acck[i][11]);
                    acck[i][12] = fmaf(hvf, wk3.x, acck[i][12]);
                    acck[i][13] = fmaf(hvf, wk3.y, acck[i][13]);
                    acck[i][14] = fmaf(hvf, wk3.z, acck[i][14]);
                    acck[i][15] = fmaf(hvf, wk3.w, acck[i][15]);
                    accq[i][0]  = fmaf(hvf, wq0.x, accq[i][0]);
                    accq[i][1]  = fmaf(hvf, wq0.y, accq[i][1]);
                    accq[i][2]  = fmaf(hvf, wq0.z, accq[i][2]);
                    accq[i][3]  = fmaf(hvf, wq0.w, accq[i][3]);
                    accq[i][4]  = fmaf(hvf, wq1.x, accq[i][4]);
                    accq[i][5]  = fmaf(hvf, wq1.y, accq[i][5]);
                    accq[i][6]  = fmaf(hvf, wq1.z, accq[i][6]);
                    accq[i][7]  = fmaf(hvf, wq1.w, accq[i][7]);
                    accq[i][8]  = fmaf(hvf, wq2.x, accq[i][8]);
                    accq[i][9]  = fmaf(hvf, wq2.y, accq[i][9]);
                    accq[i][10] = fmaf(hvf, wq2.z, accq[i][10]);
                    accq[i][11] = fmaf(hvf, wq2.w, accq[i][11]);
                    accq[i][12] = fmaf(hvf, wq3.x, accq[i][12]);
                    accq[i][13] = fmaf(hvf, wq3.y, accq[i][13]);
                    accq[i][14] = fmaf(hvf, wq3.z, accq[i][14]);
                    accq[i][15] = fmaf(hvf, wq3.w, accq[i][15]);
                }
            }
        }
#pragma unroll
        for (int i = 0; i < 2; ++i) {
            long r = base + i;
            if (r >= N) continue;
            __half2 hk[8], hq[8];
#pragma unroll
            for (int c = 0; c < 8; ++c) {
                hk[c] = __floats2half2_rn(acck[i][2 * c], acck[i][2 * c + 1]);
                hq[c] = __floats2half2_rn(accq[i][2 * c], accq[i][2 * c + 1]);
            }
            float4* kout = (float4*)(k16 + (size_t)r * FDIM + cg * 16);
            float4* qout = (float4*)(q16 + (size_t)r * FDIM + cg * 16);
            kout[0] = ((float4*)hk)[0]; kout[1] = ((float4*)hk)[1];
            qout[0] = ((float4*)hq)[0]; qout[1] = ((float4*)hq)[1];
        }
    } else if (bid < KQB + PB) {
        // ---- hp role: hp = h @ Wo (fp16 out), 128 rows/block ----
        float* sW = (float*)smem_raw;
        for (int i = t; i < FDIM * FDIM; i += 256) sW[i] = Wo[i];
        __syncthreads();
        int cg = t & 3;
        int rg = t >> 2;
        long base = (long)(bid - KQB) * 128 + rg * 2;
        const float4* sW4 = (const float4*)sW;
        const float4* h4 = (const float4*)h;
        float accp[2][16];
#pragma unroll
        for (int i = 0; i < 2; ++i)
#pragma unroll
            for (int c = 0; c < 16; ++c) accp[i][c] = 0.f;

        for (int fs = 0; fs < FDIM; fs += 4) {
            float4 hv[2];
#pragma unroll
            for (int i = 0; i < 2; ++i) {
                long r = base + i; if (r >= N) r = N - 1;
                hv[i] = h4[r * 16 + (fs >> 2)];
            }
#pragma unroll
            for (int fi = 0; fi < 4; ++fi) {
                int f = fs + fi;
                float4 w0 = sW4[f * 16 + cg * 4 + 0];
                float4 w1 = sW4[f * 16 + cg * 4 + 1];
                float4 w2 = sW4[f * 16 + cg * 4 + 2];
                float4 w3 = sW4[f * 16 + cg * 4 + 3];
#pragma unroll
                for (int i = 0; i < 2; ++i) {
                    float hvf = (&hv[i].x)[fi];
                    accp[i][0]  = fmaf(hvf, w0.x, accp[i][0]);
                    accp[i][1]  = fmaf(hvf, w0.y, accp[i][1]);
                    accp[i][2]  = fmaf(hvf, w0.z, accp[i][2]);
                    accp[i][3]  = fmaf(hvf, w0.w, accp[i][3]);
                    accp[i][4]  = fmaf(hvf, w1.x, accp[i][4]);
                    accp[i][5]  = fmaf(hvf, w1.y, accp[i][5]);
                    accp[i][6]  = fmaf(hvf, w1.z, accp[i][6]);
                    accp[i][7]  = fmaf(hvf, w1.w, accp[i][7]);
                    accp[i][8]  = fmaf(hvf, w2.x, accp[i][8]);
                    accp[i][9]  = fmaf(hvf, w2.y, accp[i][9]);
                    accp[i][10] = fmaf(hvf, w2.z, accp[i][10]);
                    accp[i][11] = fmaf(hvf, w2.w, accp[i][11]);
                    accp[i][12] = fmaf(hvf, w3.x, accp[i][12]);
                    accp[i][13] = fmaf(hvf, w3.y, accp[i][13]);
                    accp[i][14] = fmaf(hvf, w3.z, accp[i][14]);
                    accp[i][15] = fmaf(hvf, w3.w, accp[i][15]);
                }
            }
        }
#pragma unroll
        for (int i = 0; i < 2; ++i) {
            long r = base + i;
            if (r >= N) continue;
            __half2 hp[8];
#pragma unroll
            for (int c = 0; c < 8; ++c)
                hp[c] = __floats2half2_rn(accp[i][2 * c], accp[i][2 * c + 1]);
            float4* pout = (float4*)(hp16 + (size_t)r * FDIM + cg * 16);
            pout[0] = ((float4*)hp)[0];
            pout[1] = ((float4*)hp)[1];
        }
    } else {
        // ---- binA role: tile of 8192 edges -> LDS counting sort by bucket
        // (dst>>8) -> per-bucket coalesced append to ebuf. Packed entry:
        // src<<8 | (dst&255). Appends clamped to BCAP.
        unsigned int* bh     = (unsigned int*)smem_raw;          // 512
        unsigned int* bstart = bh + 512;                          // 512
        unsigned int* bbase  = bstart + 512;                      // 512
        unsigned int* sd     = bbase + 512;                       // 256
        unsigned int* ebuf_l = sd + 256;                          // 8192
        long e0 = (long)(bid - KQB - PB) * TILE;
        int cnt_tile = (int)(((long)E - e0 < (long)TILE) ? ((long)E - e0) : (long)TILE);

        bh[t] = 0; bh[t + 256] = 0;
        __syncthreads();
        for (int j = t; j < cnt_tile; j += 256)
            atomicAdd(&bh[dst[e0 + j] >> 8], 1u);
        __syncthreads();
        unsigned int c0 = bh[2 * t], c1 = bh[2 * t + 1];
        unsigned int s = c0 + c1;
        sd[t] = s;
        __syncthreads();
        for (int off = 1; off < 256; off <<= 1) {
            unsigned int v = (t >= off) ? sd[t - off] : 0;
            __syncthreads();
            sd[t] += v;
            __syncthreads();
        }
        unsigned int ex = sd[t] - s;
        bh[2 * t] = ex;          bstart[2 * t] = ex;
        bh[2 * t + 1] = ex + c0; bstart[2 * t + 1] = ex + c0;
        if (c0 > 0) bbase[2 * t] = (unsigned int)atomicAdd(&gcnt[2 * t], (int)c0);
        if (c1 > 0) bbase[2 * t + 1] = (unsigned int)atomicAdd(&gcnt[2 * t + 1], (int)c1);
        __syncthreads();
        for (int j = t; j < cnt_tile; j += 256) {
            int d = dst[e0 + j];
            int sv = src[e0 + j];
            unsigned int pos = atomicAdd(&bh[d >> 8], 1u);
            ebuf_l[pos] = ((unsigned int)sv << 8) | (unsigned int)(d & 255);
        }
        __syncthreads();
        int wave = t >> 6, lane = t & 63;
        for (int b = wave; b < nbuck; b += 4) {
            unsigned int st = bstart[b];
            unsigned int en = bh[b];
            if (st == en) continue;
            unsigned int gb = bbase[b];
            if (gb >= (unsigned int)BCAP) continue;
            unsigned int room = (unsigned int)BCAP - gb;
            if (en - st > room) en = st + room;
            unsigned int* dstp = ebuf + (size_t)b * BCAP + gb;
            for (unsigned int j = st + lane; j < en; j += 64)
                dstp[j - st] = ebuf_l[j];
        }
    }
}

// K2: binB, 1024 threads/block (16 waves of latency hiding). Inline gcnt
// scan on first 256 threads; LDS-staged counting sort; rowptr; srcs.
__global__ __launch_bounds__(1024) void binB_kernel(
    const int* __restrict__ gcnt, const unsigned int* __restrict__ ebuf,
    int* __restrict__ rowptr, int* __restrict__ srcs, int N)
{
    __shared__ int sg[512];
    __shared__ unsigned int lh[256];
    __shared__ unsigned int sd[256];
    __shared__ unsigned int ebuf_l[BCAP];
    __shared__ unsigned int srcs_l[BCAP];
    int t = threadIdx.x;
    int b = blockIdx.x;

    // inline exclusive scan of gcnt (first 256 threads, 2 entries each)
    int c0 = 0, c1 = 0;
    if (t < 256) {
        c0 = gcnt[2 * t]; c1 = gcnt[2 * t + 1];
        sd[t] = (unsigned int)(c0 + c1);
        lh[t] = 0;
    }
    __syncthreads();
    for (int off = 1; off < 256; off <<= 1) {
        unsigned int v = (t < 256 && t >= off) ? sd[t - off] : 0;
        __syncthreads();
        if (t < 256) sd[t] += v;
        __syncthreads();
    }
    if (t < 256) {
        int ex = (int)sd[t] - (c0 + c1);
        sg[2 * t] = ex;
        sg[2 * t + 1] = ex + c0;
    }
    __syncthreads();
    int gb = sg[b];
    int cnt = gcnt[b];
    if (cnt > BCAP) cnt = BCAP;   // matches binA clamp
    int n0 = b << 8;
    const unsigned int* eb = ebuf + (size_t)b * BCAP;

    // single global pass: stage into LDS + histogram
    for (int j = t; j < cnt; j += 1024) {
        unsigned int p = eb[j];
        ebuf_l[j] = p;
        atomicAdd(&lh[p & 255u], 1u);
    }
    __syncthreads();
    unsigned int c = 0;
    if (t < 256) { c = lh[t]; sd[t] = c; }
    __syncthreads();
    for (int off = 1; off < 256; off <<= 1) {
        unsigned int v = (t < 256 && t >= off) ? sd[t - off] : 0;
        __syncthreads();
        if (t < 256) sd[t] += v;
        __syncthreads();
    }
    if (t < 256) {
        unsigned int excl = sd[t] - c;
        lh[t] = excl;
        if (n0 + t < N) rowptr[n0 + t] = gb + (int)excl;
    }
    __syncthreads();
    for (int j = t; j < cnt; j += 1024) {
        unsigned int p = ebuf_l[j];
        unsigned int pos = atomicAdd(&lh[p & 255u], 1u);
        srcs_l[pos] = p >> 8;
    }
    __syncthreads();
    for (int j = t; j < cnt; j += 1024)
        srcs[gb + j] = (int)srcs_l[j];
}

__device__ __forceinline__ float dot16(const float4* kk, const float* qf) {
    const __half2* kh = (const __half2*)kk;
    float acc = 0.f;
#pragma unroll
    for (int j = 0; j < 8; ++j) {
        float2 kf = __half22float2(kh[j]);
        acc = fmaf(kf.x, qf[2 * j], acc);
        acc = fmaf(kf.y, qf[2 * j + 1], acc);
    }
    return acc;
}

// K3: fused score+aggregate, QUARTER-PER-NODE. 16-lane quarter = one node
// (4 nodes/wave, 16/block). Per chunk of 4 records:
//   phase A: ql=(rr=ql>>2, hh=ql&3) -> 4 records x 4 heads, fp16 dot,
//            w=exp2(e') in register (w=0 for tail slots).
//   phase B: lane owns feats 4ql..4ql+3 of its quarter's records for ALL
//            heads; per record one uint2 gather + 4 w-shfls + 8 pk-fma.
// Epilogue: z-fold = 2 shfl_xor (within quarter); NO accumulator merges;
// 4 coalesced float4 stores per lane.
__global__ __launch_bounds__(256) void fused_sa_kernel(
    const int* __restrict__ rowptr, const int* __restrict__ srcs,
    const __half* __restrict__ k16, const __half* __restrict__ q16,
    const __half* __restrict__ hp16, const float* __restrict__ bvec,
    float* __restrict__ out, int N, int E)
{
    int lane = threadIdx.x & 63;
    int wid = threadIdx.x >> 6;
    int qt = lane >> 4;    // quarter = node slot
    int ql = lane & 15;    // lane within quarter
    int n = blockIdx.x * 16 + wid * 4 + qt;
    bool nvalid = (n < N);
    int nc = nvalid ? n : N - 1;
    int start = rowptr[nc];
    int end = (nc == N - 1) ? E : rowptr[nc + 1];
    if (!nvalid) end = start;

    int rr = ql >> 2;      // phase A: record slot 0..3
    int hh = ql & 3;       // phase A: head
    int qb = qt * 16;      // quarter's base lane

    const float4* qp = (const float4*)(q16 + (size_t)nc * FDIM + hh * 16);
    float4 qv[2] = { qp[0], qp[1] };
    const __half2* qh = (const __half2*)qv;
    float qf[16];
#pragma unroll
    for (int j = 0; j < 8; ++j) {
        float2 f = __half22float2(qh[j]);
        qf[2 * j] = f.x;
        qf[2 * j + 1] = f.y;
    }

    float zacc = 0.f;
    // acc[head][lo/hi]: this lane's feats 4ql+{0,1} / 4ql+{2,3}, all 4 heads
    f32x2 a00 = {0.f,0.f}, a01 = {0.f,0.f};
    f32x2 a10 = {0.f,0.f}, a11 = {0.f,0.f};
    f32x2 a20 = {0.f,0.f}, a21 = {0.f,0.f};
    f32x2 a30 = {0.f,0.f}, a31 = {0.f,0.f};

    for (int base = start; base < end; base += 4) {
        // ---- issue gathers ----
        int idx = base + rr;
        bool valid = (idx < end);
        int ic = valid ? idx : (end - 1);
        int sA = srcs[ic];
        int s0 = __shfl(sA, qb + 0,  64);
        int s1 = __shfl(sA, qb + 4,  64);
        int s2 = __shfl(sA, qb + 8,  64);
        int s3 = __shfl(sA, qb + 12, 64);
        const float4* kp = (const float4*)(k16 + (size_t)sA * FDIM + hh * 16);
        float4 ka0 = kp[0], ka1 = kp[1];
        uint2 g0 = *(const uint2*)(hp16 + (size_t)s0 * FDIM + ql * 4);
        uint2 g1 = *(const uint2*)(hp16 + (size_t)s1 * FDIM + ql * 4);
        uint2 g2 = *(const uint2*)(hp16 + (size_t)s2 * FDIM + ql * 4);
        uint2 g3 = *(const uint2*)(hp16 + (size_t)s3 * FDIM + ql * 4);

        // ---- phase A ----
        float4 ka[2] = { ka0, ka1 };
        float w = __builtin_amdgcn_exp2f(dot16(ka, qf));
        w = valid ? w : 0.f;
        zacc += w;

        // ---- phase B: record r weights from lanes qb + r*4 + head ----
#define GRP(G, LBASE)                                                      \
    {   float w0 = __shfl(w, (LBASE) + 0, 64);                             \
        float w1 = __shfl(w, (LBASE) + 1, 64);                             \
        float w2 = __shfl(w, (LBASE) + 2, 64);                             \
        float w3 = __shfl(w, (LBASE) + 3, 64);                             \
        float2 flo = __half22float2(*(__half2*)&(G).x);                    \
        float2 fhi = __half22float2(*(__half2*)&(G).y);                    \
        f32x2 vlo; vlo.x = flo.x; vlo.y = flo.y;                           \
        f32x2 vhi; vhi.x = fhi.x; vhi.y = fhi.y;                           \
        f32x2 wv;                                                          \
        wv.x = w0; wv.y = w0;                                              \
        a00 = __builtin_elementwise_fma(wv, vlo, a00);                     \
        a01 = __builtin_elementwise_fma(wv, vhi, a01);                     \
        wv.x = w1; wv.y = w1;                                              \
        a10 = __builtin_elementwise_fma(wv, vlo, a10);                     \
        a11 = __builtin_elementwise_fma(wv, vhi, a11);                     \
        wv.x = w2; wv.y = w2;                                              \
        a20 = __builtin_elementwise_fma(wv, vlo, a20);                     \
        a21 = __builtin_elementwise_fma(wv, vhi, a21);                     \
        wv.x = w3; wv.y = w3;                                              \
        a30 = __builtin_elementwise_fma(wv, vlo, a30);                     \
        a31 = __builtin_elementwise_fma(wv, vhi, a31);                     }

        GRP(g0, qb + 0)
        if (base + 1 < end) { GRP(g1, qb + 4) }
        if (base + 2 < end) { GRP(g2, qb + 8) }
        if (base + 3 < end) { GRP(g3, qb + 12) }
#undef GRP
    }

    // fold z over the 4 record slots (bits 2..3 of lane, within quarter)
    zacc += __shfl_xor(zacc, 4, 64);
    zacc += __shfl_xor(zacc, 8, 64);
    float z0 = __shfl(zacc, qb + 0, 64);
    float z1 = __shfl(zacc, qb + 1, 64);
    float z2 = __shfl(zacc, qb + 2, 64);
    float z3 = __shfl(zacc, qb + 3, 64);

    if (!nvalid) return;
    float4 bv = *(const float4*)(bvec + ql * 4);
    float4* o = (float4*)(out + (size_t)n * (NHEADS * FDIM));
    if (end > start) {
        float rz0 = 1.f / z0;
        float rz1 = 1.f / z1;
        float rz2 = 1.f / z2;
        float rz3 = 1.f / z3;
        o[ql]      = make_float4(fmaf(a00.x, rz0, bv.x), fmaf(a00.y, rz0, bv.y),
                                 fmaf(a01.x, rz0, bv.z), fmaf(a01.y, rz0, bv.w));
        o[16 + ql] = make_float4(fmaf(a10.x, rz1, bv.x), fmaf(a10.y, rz1, bv.y),
                                 fmaf(a11.x, rz1, bv.z), fmaf(a11.y, rz1, bv.w));
        o[32 + ql] = make_float4(fmaf(a20.x, rz2, bv.x), fmaf(a20.y, rz2, bv.y),
                                 fmaf(a21.x, rz2, bv.z), fmaf(a21.y, rz2, bv.w));
        o[48 + ql] = make_float4(fmaf(a30.x, rz3, bv.x), fmaf(a30.y, rz3, bv.y),
                                 fmaf(a31.x, rz3, bv.z), fmaf(a31.y, rz3, bv.w));
    } else {
        o[ql] = bv; o[16 + ql] = bv; o[32 + ql] = bv; o[48 + ql] = bv;
    }
}

extern "C" void kernel_launch(void* const* d_in, const int* in_sizes, int n_in,
                              void* d_out, int out_size, void* d_ws, size_t ws_size,
                              hipStream_t stream) {
    const float* h   = (const float*)d_in[0];
    const int*   src = (const int*)d_in[1];
    const int*   dst = (const int*)d_in[2];
    const float* Wk  = (const float*)d_in[3];
    const float* Wq  = (const float*)d_in[4];
    const float* W   = (const float*)d_in[5];
    const float* b   = (const float*)d_in[6];
    float* out = (float*)d_out;

    const int N = in_sizes[0] / FDIM;   // 100000
    const int E = in_sizes[1];          // 1600000

    const int NBUCK = (N + 255) >> 8;               // 391
    const int NTILE = (E + TILE - 1) / TILE;        // 196
    const int KQB   = (N + 127) / 128;              // 782
    const int PB    = (N + 127) / 128;              // 782 (hp role)

    // Workspace: k16 12.8MB, q16 12.8MB, hp16 12.8MB,
    //            ebuf[NBUCK*BCAP u32] 9.6MB, srcs[E] 6.4MB,
    //            gcnt[512], rowptr[N].  (~55 MB)
    __half* k16 = (__half*)d_ws;
    __half* q16 = k16 + (size_t)N * FDIM;
    __half* hp16 = q16 + (size_t)N * FDIM;
    unsigned int* ebuf = (unsigned int*)(hp16 + (size_t)N * FDIM);
    int* srcs   = (int*)(ebuf + (size_t)NBUCK * BCAP);
    int* gcnt   = srcs + E;
    int* rowptr = gcnt + 512;

    hipMemsetAsync(gcnt, 0, 512 * sizeof(int), stream);

    k1_kernel<<<KQB + PB + NTILE, 256, 0, stream>>>(
        h, Wk, Wq, W, src, dst, k16, q16, hp16, gcnt, ebuf,
        N, E, KQB, PB, NBUCK);
    binB_kernel<<<NBUCK, 1024, 0, stream>>>(gcnt, ebuf, rowptr, srcs, N);
    fused_sa_kernel<<<(N + 15) / 16, 256, 0, stream>>>(
        rowptr, srcs, k16, q16, hp16, b, out, N, E);
}

// Round 16
// 272.149 us; speedup vs baseline: 2.2493x; 1.0832x over previous
//
#include <hip/hip_runtime.h>
#include <hip/hip_fp16.h>
#include <math.h>

// GAT layer: N=100000, E=1600000, F=64, H=4 (Dh=16).
//
// Pipeline (4 dispatches): memset(gcnt) ->
// K1 {binA bucket-sort FIRST | kq GEMM | hp GEMM}  (R16: binA blocks lead
//   the dispatch so they overlap the GEMM wavefront instead of trailing
//   serially; TILE 8192->6144 shrinks the LDS union to 32KB -> 5 blocks/CU)
// -> binB (1024 thr/block: inline gcnt scan; LDS-staged counting sort) ->
// fused_sa QUARTER-PER-NODE (16-lane quarter = node; phase A 4 rec x 4 head
//   edge-parallel dot; phase B lane=feature-quad, no merge epilogue).
//
// R0-R4 law: any per-edge random-slot global store/atomic costs 100-150us.
// All scattering happens in LDS; global writes are coalesced streams.
// BCAP overflow (32-sigma for random dst) is CLAMPED (graceful, no OOB).

#define FDIM 64
#define NHEADS 4
#define TILE 6144
#define BCAP 6144

typedef float f32x2 __attribute__((ext_vector_type(2)));

// ---- K1: multi-role: [0,NTILE) binA | [NTILE,+KQB) kq | [+KQB,+PB) hp ----
// LDS union 32KB: GEMM roles use 2x16KB f32 mats; binA uses 31.7KB
// (512*3 u32 tables + 256 u32 scan + 6144 u32 tile buffer).
__global__ __launch_bounds__(256) void k1_kernel(
    const float* __restrict__ h, const float* __restrict__ Wk,
    const float* __restrict__ Wq, const float* __restrict__ Wo,
    const int* __restrict__ src, const int* __restrict__ dst,
    __half* __restrict__ k16, __half* __restrict__ q16,
    __half* __restrict__ hp16, int* __restrict__ gcnt,
    unsigned int* __restrict__ ebuf,
    int N, int E, int NTILE, int KQB, int nbuck)
{
    __shared__ __align__(16) unsigned char smem_raw[32768];
    int bid = blockIdx.x;
    int t = threadIdx.x;
    if (bid < NTILE) {
        // ---- binA role: tile of 6144 edges -> LDS counting sort by bucket
        // (dst>>8) -> per-bucket coalesced append to ebuf. Packed entry:
        // src<<8 | (dst&255). Appends clamped to BCAP.
        unsigned int* bh     = (unsigned int*)smem_raw;          // 512
        unsigned int* bstart = bh + 512;                          // 512
        unsigned int* bbase  = bstart + 512;                      // 512
        unsigned int* sd     = bbase + 512;                       // 256
        unsigned int* ebuf_l = sd + 256;                          // 6144
        long e0 = (long)bid * TILE;
        int cnt_tile = (int)(((long)E - e0 < (long)TILE) ? ((long)E - e0) : (long)TILE);

        bh[t] = 0; bh[t + 256] = 0;
        __syncthreads();
        for (int j = t; j < cnt_tile; j += 256)
            atomicAdd(&bh[dst[e0 + j] >> 8], 1u);
        __syncthreads();
        unsigned int c0 = bh[2 * t], c1 = bh[2 * t + 1];
        unsigned int s = c0 + c1;
        sd[t] = s;
        __syncthreads();
        for (int off = 1; off < 256; off <<= 1) {
            unsigned int v = (t >= off) ? sd[t - off] : 0;
            __syncthreads();
            sd[t] += v;
            __syncthreads();
        }
        unsigned int ex = sd[t] - s;
        bh[2 * t] = ex;          bstart[2 * t] = ex;
        bh[2 * t + 1] = ex + c0; bstart[2 * t + 1] = ex + c0;
        if (c0 > 0) bbase[2 * t] = (unsigned int)atomicAdd(&gcnt[2 * t], (int)c0);
        if (c1 > 0) bbase[2 * t + 1] = (unsigned int)atomicAdd(&gcnt[2 * t + 1], (int)c1);
        __syncthreads();
        for (int j = t; j < cnt_tile; j += 256) {
            int d = dst[e0 + j];
            int sv = src[e0 + j];
            unsigned int pos = atomicAdd(&bh[d >> 8], 1u);
            ebuf_l[pos] = ((unsigned int)sv << 8) | (unsigned int)(d & 255);
        }
        __syncthreads();
        int wave = t >> 6, lane = t & 63;
        for (int b = wave; b < nbuck; b += 4) {
            unsigned int st = bstart[b];
            unsigned int en = bh[b];
            if (st == en) continue;
            unsigned int gb = bbase[b];
            if (gb >= (unsigned int)BCAP) continue;
            unsigned int room = (unsigned int)BCAP - gb;
            if (en - st > room) en = st + room;
            unsigned int* dstp = ebuf + (size_t)b * BCAP + gb;
            for (unsigned int j = st + lane; j < en; j += 64)
                dstp[j - st] = ebuf_l[j];
        }
    } else if (bid < NTILE + KQB) {
        // ---- kq role: k = h@(Wk*log2e), q = h@Wq, fp16 out ----
        float* sWk = (float*)smem_raw;
        float* sWq = (float*)(smem_raw + 16384);
        for (int i = t; i < FDIM * FDIM; i += 256) {
            sWk[i] = Wk[i] * 1.4426950408889634f;
            sWq[i] = Wq[i];
        }
        __syncthreads();
        int cg = t & 3;
        int rg = t >> 2;
        long base = (long)(bid - NTILE) * 128 + rg * 2;
        const float4* sWk4 = (const float4*)sWk;
        const float4* sWq4 = (const float4*)sWq;
        const float4* h4 = (const float4*)h;
        float acck[2][16], accq[2][16];
#pragma unroll
        for (int i = 0; i < 2; ++i)
#pragma unroll
            for (int c = 0; c < 16; ++c) { acck[i][c] = 0.f; accq[i][c] = 0.f; }

        for (int fs = 0; fs < FDIM; fs += 4) {
            float4 hv[2];
#pragma unroll
            for (int i = 0; i < 2; ++i) {
                long r = base + i; if (r >= N) r = N - 1;
                hv[i] = h4[r * 16 + (fs >> 2)];
            }
#pragma unroll
            for (int fi = 0; fi < 4; ++fi) {
                int f = fs + fi;
                float4 wk0 = sWk4[f * 16 + cg * 4 + 0];
                float4 wk1 = sWk4[f * 16 + cg * 4 + 1];
                float4 wk2 = sWk4[f * 16 + cg * 4 + 2];
                float4 wk3 = sWk4[f * 16 + cg * 4 + 3];
                float4 wq0 = sWq4[f * 16 + cg * 4 + 0];
                float4 wq1 = sWq4[f * 16 + cg * 4 + 1];
                float4 wq2 = sWq4[f * 16 + cg * 4 + 2];
                float4 wq3 = sWq4[f * 16 + cg * 4 + 3];
#pragma unroll
                for (int i = 0; i < 2; ++i) {
                    float hvf = (&hv[i].x)[fi];
                    acck[i][0]  = fmaf(hvf, wk0.x, acck[i][0]);
                    acck[i][1]  = fmaf(hvf, wk0.y, acck[i][1]);
                    acck[i][2]  = fmaf(hvf, wk0.z, acck[i][2]);
                    acck[i][3]  = fmaf(hvf, wk0.w, acck[i][3]);
                    acck[i][4]  = fmaf(hvf, wk1.x, acck[i][4]);
                    acck[i][5]  = fmaf(hvf, wk1.y, acck[i][5]);
                    acck[i][6]  = fmaf(hvf, wk1.z, acck[i][6]);
                    acck[i][7]  = fmaf(hvf, wk1.w, acck[i][7]);
                    acck[i][8]  = fmaf(hvf, wk2.x, acck[i][8]);
                    acck[i][9]  = fmaf(hvf, wk2.y, acck[i][9]);
                    acck[i][10] = fmaf(hvf, wk2.z, acck[i][10]);
                    acck[i][11] = fmaf(hvf, wk2.w, acck[i][11]);
                    acck[i][12] = fmaf(hvf, wk3.x, acck[i][12]);
                    acck[i][13] = fmaf(hvf, wk3.y, acck[i][13]);
                    acck[i][14] = fmaf(hvf, wk3.z, acck[i][14]);
                    acck[i][15] = fmaf(hvf, wk3.w, acck[i][15]);
                    accq[i][0]  = fmaf(hvf, wq0.x, accq[i][0]);
                    accq[i][1]  = fmaf(hvf, wq0.y, accq[i][1]);
                    accq[i][2]  = fmaf(hvf, wq0.z, accq[i][2]);
                    accq[i][3]  = fmaf(hvf, wq0.w, accq[i][3]);
                    accq[i][4]  = fmaf(hvf, wq1.x, accq[i][4]);
                    accq[i][5]  = fmaf(hvf, wq1.y, accq[i][5]);
                    accq[i][6]  = fmaf(hvf, wq1.z, accq[i][6]);
                    accq[i][7]  = fmaf(hvf, wq1.w, accq[i][7]);
                    accq[i][8]  = fmaf(hvf, wq2.x, accq[i][8]);
                    accq[i][9]  = fmaf(hvf, wq2.y, accq[i][9]);
                    accq[i][10] = fmaf(hvf, wq2.z, accq[i][10]);
                    accq[i][11] = fmaf(hvf, wq2.w, accq[i][11]);
                    accq[i][12] = fmaf(hvf, wq3.x, accq[i][12]);
                    accq[i][13] = fmaf(hvf, wq3.y, accq[i][13]);
                    accq[i][14] = fmaf(hvf, wq3.z, accq[i][14]);
                    accq[i][15] = fmaf(hvf, wq3.w, accq[i][15]);
                }
            }
        }
#pragma unroll
        for (int i = 0; i < 2; ++i) {
            long r = base + i;
            if (r >= N) continue;
            __half2 hk[8], hq[8];
#pragma unroll
            for (int c = 0; c < 8; ++c) {
                hk[c] = __floats2half2_rn(acck[i][2 * c], acck[i][2 * c + 1]);
                hq[c] = __floats2half2_rn(accq[i][2 * c], accq[i][2 * c + 1]);
            }
            float4* kout = (float4*)(k16 + (size_t)r * FDIM + cg * 16);
            float4* qout = (float4*)(q16 + (size_t)r * FDIM + cg * 16);
            kout[0] = ((float4*)hk)[0]; kout[1] = ((float4*)hk)[1];
            qout[0] = ((float4*)hq)[0]; qout[1] = ((float4*)hq)[1];
        }
    } else {
        // ---- hp role: hp = h @ Wo (fp16 out), 128 rows/block ----
        float* sW = (float*)smem_raw;
        for (int i = t; i < FDIM * FDIM; i += 256) sW[i] = Wo[i];
        __syncthreads();
        int cg = t & 3;
        int rg = t >> 2;
        long base = (long)(bid - NTILE - KQB) * 128 + rg * 2;
        const float4* sW4 = (const float4*)sW;
        const float4* h4 = (const float4*)h;
        float accp[2][16];
#pragma unroll
        for (int i = 0; i < 2; ++i)
#pragma unroll
            for (int c = 0; c < 16; ++c) accp[i][c] = 0.f;

        for (int fs = 0; fs < FDIM; fs += 4) {
            float4 hv[2];
#pragma unroll
            for (int i = 0; i < 2; ++i) {
                long r = base + i; if (r >= N) r = N - 1;
                hv[i] = h4[r * 16 + (fs >> 2)];
            }
#pragma unroll
            for (int fi = 0; fi < 4; ++fi) {
                int f = fs + fi;
                float4 w0 = sW4[f * 16 + cg * 4 + 0];
                float4 w1 = sW4[f * 16 + cg * 4 + 1];
                float4 w2 = sW4[f * 16 + cg * 4 + 2];
                float4 w3 = sW4[f * 16 + cg * 4 + 3];
#pragma unroll
                for (int i = 0; i < 2; ++i) {
                    float hvf = (&hv[i].x)[fi];
                    accp[i][0]  = fmaf(hvf, w0.x, accp[i][0]);
                    accp[i][1]  = fmaf(hvf, w0.y, accp[i][1]);
                    accp[i][2]  = fmaf(hvf, w0.z, accp[i][2]);
                    accp[i][3]  = fmaf(hvf, w0.w, accp[i][3]);
                    accp[i][4]  = fmaf(hvf, w1.x, accp[i][4]);
                    accp[i][5]  = fmaf(hvf, w1.y, accp[i][5]);
                    accp[i][6]  = fmaf(hvf, w1.z, accp[i][6]);
                    accp[i][7]  = fmaf(hvf, w1.w, accp[i][7]);
                    accp[i][8]  = fmaf(hvf, w2.x, accp[i][8]);
                    accp[i][9]  = fmaf(hvf, w2.y, accp[i][9]);
                    accp[i][10] = fmaf(hvf, w2.z, accp[i][10]);
                    accp[i][11] = fmaf(hvf, w2.w, accp[i][11]);
                    accp[i][12] = fmaf(hvf, w3.x, accp[i][12]);
                    accp[i][13] = fmaf(hvf, w3.y, accp[i][13]);
                    accp[i][14] = fmaf(hvf, w3.z, accp[i][14]);
                    accp[i][15] = fmaf(hvf, w3.w, accp[i][15]);
                }
            }
        }
#pragma unroll
        for (int i = 0; i < 2; ++i) {
            long r = base + i;
            if (r >= N) continue;
            __half2 hp[8];
#pragma unroll
            for (int c = 0; c < 8; ++c)
                hp[c] = __floats2half2_rn(accp[i][2 * c], accp[i][2 * c + 1]);
            float4* pout = (float4*)(hp16 + (size_t)r * FDIM + cg * 16);
            pout[0] = ((float4*)hp)[0];
            pout[1] = ((float4*)hp)[1];
        }
    }
}

// K2: binB, 1024 threads/block (16 waves of latency hiding). Inline gcnt
// scan on first 256 threads; LDS-staged counting sort; rowptr; srcs.
__global__ __launch_bounds__(1024) void binB_kernel(
    const int* __restrict__ gcnt, const unsigned int* __restrict__ ebuf,
    int* __restrict__ rowptr, int* __restrict__ srcs, int N)
{
    __shared__ int sg[512];
    __shared__ unsigned int lh[256];
    __shared__ unsigned int sd[256];
    __shared__ unsigned int ebuf_l[BCAP];
    __shared__ unsigned int srcs_l[BCAP];
    int t = threadIdx.x;
    int b = blockIdx.x;

    // inline exclusive scan of gcnt (first 256 threads, 2 entries each)
    int c0 = 0, c1 = 0;
    if (t < 256) {
        c0 = gcnt[2 * t]; c1 = gcnt[2 * t + 1];
        sd[t] = (unsigned int)(c0 + c1);
        lh[t] = 0;
    }
    __syncthreads();
    for (int off = 1; off < 256; off <<= 1) {
        unsigned int v = (t < 256 && t >= off) ? sd[t - off] : 0;
        __syncthreads();
        if (t < 256) sd[t] += v;
        __syncthreads();
    }
    if (t < 256) {
        int ex = (int)sd[t] - (c0 + c1);
        sg[2 * t] = ex;
        sg[2 * t + 1] = ex + c0;
    }
    __syncthreads();
    int gb = sg[b];
    int cnt = gcnt[b];
    if (cnt > BCAP) cnt = BCAP;   // matches binA clamp
    int n0 = b << 8;
    const unsigned int* eb = ebuf + (size_t)b * BCAP;

    // single global pass: stage into LDS + histogram
    for (int j = t; j < cnt; j += 1024) {
        unsigned int p = eb[j];
        ebuf_l[j] = p;
        atomicAdd(&lh[p & 255u], 1u);
    }
    __syncthreads();
    unsigned int c = 0;
    if (t < 256) { c = lh[t]; sd[t] = c; }
    __syncthreads();
    for (int off = 1; off < 256; off <<= 1) {
        unsigned int v = (t < 256 && t >= off) ? sd[t - off] : 0;
        __syncthreads();
        if (t < 256) sd[t] += v;
        __syncthreads();
    }
    if (t < 256) {
        unsigned int excl = sd[t] - c;
        lh[t] = excl;
        if (n0 + t < N) rowptr[n0 + t] = gb + (int)excl;
    }
    __syncthreads();
    for (int j = t; j < cnt; j += 1024) {
        unsigned int p = ebuf_l[j];
        unsigned int pos = atomicAdd(&lh[p & 255u], 1u);
        srcs_l[pos] = p >> 8;
    }
    __syncthreads();
    for (int j = t; j < cnt; j += 1024)
        srcs[gb + j] = (int)srcs_l[j];
}

__device__ __forceinline__ float dot16(const float4* kk, const float* qf) {
    const __half2* kh = (const __half2*)kk;
    float acc = 0.f;
#pragma unroll
    for (int j = 0; j < 8; ++j) {
        float2 kf = __half22float2(kh[j]);
        acc = fmaf(kf.x, qf[2 * j], acc);
        acc = fmaf(kf.y, qf[2 * j + 1], acc);
    }
    return acc;
}

// K3: fused score+aggregate, QUARTER-PER-NODE. 16-lane quarter = one node
// (4 nodes/wave, 16/block). Per chunk of 4 records:
//   phase A: ql=(rr=ql>>2, hh=ql&3) -> 4 records x 4 heads, fp16 dot,
//            w=exp2(e') in register (w=0 for tail slots).
//   phase B: lane owns feats 4ql..4ql+3 of its quarter's records for ALL
//            heads; per record one uint2 gather + 4 w-shfls + 8 pk-fma.
// Epilogue: z-fold = 2 shfl_xor (within quarter); NO accumulator merges;
// 4 coalesced float4 stores per lane.
__global__ __launch_bounds__(256) void fused_sa_kernel(
    const int* __restrict__ rowptr, const int* __restrict__ srcs,
    const __half* __restrict__ k16, const __half* __restrict__ q16,
    const __half* __restrict__ hp16, const float* __restrict__ bvec,
    float* __restrict__ out, int N, int E)
{
    int lane = threadIdx.x & 63;
    int wid = threadIdx.x >> 6;
    int qt = lane >> 4;    // quarter = node slot
    int ql = lane & 15;    // lane within quarter
    int n = blockIdx.x * 16 + wid * 4 + qt;
    bool nvalid = (n < N);
    int nc = nvalid ? n : N - 1;
    int start = rowptr[nc];
    int end = (nc == N - 1) ? E : rowptr[nc + 1];
    if (!nvalid) end = start;

    int rr = ql >> 2;      // phase A: record slot 0..3
    int hh = ql & 3;       // phase A: head
    int qb = qt * 16;      // quarter's base lane

    const float4* qp = (const float4*)(q16 + (size_t)nc * FDIM + hh * 16);
    float4 qv[2] = { qp[0], qp[1] };
    const __half2* qh = (const __half2*)qv;
    float qf[16];
#pragma unroll
    for (int j = 0; j < 8; ++j) {
        float2 f = __half22float2(qh[j]);
        qf[2 * j] = f.x;
        qf[2 * j + 1] = f.y;
    }

    float zacc = 0.f;
    // acc[head][lo/hi]: this lane's feats 4ql+{0,1} / 4ql+{2,3}, all 4 heads
    f32x2 a00 = {0.f,0.f}, a01 = {0.f,0.f};
    f32x2 a10 = {0.f,0.f}, a11 = {0.f,0.f};
    f32x2 a20 = {0.f,0.f}, a21 = {0.f,0.f};
    f32x2 a30 = {0.f,0.f}, a31 = {0.f,0.f};

    for (int base = start; base < end; base += 4) {
        // ---- issue gathers ----
        int idx = base + rr;
        bool valid = (idx < end);
        int ic = valid ? idx : (end - 1);
        int sA = srcs[ic];
        int s0 = __shfl(sA, qb + 0,  64);
        int s1 = __shfl(sA, qb + 4,  64);
        int s2 = __shfl(sA, qb + 8,  64);
        int s3 = __shfl(sA, qb + 12, 64);
        const float4* kp = (const float4*)(k16 + (size_t)sA * FDIM + hh * 16);
        float4 ka0 = kp[0], ka1 = kp[1];
        uint2 g0 = *(const uint2*)(hp16 + (size_t)s0 * FDIM + ql * 4);
        uint2 g1 = *(const uint2*)(hp16 + (size_t)s1 * FDIM + ql * 4);
        uint2 g2 = *(const uint2*)(hp16 + (size_t)s2 * FDIM + ql * 4);
        uint2 g3 = *(const uint2*)(hp16 + (size_t)s3 * FDIM + ql * 4);

        // ---- phase A ----
        float4 ka[2] = { ka0, ka1 };
        float w = __builtin_amdgcn_exp2f(dot16(ka, qf));
        w = valid ? w : 0.f;
        zacc += w;

        // ---- phase B: record r weights from lanes qb + r*4 + head ----
#define GRP(G, LBASE)                                                      \
    {   float w0 = __shfl(w, (LBASE) + 0, 64);                             \
        float w1 = __shfl(w, (LBASE) + 1, 64);                             \
        float w2 = __shfl(w, (LBASE) + 2, 64);                             \
        float w3 = __shfl(w, (LBASE) + 3, 64);                             \
        float2 flo = __half22float2(*(__half2*)&(G).x);                    \
        float2 fhi = __half22float2(*(__half2*)&(G).y);                    \
        f32x2 vlo; vlo.x = flo.x; vlo.y = flo.y;                           \
        f32x2 vhi; vhi.x = fhi.x; vhi.y = fhi.y;                           \
        f32x2 wv;                                                          \
        wv.x = w0; wv.y = w0;                                              \
        a00 = __builtin_elementwise_fma(wv, vlo, a00);                     \
        a01 = __builtin_elementwise_fma(wv, vhi, a01);                     \
        wv.x = w1; wv.y = w1;                                              \
        a10 = __builtin_elementwise_fma(wv, vlo, a10);                     \
        a11 = __builtin_elementwise_fma(wv, vhi, a11);                     \
        wv.x = w2; wv.y = w2;                                              \
        a20 = __builtin_elementwise_fma(wv, vlo, a20);                     \
        a21 = __builtin_elementwise_fma(wv, vhi, a21);                     \
        wv.x = w3; wv.y = w3;                                              \
        a30 = __builtin_elementwise_fma(wv, vlo, a30);                     \
        a31 = __builtin_elementwise_fma(wv, vhi, a31);                     }

        GRP(g0, qb + 0)
        if (base + 1 < end) { GRP(g1, qb + 4) }
        if (base + 2 < end) { GRP(g2, qb + 8) }
        if (base + 3 < end) { GRP(g3, qb + 12) }
#undef GRP
    }

    // fold z over the 4 record slots (bits 2..3 of lane, within quarter)
    zacc += __shfl_xor(zacc, 4, 64);
    zacc += __shfl_xor(zacc, 8, 64);
    float z0 = __shfl(zacc, qb + 0, 64);
    float z1 = __shfl(zacc, qb + 1, 64);
    float z2 = __shfl(zacc, qb + 2, 64);
    float z3 = __shfl(zacc, qb + 3, 64);

    if (!nvalid) return;
    float4 bv = *(const float4*)(bvec + ql * 4);
    float4* o = (float4*)(out + (size_t)n * (NHEADS * FDIM));
    if (end > start) {
        float rz0 = 1.f / z0;
        float rz1 = 1.f / z1;
        float rz2 = 1.f / z2;
        float rz3 = 1.f / z3;
        o[ql]      = make_float4(fmaf(a00.x, rz0, bv.x), fmaf(a00.y, rz0, bv.y),
                                 fmaf(a01.x, rz0, bv.z), fmaf(a01.y, rz0, bv.w));
        o[16 + ql] = make_float4(fmaf(a10.x, rz1, bv.x), fmaf(a10.y, rz1, bv.y),
                                 fmaf(a11.x, rz1, bv.z), fmaf(a11.y, rz1, bv.w));
        o[32 + ql] = make_float4(fmaf(a20.x, rz2, bv.x), fmaf(a20.y, rz2, bv.y),
                                 fmaf(a21.x, rz2, bv.z), fmaf(a21.y, rz2, bv.w));
        o[48 + ql] = make_float4(fmaf(a30.x, rz3, bv.x), fmaf(a30.y, rz3, bv.y),
                                 fmaf(a31.x, rz3, bv.z), fmaf(a31.y, rz3, bv.w));
    } else {
        o[ql] = bv; o[16 + ql] = bv; o[32 + ql] = bv; o[48 + ql] = bv;
    }
}

extern "C" void kernel_launch(void* const* d_in, const int* in_sizes, int n_in,
                              void* d_out, int out_size, void* d_ws, size_t ws_size,
                              hipStream_t stream) {
    const float* h   = (const float*)d_in[0];
    const int*   src = (const int*)d_in[1];
    const int*   dst = (const int*)d_in[2];
    const float* Wk  = (const float*)d_in[3];
    const float* Wq  = (const float*)d_in[4];
    const float* W   = (const float*)d_in[5];
    const float* b   = (const float*)d_in[6];
    float* out = (float*)d_out;

    const int N = in_sizes[0] / FDIM;   // 100000
    const int E = in_sizes[1];          // 1600000

    const int NBUCK = (N + 255) >> 8;               // 391
    const int NTILE = (E + TILE - 1) / TILE;        // 261
    const int KQB   = (N + 127) / 128;              // 782
    const int PB    = (N + 127) / 128;              // 782 (hp role)

    // Workspace: k16 12.8MB, q16 12.8MB, hp16 12.8MB,
    //            ebuf[NBUCK*BCAP u32] 9.6MB, srcs[E] 6.4MB,
    //            gcnt[512], rowptr[N].  (~55 MB)
    __half* k16 = (__half*)d_ws;
    __half* q16 = k16 + (size_t)N * FDIM;
    __half* hp16 = q16 + (size_t)N * FDIM;
    unsigned int* ebuf = (unsigned int*)(hp16 + (size_t)N * FDIM);
    int* srcs   = (int*)(ebuf + (size_t)NBUCK * BCAP);
    int* gcnt   = srcs + E;
    int* rowptr = gcnt + 512;

    hipMemsetAsync(gcnt, 0, 512 * sizeof(int), stream);

    k1_kernel<<<NTILE + KQB + PB, 256, 0, stream>>>(
        h, Wk, Wq, W, src, dst, k16, q16, hp16, gcnt, ebuf,
        N, E, NTILE, KQB, NBUCK);
    binB_kernel<<<NBUCK, 1024, 0, stream>>>(gcnt, ebuf, rowptr, srcs, N);
    fused_sa_kernel<<<(N + 15) / 16, 256, 0, stream>>>(
        rowptr, srcs, k16, q16, hp16, b, out, N, E);
}